// Round 1
// baseline (1314.677 us; speedup 1.0000x reference)
//
#include <hip/hip_runtime.h>
#include <hip/hip_bf16.h>

// Problem constants: B=4, C=256, C8=32, H=128, W=128, H2=W2=64, N=4096, HW=16384
#define EPS_BN 1e-5f

// ---------------------------------------------------------------------------
// Tiled fp32 GEMM for 1x1 conv:  Y[b,o,p] = sum_c W[o,c] * X[b,c,p] (+bias[o])
// BM=64, BN=64, BK=16, 256 threads, 4x4 per thread.
// UP: B-matrix elements are bilinear-upsampled on the fly from a 64x64 grid
//     (X has per-batch P_in=4096, output pixels P=16384 over 128x128).
// TOUT: write transposed output Y[b,p,o] (for qT/kT/vT layouts).
// ---------------------------------------------------------------------------
template<int UP, int TOUT>
__global__ __launch_bounds__(256) void conv_gemm(
    const float* __restrict__ W, const float* __restrict__ X,
    const float* __restrict__ bias, float* __restrict__ Y,
    int O, int K, int P)
{
    const int tid = threadIdx.x;
    const int b  = blockIdx.z;
    const int p0 = blockIdx.x * 64;
    const int o0 = blockIdx.y * 64;
    const int Pin = UP ? 4096 : P;
    const float* Xb = X + (size_t)b * K * Pin;

    __shared__ float As[16][68];  // As[k][o], row stride 272B (16B aligned, bank-shifted)
    __shared__ float Bs[16][68];  // Bs[k][p]

    float acc[4][4];
#pragma unroll
    for (int i = 0; i < 4; i++)
#pragma unroll
        for (int j = 0; j < 4; j++) acc[i][j] = 0.f;

    const int tx = tid & 15, ty = tid >> 4;
    const int arow = tid >> 2, acol = (tid & 3) * 4;
    const int bkk = tid >> 4, bpx = (tid & 15) * 4;

    for (int k0 = 0; k0 < K; k0 += 16) {
        // stage A (weights), guarded for O<64 tiles
        float4 a;
        if (o0 + arow < O) a = *(const float4*)&W[(size_t)(o0 + arow) * K + k0 + acol];
        else               a = make_float4(0.f, 0.f, 0.f, 0.f);
        As[acol + 0][arow] = a.x; As[acol + 1][arow] = a.y;
        As[acol + 2][arow] = a.z; As[acol + 3][arow] = a.w;

        // stage B (activations), optionally upsampling on the fly
        float4 v;
        if (!UP) {
            v = *(const float4*)&Xb[(size_t)(k0 + bkk) * Pin + p0 + bpx];
        } else {
            const float* src = Xb + (size_t)(k0 + bkk) * 4096;
            float t[4];
#pragma unroll
            for (int q = 0; q < 4; q++) {
                int p = p0 + bpx + q;
                int yy = p >> 7, xx = p & 127;
                float fy = 0.5f * yy - 0.25f, fx = 0.5f * xx - 0.25f;
                float fiy = floorf(fy), fixv = floorf(fx);
                float wy1 = fy - fiy, wx1 = fx - fixv;
                int iy = (int)fiy, ix = (int)fixv;
                int iy0 = max(iy, 0), iy1 = min(iy + 1, 63);
                int ix0 = max(ix, 0), ix1 = min(ix + 1, 63);
                float v00 = src[iy0 * 64 + ix0], v01 = src[iy0 * 64 + ix1];
                float v10 = src[iy1 * 64 + ix0], v11 = src[iy1 * 64 + ix1];
                t[q] = (1.f - wy1) * ((1.f - wx1) * v00 + wx1 * v01)
                     + wy1 * ((1.f - wx1) * v10 + wx1 * v11);
            }
            v = make_float4(t[0], t[1], t[2], t[3]);
        }
        *(float4*)&Bs[bkk][bpx] = v;

        __syncthreads();
#pragma unroll
        for (int kk = 0; kk < 16; kk++) {
            float4 av = *(const float4*)&As[kk][ty * 4];
            float4 bv = *(const float4*)&Bs[kk][tx * 4];
            acc[0][0] = fmaf(av.x, bv.x, acc[0][0]); acc[0][1] = fmaf(av.x, bv.y, acc[0][1]);
            acc[0][2] = fmaf(av.x, bv.z, acc[0][2]); acc[0][3] = fmaf(av.x, bv.w, acc[0][3]);
            acc[1][0] = fmaf(av.y, bv.x, acc[1][0]); acc[1][1] = fmaf(av.y, bv.y, acc[1][1]);
            acc[1][2] = fmaf(av.y, bv.z, acc[1][2]); acc[1][3] = fmaf(av.y, bv.w, acc[1][3]);
            acc[2][0] = fmaf(av.z, bv.x, acc[2][0]); acc[2][1] = fmaf(av.z, bv.y, acc[2][1]);
            acc[2][2] = fmaf(av.z, bv.z, acc[2][2]); acc[2][3] = fmaf(av.z, bv.w, acc[2][3]);
            acc[3][0] = fmaf(av.w, bv.x, acc[3][0]); acc[3][1] = fmaf(av.w, bv.y, acc[3][1]);
            acc[3][2] = fmaf(av.w, bv.z, acc[3][2]); acc[3][3] = fmaf(av.w, bv.w, acc[3][3]);
        }
        __syncthreads();
    }

#pragma unroll
    for (int i = 0; i < 4; i++) {
        int o = o0 + ty * 4 + i;
        if (o < O) {
            float bs = bias ? bias[o] : 0.f;
#pragma unroll
            for (int j = 0; j < 4; j++) {
                int p = p0 + tx * 4 + j;
                float val = acc[i][j] + bs;
                if (TOUT) Y[(size_t)b * P * O + (size_t)p * O + o] = val;
                else      Y[((size_t)b * O + o) * (size_t)P + p] = val;
            }
        }
    }
}

// ---------------------------------------------------------------------------
// Per-(channel, batch) partial sums for BatchNorm stats (deterministic).
// grid (O, B); psum/psumsq have O*B slots laid out [b*O + o].
// ---------------------------------------------------------------------------
__global__ __launch_bounds__(256) void channel_stats(
    const float* __restrict__ Y, float* __restrict__ psum,
    float* __restrict__ psumsq, int Pn)
{
    const int o = blockIdx.x, b = blockIdx.y, O = gridDim.x;
    const float* p = Y + ((size_t)b * O + o) * Pn;
    float s = 0.f, s2 = 0.f;
    for (int i = threadIdx.x * 4; i < Pn; i += 256 * 4) {
        float4 v = *(const float4*)&p[i];
        s  += v.x + v.y + v.z + v.w;
        s2 += v.x * v.x + v.y * v.y + v.z * v.z + v.w * v.w;
    }
#pragma unroll
    for (int off = 32; off; off >>= 1) {
        s  += __shfl_down(s, off);
        s2 += __shfl_down(s2, off);
    }
    __shared__ float ws1[4], ws2[4];
    int lane = threadIdx.x & 63, w = threadIdx.x >> 6;
    if (lane == 0) { ws1[w] = s; ws2[w] = s2; }
    __syncthreads();
    if (threadIdx.x == 0) {
        float ts = 0.f, ts2 = 0.f;
#pragma unroll
        for (int k = 0; k < 4; k++) { ts += ws1[k]; ts2 += ws2[k]; }
        psum[(size_t)b * O + o] = ts;
        psumsq[(size_t)b * O + o] = ts2;
    }
}

// one block x 256 threads: fold batch partials -> scale/shift per channel
__global__ void bn_finalize(const float* __restrict__ psum, const float* __restrict__ psumsq,
                            const float* __restrict__ g, const float* __restrict__ bb,
                            float* __restrict__ scale, float* __restrict__ shift, float invN)
{
    int o = threadIdx.x;
    float s = 0.f, s2 = 0.f;
#pragma unroll
    for (int b = 0; b < 4; b++) { s += psum[b * 256 + o]; s2 += psumsq[b * 256 + o]; }
    float mean = s * invN;
    float var  = s2 * invN - mean * mean;
    float r = rsqrtf(var + EPS_BN);
    float sc = g[o] * r;
    scale[o] = sc;
    shift[o] = bb[o] - mean * sc;
}

// antialiased bilinear 2x downsample taps (jax.image.resize semantics)
__device__ __forceinline__ int dtaps(int u, int* j, float* w) {
    if (u == 0)  { j[0]=0;   j[1]=1;   j[2]=2;   w[0]=3.f/7.f; w[1]=3.f/7.f; w[2]=1.f/7.f; return 3; }
    if (u == 63) { j[0]=125; j[1]=126; j[2]=127; w[0]=1.f/7.f; w[1]=3.f/7.f; w[2]=3.f/7.f; return 3; }
    j[0]=2*u-1; j[1]=2*u; j[2]=2*u+1; j[3]=2*u+2;
    w[0]=0.125f; w[1]=0.375f; w[2]=0.375f; w[3]=0.125f; return 4;
}

// BN + ReLU + antialiased bilinear 128->64 downsample.  grid (16, 256, 4)
__global__ __launch_bounds__(256) void bnrelu_down(
    const float* __restrict__ y1, const float* __restrict__ scale,
    const float* __restrict__ shift, float* __restrict__ h)
{
    int i = blockIdx.x * 256 + threadIdx.x;          // 0..4095 over 64x64
    int o = blockIdx.y, b = blockIdx.z;
    int y2 = i >> 6, x2 = i & 63;
    const float* base = y1 + ((size_t)(b * 256 + o)) * 16384;
    float sc = scale[o], sh = shift[o];
    int jy[4]; float wy[4]; int ny = dtaps(y2, jy, wy);
    int jx[4]; float wx[4]; int nx = dtaps(x2, jx, wx);
    float acc = 0.f;
    for (int a = 0; a < ny; a++) {
        const float* row = base + jy[a] * 128;
        for (int c = 0; c < nx; c++) {
            float v = fmaxf(fmaf(sc, row[jx[c]], sh), 0.f);
            acc += wy[a] * wx[c] * v;
        }
    }
    h[((size_t)(b * 256 + o)) * 4096 + i] = acc;
}

// ---------------------------------------------------------------------------
// Fused flash-style attention, fp32, online softmax.
// qT/kT: (B, N, 32); vT: (B, N, 256); h: (B, 256, N); h2 out: (B, 256, N).
// Block: 256 threads; TI=32 query rows; TJ=32 key tile.
// Thread roles:  score phase: (rg = tid>>5 -> rows rg*4..+3, jloc = tid&31)
//                PV phase:    same rows, channels {cx*4..+3, 128+cx*4..+3}
// ---------------------------------------------------------------------------
__global__ __launch_bounds__(256) void attn_fused(
    const float* __restrict__ qT, const float* __restrict__ kT,
    const float* __restrict__ vT, const float* __restrict__ h,
    const float* __restrict__ gamma_p, float* __restrict__ h2)
{
    const int b  = blockIdx.y;
    const int i0 = blockIdx.x * 32;
    const int tid = threadIdx.x;
    const int jloc = tid & 31;
    const int rg   = tid >> 5;
    const int cx   = tid & 31;

    __shared__ float qs[32][32];
    __shared__ float ks[32][33];   // +1 pad: conflict-free column reads
    __shared__ float ps[32][32];
    __shared__ float vs[32][256];

    const float* qTb = qT + (size_t)b * 4096 * 32;
    const float* kTb = kT + (size_t)b * 4096 * 32;
    const float* vTb = vT + (size_t)b * 4096 * 256;

    {   // load q tile (32x32)
        int idx = tid * 4;
        *(float4*)&qs[idx >> 5][idx & 31] =
            *(const float4*)&qTb[(size_t)(i0 + (idx >> 5)) * 32 + (idx & 31)];
    }

    float m[4], z[4], acc[4][8];
#pragma unroll
    for (int k = 0; k < 4; k++) {
        m[k] = -1e30f; z[k] = 0.f;
#pragma unroll
        for (int c = 0; c < 8; c++) acc[k][c] = 0.f;
    }
    __syncthreads();

    for (int jt = 0; jt < 4096; jt += 32) {
        // stage ks (32x32) and vs (32x256)
        {
            int idx = tid * 4;
            float4 t = *(const float4*)&kTb[(size_t)(jt + (idx >> 5)) * 32 + (idx & 31)];
            int r_ = idx >> 5, c_ = idx & 31;
            ks[r_][c_ + 0] = t.x; ks[r_][c_ + 1] = t.y;
            ks[r_][c_ + 2] = t.z; ks[r_][c_ + 3] = t.w;
#pragma unroll
            for (int it = 0; it < 8; it++) {
                int lin = it * 1024 + tid * 4;
                *(float4*)&vs[lin >> 8][lin & 255] =
                    *(const float4*)&vTb[(size_t)jt * 256 + lin];
            }
        }
        __syncthreads();

        // scores for column jloc, rows rg*4..+3
        float kr[32];
#pragma unroll
        for (int d = 0; d < 32; d++) kr[d] = ks[jloc][d];
        float sv[4];
#pragma unroll
        for (int k = 0; k < 4; k++) {
            int r = rg * 4 + k;
            float s = 0.f;
#pragma unroll
            for (int d = 0; d < 8; d++) {
                float4 qv = *(const float4*)&qs[r][d * 4];
                s = fmaf(qv.x, kr[d*4+0], s);
                s = fmaf(qv.y, kr[d*4+1], s);
                s = fmaf(qv.z, kr[d*4+2], s);
                s = fmaf(qv.w, kr[d*4+3], s);
            }
            sv[k] = s;
        }
        // online softmax update (reduce over the 32 jloc lanes of this rg group)
        float corr[4];
#pragma unroll
        for (int k = 0; k < 4; k++) {
            float tm = sv[k];
#pragma unroll
            for (int off = 16; off; off >>= 1) tm = fmaxf(tm, __shfl_xor(tm, off));
            float mn = fmaxf(m[k], tm);
            corr[k] = __expf(m[k] - mn);
            m[k] = mn;
            float p = __expf(sv[k] - mn);
            z[k] = z[k] * corr[k] + p;
            ps[rg * 4 + k][jloc] = p;
        }
        __syncthreads();

        // PV: rescale accumulators, then accumulate this tile
#pragma unroll
        for (int k = 0; k < 4; k++) {
            float c0 = corr[k];
#pragma unroll
            for (int c = 0; c < 8; c++) acc[k][c] *= c0;
        }
#pragma unroll 4
        for (int jj = 0; jj < 32; jj++) {
            float4 v0 = *(const float4*)&vs[jj][cx * 4];
            float4 v1 = *(const float4*)&vs[jj][128 + cx * 4];
#pragma unroll
            for (int k = 0; k < 4; k++) {
                float p = ps[rg * 4 + k][jj];
                acc[k][0] = fmaf(p, v0.x, acc[k][0]);
                acc[k][1] = fmaf(p, v0.y, acc[k][1]);
                acc[k][2] = fmaf(p, v0.z, acc[k][2]);
                acc[k][3] = fmaf(p, v0.w, acc[k][3]);
                acc[k][4] = fmaf(p, v1.x, acc[k][4]);
                acc[k][5] = fmaf(p, v1.y, acc[k][5]);
                acc[k][6] = fmaf(p, v1.z, acc[k][6]);
                acc[k][7] = fmaf(p, v1.w, acc[k][7]);
            }
        }
        __syncthreads();
    }

    // finalize Z across the 32-lane group
#pragma unroll
    for (int k = 0; k < 4; k++) {
        float zz = z[k];
#pragma unroll
        for (int off = 16; off; off >>= 1) zz += __shfl_xor(zz, off);
        z[k] = zz;
    }
    float gamma = gamma_p[0];
#pragma unroll
    for (int k = 0; k < 4; k++) {
        int r = i0 + rg * 4 + k;
        float invz = 1.f / z[k];
#pragma unroll
        for (int c = 0; c < 8; c++) {
            int ch = (c < 4) ? (cx * 4 + c) : (128 + cx * 4 + (c - 4));
            size_t off = ((size_t)(b * 256 + ch)) * 4096 + r;
            h2[off] = gamma * acc[k][c] * invz + h[off];
        }
    }
}

// elementwise BN+ReLU over (B,256,4096).  grid 4096 x 256, float4
__global__ __launch_bounds__(256) void bnrelu_flat(
    const float* __restrict__ h2, const float* __restrict__ scale,
    const float* __restrict__ shift, float* __restrict__ outp)
{
    size_t e = ((size_t)blockIdx.x * 256 + threadIdx.x) * 4;
    int c = (int)((e >> 12) & 255);
    float4 v = *(const float4*)&h2[e];
    float sc = scale[c], sh = shift[c];
    v.x = fmaxf(fmaf(sc, v.x, sh), 0.f);
    v.y = fmaxf(fmaf(sc, v.y, sh), 0.f);
    v.z = fmaxf(fmaf(sc, v.z, sh), 0.f);
    v.w = fmaxf(fmaf(sc, v.w, sh), 0.f);
    *(float4*)&outp[e] = v;
}

// final: out = relu(bn3(y3) + x).  grid 16384 x 256, float4
__global__ __launch_bounds__(256) void final_add_relu(
    const float* __restrict__ y3, const float* __restrict__ scale,
    const float* __restrict__ shift, const float* __restrict__ x,
    float* __restrict__ outp)
{
    size_t e = ((size_t)blockIdx.x * 256 + threadIdx.x) * 4;
    int c = (int)((e >> 14) & 255);
    float4 v = *(const float4*)&y3[e];
    float4 xv = *(const float4*)&x[e];
    float sc = scale[c], sh = shift[c];
    v.x = fmaxf(fmaf(sc, v.x, sh) + xv.x, 0.f);
    v.y = fmaxf(fmaf(sc, v.y, sh) + xv.y, 0.f);
    v.z = fmaxf(fmaf(sc, v.z, sh) + xv.z, 0.f);
    v.w = fmaxf(fmaf(sc, v.w, sh) + xv.w, 0.f);
    *(float4*)&outp[e] = v;
}

extern "C" void kernel_launch(void* const* d_in, const int* in_sizes, int n_in,
                              void* d_out, int out_size, void* d_ws, size_t ws_size,
                              hipStream_t stream)
{
    const float* x     = (const float*)d_in[0];
    const float* w1    = (const float*)d_in[1];
    const float* g1    = (const float*)d_in[2];
    const float* b1    = (const float*)d_in[3];
    const float* wq    = (const float*)d_in[4];
    const float* bq    = (const float*)d_in[5];
    const float* wk    = (const float*)d_in[6];
    const float* bk    = (const float*)d_in[7];
    const float* wv    = (const float*)d_in[8];
    const float* bv    = (const float*)d_in[9];
    const float* gamma = (const float*)d_in[10];
    const float* g2    = (const float*)d_in[11];
    const float* b2    = (const float*)d_in[12];
    const float* w3    = (const float*)d_in[13];
    const float* g3    = (const float*)d_in[14];
    const float* b3    = (const float*)d_in[15];
    float* out = (float*)d_out;

    float* ws = (float*)d_ws;
    float* y1 = ws;                    // 16,777,216 floats (reused as y3)
    float* hs = y1 + 16777216;         //  4,194,304 (h_small, reused as h2n)
    float* vT = hs + 4194304;          //  4,194,304
    float* h2 = vT + 4194304;          //  4,194,304
    float* qT = h2 + 4194304;          //    524,288
    float* kT = qT + 524288;           //    524,288
    float* st = kT + 524288;           //      7,680 stats
    // stats layout per stage: psum[1024], psumsq[1024], scale[256], shift[256]
    float* S1P = st;        float* S1Q = st + 1024; float* SC1 = st + 2048; float* SH1 = st + 2304;
    float* S2P = st + 2560; float* S2Q = st + 3584; float* SC2 = st + 4608; float* SH2 = st + 4864;
    float* S3P = st + 5120; float* S3Q = st + 6144; float* SC3 = st + 7168; float* SH3 = st + 7424;

    // net1: conv1 -> BN stats -> BN+ReLU+down
    conv_gemm<0,0><<<dim3(256, 4, 4), 256, 0, stream>>>(w1, x, nullptr, y1, 256, 256, 16384);
    channel_stats<<<dim3(256, 4), 256, 0, stream>>>(y1, S1P, S1Q, 16384);
    bn_finalize<<<1, 256, 0, stream>>>(S1P, S1Q, g1, b1, SC1, SH1, 1.f / 65536.f);
    bnrelu_down<<<dim3(16, 256, 4), 256, 0, stream>>>(y1, SC1, SH1, hs);

    // net2: q, k, v projections (transposed layouts), fused attention
    conv_gemm<0,1><<<dim3(64, 1, 4), 256, 0, stream>>>(wq, hs, bq, qT, 32, 256, 4096);
    conv_gemm<0,1><<<dim3(64, 1, 4), 256, 0, stream>>>(wk, hs, bk, kT, 32, 256, 4096);
    conv_gemm<0,1><<<dim3(64, 4, 4), 256, 0, stream>>>(wv, hs, bv, vT, 256, 256, 4096);
    attn_fused<<<dim3(128, 4), 256, 0, stream>>>(qT, kT, vT, hs, gamma, h2);

    // net2 tail: BN2 + ReLU
    channel_stats<<<dim3(256, 4), 256, 0, stream>>>(h2, S2P, S2Q, 4096);
    bn_finalize<<<1, 256, 0, stream>>>(S2P, S2Q, g2, b2, SC2, SH2, 1.f / 16384.f);
    bnrelu_flat<<<4096, 256, 0, stream>>>(h2, SC2, SH2, hs);

    // net3: conv3 with fused bilinear upsample of hs (64->128), then BN3 + residual + ReLU
    conv_gemm<1,0><<<dim3(256, 4, 4), 256, 0, stream>>>(w3, hs, nullptr, y1, 256, 256, 16384);
    channel_stats<<<dim3(256, 4), 256, 0, stream>>>(y1, S3P, S3Q, 16384);
    bn_finalize<<<1, 256, 0, stream>>>(S3P, S3Q, g3, b3, SC3, SH3, 1.f / 65536.f);
    final_add_relu<<<16384, 256, 0, stream>>>(y1, SC3, SH3, x, out);
}

// Round 3
// 496.023 us; speedup vs baseline: 2.6504x; 2.6504x over previous
//
#include <hip/hip_runtime.h>
#include <hip/hip_bf16.h>

// B=4, C=256, C8=32, H=128, W=128, H2=W2=64, N=4096, HW=16384
#define EPS_BN 1e-5f

typedef short bf16x8 __attribute__((ext_vector_type(8)));
typedef float f32x4 __attribute__((ext_vector_type(4)));

__device__ __forceinline__ unsigned short f2bf(float f) {
    __hip_bfloat16 h = __float2bfloat16(f);
    return __builtin_bit_cast(unsigned short, h);
}
__device__ __forceinline__ float bf2f(unsigned short u) {
    return __builtin_bit_cast(float, (unsigned)u << 16);
}

// ---------------------------------------------------------------------------
// bf16 MFMA GEMM: Y[b,o,p] = sum_c Wb[o,c] * Xt[b,p,c]  (K=256 fixed)
// BM in {128,32}; BN=128; BK=32; 256 threads (4 waves).
// Register staging (uint4 global load -> ds_write_b128), padded linear LDS:
// rows of 40 shorts (80B) -> 2-way worst bank aliasing (free, m136).
// MODE 1: bf16 p-major out (B,P,32) + bias  (q/k projections, O=32)
// MODE 2: bf16 c-major out (B,256,P) + optional bias (conv1/conv3/v)
// ---------------------------------------------------------------------------
template<int BM, int MODE>
__global__ __launch_bounds__(256) void gemm_mfma(
    const unsigned short* __restrict__ Wb,   // (O,256) bf16
    const unsigned short* __restrict__ Xt,   // (B,P,256) bf16
    const float* __restrict__ bias,
    unsigned short* __restrict__ Y,
    int P)
{
    const int tid = threadIdx.x;
    const int w = tid >> 6, l = tid & 63;
    const int b = blockIdx.z;
    const int p0 = blockIdx.x * 128;
    const int o0 = blockIdx.y * BM;
    const int lr = l & 15, lk = l >> 4;
    const int srow = l >> 2, sq = l & 3;     // staging: 16 rows x 4 chunks / wave

    __shared__ unsigned short Al[BM * 40];
    __shared__ unsigned short Bl[128 * 40];

    constexpr int WC = (BM == 128) ? 2 : 4;   // waves along p
    constexpr int MT = (BM == 128) ? 4 : 2;   // o-subtiles / wave
    constexpr int NT = (BM == 128) ? 4 : 2;   // p-subtiles / wave
    const int wr = w / WC, wc = w % WC;
    const int osub = wr * MT * 16, psub = wc * NT * 16;

    f32x4 acc[MT][NT];
#pragma unroll
    for (int i = 0; i < MT; i++)
#pragma unroll
        for (int j = 0; j < NT; j++) acc[i][j] = (f32x4){0.f, 0.f, 0.f, 0.f};

    const unsigned short* Xb = Xt + (size_t)b * P * 256;
    const int ar0 = w * 16, ar1 = w * 16 + 64;   // A rows staged by this wave
    const int br0 = w * 16, br1 = w * 16 + 64;   // B rows staged by this wave

    for (int k0 = 0; k0 < 256; k0 += 32) {
        // 1) global -> regs (no LDS touched; overlaps others' prior reads)
        uint4 vb0 = *(const uint4*)(Xb + (size_t)(p0 + br0 + srow) * 256 + k0 + sq * 8);
        uint4 vb1 = *(const uint4*)(Xb + (size_t)(p0 + br1 + srow) * 256 + k0 + sq * 8);
        uint4 va0, va1;
        if (ar0 < BM) va0 = *(const uint4*)(Wb + (size_t)(o0 + ar0 + srow) * 256 + k0 + sq * 8);
        if (ar1 < BM) va1 = *(const uint4*)(Wb + (size_t)(o0 + ar1 + srow) * 256 + k0 + sq * 8);
        __syncthreads();   // prior k-step's LDS reads complete
        // 2) regs -> LDS
        *(uint4*)&Bl[(br0 + srow) * 40 + sq * 8] = vb0;
        *(uint4*)&Bl[(br1 + srow) * 40 + sq * 8] = vb1;
        if (ar0 < BM) *(uint4*)&Al[(ar0 + srow) * 40 + sq * 8] = va0;
        if (ar1 < BM) *(uint4*)&Al[(ar1 + srow) * 40 + sq * 8] = va1;
        __syncthreads();   // staging visible
        // 3) fragments + MFMA
        bf16x8 af[MT], bfr[NT];
#pragma unroll
        for (int i = 0; i < MT; i++) {
            int row = osub + i * 16 + lr;
            af[i] = *(const bf16x8*)&Al[row * 40 + lk * 8];
        }
#pragma unroll
        for (int j = 0; j < NT; j++) {
            int row = psub + j * 16 + lr;
            bfr[j] = *(const bf16x8*)&Bl[row * 40 + lk * 8];
        }
#pragma unroll
        for (int i = 0; i < MT; i++)
#pragma unroll
            for (int j = 0; j < NT; j++)
                acc[i][j] = __builtin_amdgcn_mfma_f32_16x16x32_bf16(af[i], bfr[j], acc[i][j], 0, 0, 0);
    }

    // epilogue; C/D: col = lane&15 (p), row = (lane>>4)*4 + reg (o)
    if (MODE == 1) {
#pragma unroll
        for (int i = 0; i < MT; i++) {
            int ob = o0 + osub + i * 16 + lk * 4;
#pragma unroll
            for (int j = 0; j < NT; j++) {
                int p = p0 + psub + j * 16 + lr;
                ushort4 pk;
                pk.x = f2bf(acc[i][j][0] + bias[ob + 0]);
                pk.y = f2bf(acc[i][j][1] + bias[ob + 1]);
                pk.z = f2bf(acc[i][j][2] + bias[ob + 2]);
                pk.w = f2bf(acc[i][j][3] + bias[ob + 3]);
                *(ushort4*)&Y[((size_t)b * P + p) * 32 + ob] = pk;
            }
        }
    } else {
#pragma unroll
        for (int i = 0; i < MT; i++)
#pragma unroll
            for (int r = 0; r < 4; r++) {
                int o = o0 + osub + i * 16 + lk * 4 + r;
                float bs = bias ? bias[o] : 0.f;
#pragma unroll
                for (int j = 0; j < NT; j++) {
                    int p = p0 + psub + j * 16 + lr;
                    Y[((size_t)(b * 256 + o)) * P + p] = f2bf(acc[i][j][r] + bs);
                }
            }
    }
}

// ---------------------------------------------------------------------------
// LDS-tiled transpose + cvt: (B,256,P) f32 -> (B,P,256) bf16
// ---------------------------------------------------------------------------
__global__ __launch_bounds__(256) void transpose_cvt(
    const float* __restrict__ src, unsigned short* __restrict__ dst, int P)
{
    __shared__ float t[64][65];
    const int tid = threadIdx.x;
    const int p0 = blockIdx.x * 64, c0 = blockIdx.y * 64, b = blockIdx.z;
    const float* sb = src + ((size_t)b * 256 + c0) * P + p0;
#pragma unroll
    for (int i = 0; i < 16; i++) {
        int r = (tid >> 6) + 4 * i;   // c-local
        int c = tid & 63;             // p-local
        t[c][r] = sb[(size_t)r * P + c];
    }
    __syncthreads();
#pragma unroll
    for (int i = 0; i < 8; i++) {
        int pr = (tid >> 5) + 8 * i;
        int cc = (tid & 31) * 2;
        unsigned pk = ((unsigned)f2bf(t[pr][cc + 1]) << 16) | f2bf(t[pr][cc]);
        *(unsigned*)&dst[((size_t)b * P + p0 + pr) * 256 + c0 + cc] = pk;
    }
}

__global__ void cvt_weights(const float* __restrict__ w1, const float* __restrict__ wq,
                            const float* __restrict__ wk, const float* __restrict__ wv,
                            const float* __restrict__ w3,
                            unsigned short* o1, unsigned short* oq, unsigned short* ok,
                            unsigned short* ov, unsigned short* o3)
{
    int i = blockIdx.x * 256 + threadIdx.x;
    if (i < 65536) { o1[i] = f2bf(w1[i]); ov[i] = f2bf(wv[i]); o3[i] = f2bf(w3[i]); }
    if (i < 8192)  { oq[i] = f2bf(wq[i]); ok[i] = f2bf(wk[i]); }
}

// per-(channel,batch) partial sums over c-major bf16 (B,256,Pn)
__global__ __launch_bounds__(256) void channel_stats_bf16(
    const unsigned short* __restrict__ Y, float* __restrict__ psum,
    float* __restrict__ psumsq, int Pn)
{
    const int o = blockIdx.x, b = blockIdx.y;
    const unsigned short* p = Y + ((size_t)b * 256 + o) * Pn;
    float s = 0.f, s2 = 0.f;
    for (int i = threadIdx.x * 8; i < Pn; i += 2048) {
        uint4 v = *(const uint4*)&p[i];
        unsigned uu[4] = {v.x, v.y, v.z, v.w};
#pragma unroll
        for (int k = 0; k < 4; k++) {
            float a = __builtin_bit_cast(float, uu[k] << 16);
            float c = __builtin_bit_cast(float, uu[k] & 0xffff0000u);
            s += a + c; s2 += a * a + c * c;
        }
    }
#pragma unroll
    for (int off = 32; off; off >>= 1) {
        s  += __shfl_down(s, off);
        s2 += __shfl_down(s2, off);
    }
    __shared__ float ws1[4], ws2[4];
    int lane = threadIdx.x & 63, w = threadIdx.x >> 6;
    if (lane == 0) { ws1[w] = s; ws2[w] = s2; }
    __syncthreads();
    if (threadIdx.x == 0) {
        float ts = 0.f, ts2 = 0.f;
#pragma unroll
        for (int k = 0; k < 4; k++) { ts += ws1[k]; ts2 += ws2[k]; }
        psum[(size_t)b * 256 + o] = ts;
        psumsq[(size_t)b * 256 + o] = ts2;
    }
}

// per-channel partials over p-major f32 (B,4096,256); grid (32, B)
__global__ __launch_bounds__(256) void stats_pmajor(
    const float* __restrict__ Y, float* __restrict__ psum, float* __restrict__ psumsq)
{
    const int chunk = blockIdx.x, b = blockIdx.y, c = threadIdx.x;
    const float* base = Y + ((size_t)b * 4096 + chunk * 128) * 256 + c;
    float s = 0.f, s2 = 0.f;
    for (int i = 0; i < 128; i++) { float v = base[(size_t)i * 256]; s += v; s2 += v * v; }
    psum[((size_t)b * 32 + chunk) * 256 + c] = s;
    psumsq[((size_t)b * 32 + chunk) * 256 + c] = s2;
}

__global__ void bn_finalize(const float* __restrict__ psum, const float* __restrict__ psumsq,
                            const float* __restrict__ g, const float* __restrict__ bb,
                            float* __restrict__ scale, float* __restrict__ shift,
                            float invN, int NP)
{
    int o = threadIdx.x;
    float s = 0.f, s2 = 0.f;
    for (int k = 0; k < NP; k++) { s += psum[k * 256 + o]; s2 += psumsq[k * 256 + o]; }
    float mean = s * invN;
    float var  = s2 * invN - mean * mean;
    float r = rsqrtf(var + EPS_BN);
    float sc = g[o] * r;
    scale[o] = sc;
    shift[o] = bb[o] - mean * sc;
}

// antialiased bilinear 2x downsample taps (jax.image.resize)
__device__ __forceinline__ int dtaps(int u, int* j, float* w) {
    if (u == 0)  { j[0]=0;   j[1]=1;   j[2]=2;   w[0]=3.f/7.f; w[1]=3.f/7.f; w[2]=1.f/7.f; return 3; }
    if (u == 63) { j[0]=125; j[1]=126; j[2]=127; w[0]=1.f/7.f; w[1]=3.f/7.f; w[2]=3.f/7.f; return 3; }
    j[0]=2*u-1; j[1]=2*u; j[2]=2*u+1; j[3]=2*u+2;
    w[0]=0.125f; w[1]=0.375f; w[2]=0.375f; w[3]=0.125f; return 4;
}

// BN + ReLU + 128->64 downsample; y1 bf16 c-major in, hs f32 c-major out
__global__ __launch_bounds__(256) void bnrelu_down(
    const unsigned short* __restrict__ y1, const float* __restrict__ scale,
    const float* __restrict__ shift, float* __restrict__ h)
{
    int i = blockIdx.x * 256 + threadIdx.x;  // 0..4095 over 64x64
    int o = blockIdx.y, b = blockIdx.z;
    int y2 = i >> 6, x2 = i & 63;
    const unsigned short* base = y1 + ((size_t)(b * 256 + o)) * 16384;
    float sc = scale[o], sh = shift[o];
    int jy[4]; float wy[4]; int ny = dtaps(y2, jy, wy);
    int jx[4]; float wx[4]; int nx = dtaps(x2, jx, wx);
    float acc = 0.f;
    for (int a = 0; a < ny; a++) {
        const unsigned short* row = base + jy[a] * 128;
        for (int c = 0; c < nx; c++) {
            float v = fmaxf(fmaf(sc, bf2f(row[jx[c]]), sh), 0.f);
            acc += wy[a] * wx[c] * v;
        }
    }
    h[((size_t)(b * 256 + o)) * 4096 + i] = acc;
}

// ---------------------------------------------------------------------------
// bf16 MFMA flash attention. qT/kT (B,4096,32) bf16; vb (B,256,4096) bf16;
// hst (B,4096,256) bf16 residual; out h2t (B,4096,256) f32.
// 512 thr = 8 waves: (wr=w>>1 -> rows i0+wr*16, wc=w&1 -> ch wc*128).
// KV tile 64. Padded linear LDS: K rows 40 sh (80B), V/P rows 72 sh (144B).
// Register staging; online softmax with rescale-skip.
// ---------------------------------------------------------------------------
__global__ __launch_bounds__(512) void attn_mfma(
    const unsigned short* __restrict__ qT, const unsigned short* __restrict__ kT,
    const unsigned short* __restrict__ vb, const unsigned short* __restrict__ hst,
    const float* __restrict__ gamma_p, float* __restrict__ h2t)
{
    const int b = blockIdx.y;
    const int i0 = blockIdx.x * 64;
    const int tid = threadIdx.x;
    const int w = tid >> 6, l = tid & 63;
    const int wr = w >> 1, wc = w & 1;
    const int lr = l & 15, lk = l >> 4;

    __shared__ unsigned short Kl[64 * 40];        // 5.0 KB
    __shared__ unsigned short Vl[256 * 72];       // 36.0 KB
    __shared__ unsigned short Pl[8][16 * 72];     // 18.0 KB

    // Q fragment (A): row = i0+wr*16+lr, k = lk*8..+7
    bf16x8 qf = *(const bf16x8*)&qT[((size_t)b * 4096 + i0 + wr * 16 + lr) * 32 + lk * 8];

    f32x4 acc[8];
#pragma unroll
    for (int i = 0; i < 8; i++) acc[i] = (f32x4){0.f, 0.f, 0.f, 0.f};
    float m[4], zp[4];
#pragma unroll
    for (int r = 0; r < 4; r++) { m[r] = -1e30f; zp[r] = 0.f; }

    const unsigned short* kTb = kT + (size_t)b * 4096 * 32;
    const unsigned short* vbb = vb + (size_t)b * 256 * 4096;
    unsigned short* Pw = Pl[w];

    for (int j0 = 0; j0 < 4096; j0 += 64) {
        // 1) global -> regs
        uint4 kreg;
        if (w < 4)
            kreg = *(const uint4*)(kTb + (size_t)(j0 + w * 16 + (l >> 2)) * 32 + (l & 3) * 8);
        uint4 vreg[4];
#pragma unroll
        for (int it = 0; it < 4; it++)
            vreg[it] = *(const uint4*)(vbb + (size_t)(w * 32 + it * 8 + (l >> 3)) * 4096
                                       + j0 + (l & 7) * 8);
        __syncthreads();   // prior tile's LDS reads complete
        // 2) regs -> LDS (padded linear)
        if (w < 4)
            *(uint4*)&Kl[(w * 16 + (l >> 2)) * 40 + (l & 3) * 8] = kreg;
#pragma unroll
        for (int it = 0; it < 4; it++)
            *(uint4*)&Vl[(w * 32 + it * 8 + (l >> 3)) * 72 + (l & 7) * 8] = vreg[it];
        __syncthreads();

        // QK^T: 4 j-subtiles of 16
        f32x4 s[4];
#pragma unroll
        for (int jt = 0; jt < 4; jt++) {
            int j = jt * 16 + lr;
            bf16x8 kf = *(const bf16x8*)&Kl[j * 40 + lk * 8];
            s[jt] = __builtin_amdgcn_mfma_f32_16x16x32_bf16(qf, kf, (f32x4){0.f,0.f,0.f,0.f}, 0, 0, 0);
        }

        // online softmax (rows R = lk*4+r; reduce over 16-lane group lk)
        bool grew = false;
        float corr[4], pv[4][4];
#pragma unroll
        for (int r = 0; r < 4; r++) {
            float tm = fmaxf(fmaxf(s[0][r], s[1][r]), fmaxf(s[2][r], s[3][r]));
#pragma unroll
            for (int off = 1; off < 16; off <<= 1) tm = fmaxf(tm, __shfl_xor(tm, off));
            float mo = m[r];
            float mn = fmaxf(mo, tm);
            bool g = tm > mo;
            corr[r] = g ? __expf(mo - mn) : 1.f;
            grew |= g;
            m[r] = mn;
            float ps = 0.f;
#pragma unroll
            for (int jt = 0; jt < 4; jt++) {
                float p = __expf(s[jt][r] - mn);
                pv[jt][r] = p; ps += p;
            }
            zp[r] = zp[r] * corr[r] + ps;
        }
        if (__any(grew)) {
#pragma unroll
            for (int i = 0; i < 8; i++)
#pragma unroll
                for (int r = 0; r < 4; r++) acc[i][r] *= corr[r];
        }

        // P -> per-wave LDS (row R, 64 keys, padded to 72)
#pragma unroll
        for (int jt = 0; jt < 4; jt++) {
            int cc = lr + 16 * jt;
#pragma unroll
            for (int r = 0; r < 4; r++) {
                int R = lk * 4 + r;
                Pw[R * 72 + cc] = f2bf(pv[jt][r]);
            }
        }

        // PV: 2 k-chunks x 8 channel subtiles
#pragma unroll
        for (int kc = 0; kc < 2; kc++) {
            bf16x8 pa = *(const bf16x8*)&Pw[lr * 72 + (kc * 4 + lk) * 8];
#pragma unroll
            for (int ct = 0; ct < 8; ct++) {
                int ch = wc * 128 + ct * 16 + lr;
                bf16x8 vf = *(const bf16x8*)&Vl[ch * 72 + (kc * 4 + lk) * 8];
                acc[ct] = __builtin_amdgcn_mfma_f32_16x16x32_bf16(pa, vf, acc[ct], 0, 0, 0);
            }
        }
    }

    float gamma = gamma_p[0];
    float z[4];
#pragma unroll
    for (int r = 0; r < 4; r++) {
        float zz = zp[r];
#pragma unroll
        for (int off = 1; off < 16; off <<= 1) zz += __shfl_xor(zz, off);
        z[r] = 1.f / zz;
    }
#pragma unroll
    for (int ct = 0; ct < 8; ct++) {
        int ch = wc * 128 + ct * 16 + lr;
#pragma unroll
        for (int r = 0; r < 4; r++) {
            size_t off = ((size_t)b * 4096 + i0 + wr * 16 + lk * 4 + r) * 256 + ch;
            h2t[off] = gamma * acc[ct][r] * z[r] + bf2f(hst[off]);
        }
    }
}

// BN2+ReLU fused with bilinear 64->128 upsample; p-major in/out
__global__ __launch_bounds__(256) void upsample_bnrelu(
    const float* __restrict__ h2t, const float* __restrict__ scale,
    const float* __restrict__ shift, unsigned short* __restrict__ upn)
{
    const int p = blockIdx.x, b = blockIdx.y, c = threadIdx.x;
    int y = p >> 7, x = p & 127;
    float fy = 0.5f * y - 0.25f, fx = 0.5f * x - 0.25f;
    float fiy = floorf(fy), fix = floorf(fx);
    float wy = fy - fiy, wx = fx - fix;
    int iy = (int)fiy, ix = (int)fix;
    int iy0 = max(iy, 0), iy1 = min(iy + 1, 63);
    int ix0 = max(ix, 0), ix1 = min(ix + 1, 63);
    const float* basep = h2t + ((size_t)b * 4096) * 256 + c;
    float sc = scale[c], sh = shift[c];
    float v00 = fmaxf(fmaf(sc, basep[(size_t)(iy0 * 64 + ix0) * 256], sh), 0.f);
    float v01 = fmaxf(fmaf(sc, basep[(size_t)(iy0 * 64 + ix1) * 256], sh), 0.f);
    float v10 = fmaxf(fmaf(sc, basep[(size_t)(iy1 * 64 + ix0) * 256], sh), 0.f);
    float v11 = fmaxf(fmaf(sc, basep[(size_t)(iy1 * 64 + ix1) * 256], sh), 0.f);
    float r0 = (1.f - wy) * ((1.f - wx) * v00 + wx * v01)
             + wy * ((1.f - wx) * v10 + wx * v11);
    upn[((size_t)b * 16384 + p) * 256 + c] = f2bf(r0);
}

// out = relu(bn3(y3) + x); y3 bf16 c-major
__global__ __launch_bounds__(256) void final_add_relu(
    const unsigned short* __restrict__ y3, const float* __restrict__ scale,
    const float* __restrict__ shift, const float* __restrict__ x,
    float* __restrict__ outp)
{
    size_t e = ((size_t)blockIdx.x * 256 + threadIdx.x) * 4;
    int c = (int)((e >> 14) & 255);
    ushort4 yv = *(const ushort4*)&y3[e];
    float4 xv = *(const float4*)&x[e];
    float sc = scale[c], sh = shift[c];
    float4 o;
    o.x = fmaxf(fmaf(sc, bf2f(yv.x), sh) + xv.x, 0.f);
    o.y = fmaxf(fmaf(sc, bf2f(yv.y), sh) + xv.y, 0.f);
    o.z = fmaxf(fmaf(sc, bf2f(yv.z), sh) + xv.z, 0.f);
    o.w = fmaxf(fmaf(sc, bf2f(yv.w), sh) + xv.w, 0.f);
    *(float4*)&outp[e] = o;
}

extern "C" void kernel_launch(void* const* d_in, const int* in_sizes, int n_in,
                              void* d_out, int out_size, void* d_ws, size_t ws_size,
                              hipStream_t stream)
{
    const float* x     = (const float*)d_in[0];
    const float* w1    = (const float*)d_in[1];
    const float* g1    = (const float*)d_in[2];
    const float* b1    = (const float*)d_in[3];
    const float* wq    = (const float*)d_in[4];
    const float* bq    = (const float*)d_in[5];
    const float* wk    = (const float*)d_in[6];
    const float* bk    = (const float*)d_in[7];
    const float* wv    = (const float*)d_in[8];
    const float* bv    = (const float*)d_in[9];
    const float* gamma = (const float*)d_in[10];
    const float* g2    = (const float*)d_in[11];
    const float* b2    = (const float*)d_in[12];
    const float* w3    = (const float*)d_in[13];
    const float* g3    = (const float*)d_in[14];
    const float* b3    = (const float*)d_in[15];
    float* out = (float*)d_out;

    char* wsb = (char*)d_ws;
    unsigned short* y1b = (unsigned short*)(wsb);                      // 32MB (later y3b)
    unsigned short* xt  = (unsigned short*)(wsb + (size_t)(32 << 20)); // 32MB (later upn)
    float* hs  = (float*)(wsb + (size_t)(64 << 20));                   // 16MB (later h2t)
    unsigned short* hst = (unsigned short*)(wsb + (size_t)(80 << 20)); // 8MB
    unsigned short* vbb = (unsigned short*)(wsb + (size_t)(88 << 20)); // 8MB
    unsigned short* qTb = (unsigned short*)(wsb + (size_t)(96 << 20)); // 1MB
    unsigned short* kTb = (unsigned short*)(wsb + (size_t)(97 << 20)); // 1MB
    unsigned short* w1b = (unsigned short*)(wsb + (size_t)(98 << 20));
    unsigned short* wvb = w1b + 65536;
    unsigned short* w3b = wvb + 65536;
    unsigned short* wqb = w3b + 65536;
    unsigned short* wkb = wqb + 8192;
    float* psum   = (float*)(wsb + (size_t)(99 << 20));                // 128KB
    float* psumsq = psum + 32768;                                      // 128KB
    float* sc1 = psumsq + 32768; float* sh1 = sc1 + 256;
    float* sc2 = sh1 + 256;      float* sh2 = sc2 + 256;
    float* sc3 = sh2 + 256;      float* sh3 = sc3 + 256;
    unsigned short* y3b = y1b;
    unsigned short* upn = xt;
    float* h2t = hs;

    cvt_weights<<<256, 256, 0, stream>>>(w1, wq, wk, wv, w3, w1b, wqb, wkb, wvb, w3b);
    transpose_cvt<<<dim3(256, 4, 4), 256, 0, stream>>>(x, xt, 16384);

    // net1: conv1 (MFMA) -> BN stats -> BN+ReLU+down
    gemm_mfma<128, 2><<<dim3(128, 2, 4), 256, 0, stream>>>(w1b, xt, nullptr, y1b, 16384);
    channel_stats_bf16<<<dim3(256, 4), 256, 0, stream>>>(y1b, psum, psumsq, 16384);
    bn_finalize<<<1, 256, 0, stream>>>(psum, psumsq, g1, b1, sc1, sh1, 1.f / 65536.f, 4);
    bnrelu_down<<<dim3(16, 256, 4), 256, 0, stream>>>(y1b, sc1, sh1, hs);
    transpose_cvt<<<dim3(64, 4, 4), 256, 0, stream>>>(hs, hst, 4096);

    // net2: q,k,v projections + fused MFMA attention
    gemm_mfma<32, 1><<<dim3(32, 1, 4), 256, 0, stream>>>(wqb, hst, bq, qTb, 4096);
    gemm_mfma<32, 1><<<dim3(32, 1, 4), 256, 0, stream>>>(wkb, hst, bk, kTb, 4096);
    gemm_mfma<128, 2><<<dim3(32, 2, 4), 256, 0, stream>>>(wvb, hst, bv, vbb, 4096);
    attn_mfma<<<dim3(64, 4), 512, 0, stream>>>(qTb, kTb, vbb, hst, gamma, h2t);

    // net2 tail: BN2 + ReLU fused into upsample
    stats_pmajor<<<dim3(32, 4), 256, 0, stream>>>(h2t, psum, psumsq);
    bn_finalize<<<1, 256, 0, stream>>>(psum, psumsq, g2, b2, sc2, sh2, 1.f / 16384.f, 128);
    upsample_bnrelu<<<dim3(16384, 4), 256, 0, stream>>>(h2t, sc2, sh2, upn);

    // net3: conv3 (MFMA) -> BN3 + residual + ReLU
    gemm_mfma<128, 2><<<dim3(128, 2, 4), 256, 0, stream>>>(w3b, upn, nullptr, y3b, 16384);
    channel_stats_bf16<<<dim3(256, 4), 256, 0, stream>>>(y3b, psum, psumsq, 16384);
    bn_finalize<<<1, 256, 0, stream>>>(psum, psumsq, g3, b3, sc3, sh3, 1.f / 65536.f, 4);
    final_add_relu<<<16384, 256, 0, stream>>>(y3b, sc3, sh3, x, out);
}

// Round 4
// 479.103 us; speedup vs baseline: 2.7440x; 1.0353x over previous
//
#include <hip/hip_runtime.h>
#include <hip/hip_bf16.h>

// B=4, C=256, C8=32, H=128, W=128, H2=W2=64, N=4096, HW=16384
#define EPS_BN 1e-5f

typedef short bf16x8 __attribute__((ext_vector_type(8)));
typedef float f32x4 __attribute__((ext_vector_type(4)));

__device__ __forceinline__ unsigned short f2bf(float f) {
    __hip_bfloat16 h = __float2bfloat16(f);
    return __builtin_bit_cast(unsigned short, h);
}
__device__ __forceinline__ float bf2f(unsigned short u) {
    return __builtin_bit_cast(float, (unsigned)u << 16);
}

// ---------------------------------------------------------------------------
// bf16 MFMA GEMM: Y[b,o,p] = sum_c Wb[o,c] * Xt[b,p,c]  (K=256 fixed)
// BM in {128,32}; BN=128; BK=32; 256 threads (4 waves).
// 2-phase pipeline: prologue-load k0=0; per step: bar, ds_write, bar,
// prefetch k0+32 (global->regs, in flight during compute), frags+MFMA.
// MODE 1: bf16 p-major out (B,P,32) + bias  (q/k projections, O=32)
// MODE 2: bf16 c-major out (B,256,P) + optional bias (conv1/conv3/v)
// ---------------------------------------------------------------------------
template<int BM, int MODE>
__global__ __launch_bounds__(256) void gemm_mfma(
    const unsigned short* __restrict__ Wb,   // (O,256) bf16
    const unsigned short* __restrict__ Xt,   // (B,P,256) bf16
    const float* __restrict__ bias,
    unsigned short* __restrict__ Y,
    int P)
{
    const int tid = threadIdx.x;
    const int w = tid >> 6, l = tid & 63;
    const int b = blockIdx.z;
    const int p0 = blockIdx.x * 128;
    const int o0 = blockIdx.y * BM;
    const int lr = l & 15, lk = l >> 4;
    const int srow = l >> 2, sq = l & 3;     // staging: 16 rows x 4 chunks / wave

    __shared__ unsigned short Al[BM * 40];
    __shared__ unsigned short Bl[128 * 40];

    constexpr int WC = (BM == 128) ? 2 : 4;   // waves along p
    constexpr int MT = (BM == 128) ? 4 : 2;   // o-subtiles / wave
    constexpr int NT = (BM == 128) ? 4 : 2;   // p-subtiles / wave
    const int wr = w / WC, wc = w % WC;
    const int osub = wr * MT * 16, psub = wc * NT * 16;

    f32x4 acc[MT][NT];
#pragma unroll
    for (int i = 0; i < MT; i++)
#pragma unroll
        for (int j = 0; j < NT; j++) acc[i][j] = (f32x4){0.f, 0.f, 0.f, 0.f};

    const unsigned short* Xb = Xt + (size_t)b * P * 256;
    const int ar0 = w * 16, ar1 = w * 16 + 64;   // A rows staged by this wave
    const int br0 = w * 16, br1 = w * 16 + 64;   // B rows staged by this wave

    uint4 vb0, vb1, va0, va1;
#define G_LOADS(K0)                                                                        \
    vb0 = *(const uint4*)(Xb + (size_t)(p0 + br0 + srow) * 256 + (K0) + sq * 8);           \
    vb1 = *(const uint4*)(Xb + (size_t)(p0 + br1 + srow) * 256 + (K0) + sq * 8);           \
    if (ar0 < BM) va0 = *(const uint4*)(Wb + (size_t)(o0 + ar0 + srow) * 256 + (K0) + sq * 8); \
    if (ar1 < BM) va1 = *(const uint4*)(Wb + (size_t)(o0 + ar1 + srow) * 256 + (K0) + sq * 8);

    G_LOADS(0)
    for (int k0 = 0; k0 < 256; k0 += 32) {
        __syncthreads();   // prior k-step's LDS reads complete
        *(uint4*)&Bl[(br0 + srow) * 40 + sq * 8] = vb0;
        *(uint4*)&Bl[(br1 + srow) * 40 + sq * 8] = vb1;
        if (ar0 < BM) *(uint4*)&Al[(ar0 + srow) * 40 + sq * 8] = va0;
        if (ar1 < BM) *(uint4*)&Al[(ar1 + srow) * 40 + sq * 8] = va1;
        __syncthreads();   // staging visible
        if (k0 < 224) { G_LOADS(k0 + 32) }   // prefetch next, in flight during MFMA
        bf16x8 af[MT], bfr[NT];
#pragma unroll
        for (int i = 0; i < MT; i++) {
            int row = osub + i * 16 + lr;
            af[i] = *(const bf16x8*)&Al[row * 40 + lk * 8];
        }
#pragma unroll
        for (int j = 0; j < NT; j++) {
            int row = psub + j * 16 + lr;
            bfr[j] = *(const bf16x8*)&Bl[row * 40 + lk * 8];
        }
#pragma unroll
        for (int i = 0; i < MT; i++)
#pragma unroll
            for (int j = 0; j < NT; j++)
                acc[i][j] = __builtin_amdgcn_mfma_f32_16x16x32_bf16(af[i], bfr[j], acc[i][j], 0, 0, 0);
    }
#undef G_LOADS

    // epilogue; C/D: col = lane&15 (p), row = (lane>>4)*4 + reg (o)
    if (MODE == 1) {
#pragma unroll
        for (int i = 0; i < MT; i++) {
            int ob = o0 + osub + i * 16 + lk * 4;
#pragma unroll
            for (int j = 0; j < NT; j++) {
                int p = p0 + psub + j * 16 + lr;
                ushort4 pk;
                pk.x = f2bf(acc[i][j][0] + bias[ob + 0]);
                pk.y = f2bf(acc[i][j][1] + bias[ob + 1]);
                pk.z = f2bf(acc[i][j][2] + bias[ob + 2]);
                pk.w = f2bf(acc[i][j][3] + bias[ob + 3]);
                *(ushort4*)&Y[((size_t)b * P + p) * 32 + ob] = pk;
            }
        }
    } else {
#pragma unroll
        for (int i = 0; i < MT; i++)
#pragma unroll
            for (int r = 0; r < 4; r++) {
                int o = o0 + osub + i * 16 + lk * 4 + r;
                float bs = bias ? bias[o] : 0.f;
#pragma unroll
                for (int j = 0; j < NT; j++) {
                    int p = p0 + psub + j * 16 + lr;
                    Y[((size_t)(b * 256 + o)) * P + p] = f2bf(acc[i][j][r] + bs);
                }
            }
    }
}

// ---------------------------------------------------------------------------
// LDS-tiled transpose + cvt: (B,256,P) f32 -> (B,P,256) bf16
// ---------------------------------------------------------------------------
__global__ __launch_bounds__(256) void transpose_cvt(
    const float* __restrict__ src, unsigned short* __restrict__ dst, int P)
{
    __shared__ float t[64][65];
    const int tid = threadIdx.x;
    const int p0 = blockIdx.x * 64, c0 = blockIdx.y * 64, b = blockIdx.z;
    const float* sb = src + ((size_t)b * 256 + c0) * P + p0;
#pragma unroll
    for (int i = 0; i < 16; i++) {
        int r = (tid >> 6) + 4 * i;   // c-local
        int c = tid & 63;             // p-local
        t[c][r] = sb[(size_t)r * P + c];
    }
    __syncthreads();
#pragma unroll
    for (int i = 0; i < 8; i++) {
        int pr = (tid >> 5) + 8 * i;
        int cc = (tid & 31) * 2;
        unsigned pk = ((unsigned)f2bf(t[pr][cc + 1]) << 16) | f2bf(t[pr][cc]);
        *(unsigned*)&dst[((size_t)b * P + p0 + pr) * 256 + c0 + cc] = pk;
    }
}

__global__ void cvt_weights(const float* __restrict__ w1, const float* __restrict__ wq,
                            const float* __restrict__ wk, const float* __restrict__ wv,
                            const float* __restrict__ w3,
                            unsigned short* o1, unsigned short* oq, unsigned short* ok,
                            unsigned short* ov, unsigned short* o3)
{
    int i = blockIdx.x * 256 + threadIdx.x;
    if (i < 65536) { o1[i] = f2bf(w1[i]); ov[i] = f2bf(wv[i]); o3[i] = f2bf(w3[i]); }
    if (i < 8192)  { oq[i] = f2bf(wq[i]); ok[i] = f2bf(wk[i]); }
}

// per-(channel,batch) partial sums over c-major bf16 (B,256,Pn)
__global__ __launch_bounds__(256) void channel_stats_bf16(
    const unsigned short* __restrict__ Y, float* __restrict__ psum,
    float* __restrict__ psumsq, int Pn)
{
    const int o = blockIdx.x, b = blockIdx.y;
    const unsigned short* p = Y + ((size_t)b * 256 + o) * Pn;
    float s = 0.f, s2 = 0.f;
    for (int i = threadIdx.x * 8; i < Pn; i += 2048) {
        uint4 v = *(const uint4*)&p[i];
        unsigned uu[4] = {v.x, v.y, v.z, v.w};
#pragma unroll
        for (int k = 0; k < 4; k++) {
            float a = __builtin_bit_cast(float, uu[k] << 16);
            float c = __builtin_bit_cast(float, uu[k] & 0xffff0000u);
            s += a + c; s2 += a * a + c * c;
        }
    }
#pragma unroll
    for (int off = 32; off; off >>= 1) {
        s  += __shfl_down(s, off);
        s2 += __shfl_down(s2, off);
    }
    __shared__ float ws1[4], ws2[4];
    int lane = threadIdx.x & 63, w = threadIdx.x >> 6;
    if (lane == 0) { ws1[w] = s; ws2[w] = s2; }
    __syncthreads();
    if (threadIdx.x == 0) {
        float ts = 0.f, ts2 = 0.f;
#pragma unroll
        for (int k = 0; k < 4; k++) { ts += ws1[k]; ts2 += ws2[k]; }
        psum[(size_t)b * 256 + o] = ts;
        psumsq[(size_t)b * 256 + o] = ts2;
    }
}

// per-channel partials over p-major f32 (B,4096,256); grid (32, B)
__global__ __launch_bounds__(256) void stats_pmajor(
    const float* __restrict__ Y, float* __restrict__ psum, float* __restrict__ psumsq)
{
    const int chunk = blockIdx.x, b = blockIdx.y, c = threadIdx.x;
    const float* base = Y + ((size_t)b * 4096 + chunk * 128) * 256 + c;
    float s = 0.f, s2 = 0.f;
    for (int i = 0; i < 128; i++) { float v = base[(size_t)i * 256]; s += v; s2 += v * v; }
    psum[((size_t)b * 32 + chunk) * 256 + c] = s;
    psumsq[((size_t)b * 32 + chunk) * 256 + c] = s2;
}

__global__ void bn_finalize(const float* __restrict__ psum, const float* __restrict__ psumsq,
                            const float* __restrict__ g, const float* __restrict__ bb,
                            float* __restrict__ scale, float* __restrict__ shift,
                            float invN, int NP)
{
    int o = threadIdx.x;
    float s = 0.f, s2 = 0.f;
    for (int k = 0; k < NP; k++) { s += psum[k * 256 + o]; s2 += psumsq[k * 256 + o]; }
    float mean = s * invN;
    float var  = s2 * invN - mean * mean;
    float r = rsqrtf(var + EPS_BN);
    float sc = g[o] * r;
    scale[o] = sc;
    shift[o] = bb[o] - mean * sc;
}

// antialiased bilinear 2x downsample taps (jax.image.resize)
__device__ __forceinline__ int dtaps(int u, int* j, float* w) {
    if (u == 0)  { j[0]=0;   j[1]=1;   j[2]=2;   w[0]=3.f/7.f; w[1]=3.f/7.f; w[2]=1.f/7.f; return 3; }
    if (u == 63) { j[0]=125; j[1]=126; j[2]=127; w[0]=1.f/7.f; w[1]=3.f/7.f; w[2]=3.f/7.f; return 3; }
    j[0]=2*u-1; j[1]=2*u; j[2]=2*u+1; j[3]=2*u+2;
    w[0]=0.125f; w[1]=0.375f; w[2]=0.375f; w[3]=0.125f; return 4;
}

// BN + ReLU + 128->64 downsample; y1 bf16 c-major in, hs f32 c-major out
__global__ __launch_bounds__(256) void bnrelu_down(
    const unsigned short* __restrict__ y1, const float* __restrict__ scale,
    const float* __restrict__ shift, float* __restrict__ h)
{
    int i = blockIdx.x * 256 + threadIdx.x;  // 0..4095 over 64x64
    int o = blockIdx.y, b = blockIdx.z;
    int y2 = i >> 6, x2 = i & 63;
    const unsigned short* base = y1 + ((size_t)(b * 256 + o)) * 16384;
    float sc = scale[o], sh = shift[o];
    int jy[4]; float wy[4]; int ny = dtaps(y2, jy, wy);
    int jx[4]; float wx[4]; int nx = dtaps(x2, jx, wx);
    float acc = 0.f;
    for (int a = 0; a < ny; a++) {
        const unsigned short* row = base + jy[a] * 128;
        for (int c = 0; c < nx; c++) {
            float v = fmaxf(fmaf(sc, bf2f(row[jx[c]]), sh), 0.f);
            acc += wy[a] * wx[c] * v;
        }
    }
    h[((size_t)(b * 256 + o)) * 4096 + i] = acc;
}

// ---------------------------------------------------------------------------
// bf16 MFMA flash attention. qT/kT (B,4096,32) bf16; vb (B,256,4096) bf16;
// hst (B,4096,256) bf16 residual; out h2t (B,4096,256) f32.
// 512 thr = 8 waves: (wr=w>>1 -> rows i0+wr*16, wc=w&1 -> ch wc*128).
// KV tile 64.  LDS: K rows 40sh (80B, 2-way free); V rows 64sh unpadded with
// 16B-slot XOR swizzle (slot ^= ch&7, applied on write AND read -> each
// 8-lane phase covers all 32 banks); P per-wave rows 68sh (conflict-free).
// 2-phase pipeline: prefetch next tile's K/V into regs during compute.
// ---------------------------------------------------------------------------
__global__ __launch_bounds__(512) void attn_mfma(
    const unsigned short* __restrict__ qT, const unsigned short* __restrict__ kT,
    const unsigned short* __restrict__ vb, const unsigned short* __restrict__ hst,
    const float* __restrict__ gamma_p, float* __restrict__ h2t)
{
    const int b = blockIdx.y;
    const int i0 = blockIdx.x * 64;
    const int tid = threadIdx.x;
    const int w = tid >> 6, l = tid & 63;
    const int wr = w >> 1, wc = w & 1;
    const int lr = l & 15, lk = l >> 4;

    __shared__ unsigned short Kl[64 * 40];        // 5.0 KB
    __shared__ unsigned short Vl[256 * 64];       // 32.0 KB (swizzled)
    __shared__ unsigned short Pl[8][16 * 68];     // 17.0 KB

    // Q fragment (A): row = i0+wr*16+lr, k = lk*8..+7
    bf16x8 qf = *(const bf16x8*)&qT[((size_t)b * 4096 + i0 + wr * 16 + lr) * 32 + lk * 8];

    f32x4 acc[8];
#pragma unroll
    for (int i = 0; i < 8; i++) acc[i] = (f32x4){0.f, 0.f, 0.f, 0.f};
    float m[4], zp[4];
#pragma unroll
    for (int r = 0; r < 4; r++) { m[r] = -1e30f; zp[r] = 0.f; }

    const unsigned short* kTb = kT + (size_t)b * 4096 * 32;
    const unsigned short* vbb = vb + (size_t)b * 256 * 4096;
    unsigned short* Pw = Pl[w];

    uint4 kreg, vreg[4];
#define LOAD_TILE(J0)                                                                      \
    if (w < 4)                                                                             \
        kreg = *(const uint4*)(kTb + (size_t)((J0) + w * 16 + (l >> 2)) * 32 + (l & 3) * 8); \
    _Pragma("unroll")                                                                      \
    for (int it = 0; it < 4; it++)                                                         \
        vreg[it] = *(const uint4*)(vbb + (size_t)(w * 32 + it * 8 + (l >> 3)) * 4096       \
                                   + (J0) + (l & 7) * 8);

    LOAD_TILE(0)
    for (int t = 0; t < 64; t++) {
        const int j0 = t * 64;
        __syncthreads();   // prior tile's LDS reads complete
        // staged regs -> LDS
        if (w < 4)
            *(uint4*)&Kl[(w * 16 + (l >> 2)) * 40 + (l & 3) * 8] = kreg;
#pragma unroll
        for (int it = 0; it < 4; it++) {
            int ch = w * 32 + it * 8 + (l >> 3);
            *(uint4*)&Vl[ch * 64 + (((l & 7) ^ (ch & 7)) * 8)] = vreg[it];
        }
        __syncthreads();
        if (t < 63) { LOAD_TILE(j0 + 64) }   // prefetch next tile during compute

        // QK^T: 4 j-subtiles of 16
        f32x4 s[4];
#pragma unroll
        for (int jt = 0; jt < 4; jt++) {
            int j = jt * 16 + lr;
            bf16x8 kf = *(const bf16x8*)&Kl[j * 40 + lk * 8];
            s[jt] = __builtin_amdgcn_mfma_f32_16x16x32_bf16(qf, kf, (f32x4){0.f,0.f,0.f,0.f}, 0, 0, 0);
        }

        // online softmax (rows R = lk*4+r; reduce over 16-lane group lk)
        bool grew = false;
        float corr[4], pv[4][4];
#pragma unroll
        for (int r = 0; r < 4; r++) {
            float tm = fmaxf(fmaxf(s[0][r], s[1][r]), fmaxf(s[2][r], s[3][r]));
#pragma unroll
            for (int off = 1; off < 16; off <<= 1) tm = fmaxf(tm, __shfl_xor(tm, off));
            float mo = m[r];
            float mn = fmaxf(mo, tm);
            bool g = tm > mo;
            corr[r] = g ? __expf(mo - mn) : 1.f;
            grew |= g;
            m[r] = mn;
            float ps = 0.f;
#pragma unroll
            for (int jt = 0; jt < 4; jt++) {
                float p = __expf(s[jt][r] - mn);
                pv[jt][r] = p; ps += p;
            }
            zp[r] = zp[r] * corr[r] + ps;
        }
        if (__any(grew)) {
#pragma unroll
            for (int i = 0; i < 8; i++)
#pragma unroll
                for (int r = 0; r < 4; r++) acc[i][r] *= corr[r];
        }

        // P -> per-wave LDS (row R, 64 keys, padded to 68)
#pragma unroll
        for (int jt = 0; jt < 4; jt++) {
            int cc = lr + 16 * jt;
#pragma unroll
            for (int r = 0; r < 4; r++) {
                int R = lk * 4 + r;
                Pw[R * 68 + cc] = f2bf(pv[jt][r]);
            }
        }

        // PV: 2 k-chunks x 8 channel subtiles (V read with matching swizzle)
#pragma unroll
        for (int kc = 0; kc < 2; kc++) {
            bf16x8 pa = *(const bf16x8*)&Pw[lr * 68 + (kc * 4 + lk) * 8];
#pragma unroll
            for (int ct = 0; ct < 8; ct++) {
                int ch = wc * 128 + ct * 16 + lr;
                bf16x8 vf = *(const bf16x8*)&Vl[ch * 64 + (((kc * 4 + lk) ^ (ch & 7)) * 8)];
                acc[ct] = __builtin_amdgcn_mfma_f32_16x16x32_bf16(pa, vf, acc[ct], 0, 0, 0);
            }
        }
    }
#undef LOAD_TILE

    float gamma = gamma_p[0];
    float z[4];
#pragma unroll
    for (int r = 0; r < 4; r++) {
        float zz = zp[r];
#pragma unroll
        for (int off = 1; off < 16; off <<= 1) zz += __shfl_xor(zz, off);
        z[r] = 1.f / zz;
    }
#pragma unroll
    for (int ct = 0; ct < 8; ct++) {
        int ch = wc * 128 + ct * 16 + lr;
#pragma unroll
        for (int r = 0; r < 4; r++) {
            size_t off = ((size_t)b * 4096 + i0 + wr * 16 + lk * 4 + r) * 256 + ch;
            h2t[off] = gamma * acc[ct][r] * z[r] + bf2f(hst[off]);
        }
    }
}

// BN2+ReLU fused with bilinear 64->128 upsample; p-major in/out
__global__ __launch_bounds__(256) void upsample_bnrelu(
    const float* __restrict__ h2t, const float* __restrict__ scale,
    const float* __restrict__ shift, unsigned short* __restrict__ upn)
{
    const int p = blockIdx.x, b = blockIdx.y, c = threadIdx.x;
    int y = p >> 7, x = p & 127;
    float fy = 0.5f * y - 0.25f, fx = 0.5f * x - 0.25f;
    float fiy = floorf(fy), fix = floorf(fx);
    float wy = fy - fiy, wx = fx - fix;
    int iy = (int)fiy, ix = (int)fix;
    int iy0 = max(iy, 0), iy1 = min(iy + 1, 63);
    int ix0 = max(ix, 0), ix1 = min(ix + 1, 63);
    const float* basep = h2t + ((size_t)b * 4096) * 256 + c;
    float sc = scale[c], sh = shift[c];
    float v00 = fmaxf(fmaf(sc, basep[(size_t)(iy0 * 64 + ix0) * 256], sh), 0.f);
    float v01 = fmaxf(fmaf(sc, basep[(size_t)(iy0 * 64 + ix1) * 256], sh), 0.f);
    float v10 = fmaxf(fmaf(sc, basep[(size_t)(iy1 * 64 + ix0) * 256], sh), 0.f);
    float v11 = fmaxf(fmaf(sc, basep[(size_t)(iy1 * 64 + ix1) * 256], sh), 0.f);
    float r0 = (1.f - wy) * ((1.f - wx) * v00 + wx * v01)
             + wy * ((1.f - wx) * v10 + wx * v11);
    upn[((size_t)b * 16384 + p) * 256 + c] = f2bf(r0);
}

// out = relu(bn3(y3) + x); y3 bf16 c-major
__global__ __launch_bounds__(256) void final_add_relu(
    const unsigned short* __restrict__ y3, const float* __restrict__ scale,
    const float* __restrict__ shift, const float* __restrict__ x,
    float* __restrict__ outp)
{
    size_t e = ((size_t)blockIdx.x * 256 + threadIdx.x) * 4;
    int c = (int)((e >> 14) & 255);
    ushort4 yv = *(const ushort4*)&y3[e];
    float4 xv = *(const float4*)&x[e];
    float sc = scale[c], sh = shift[c];
    float4 o;
    o.x = fmaxf(fmaf(sc, bf2f(yv.x), sh) + xv.x, 0.f);
    o.y = fmaxf(fmaf(sc, bf2f(yv.y), sh) + xv.y, 0.f);
    o.z = fmaxf(fmaf(sc, bf2f(yv.z), sh) + xv.z, 0.f);
    o.w = fmaxf(fmaf(sc, bf2f(yv.w), sh) + xv.w, 0.f);
    *(float4*)&outp[e] = o;
}

extern "C" void kernel_launch(void* const* d_in, const int* in_sizes, int n_in,
                              void* d_out, int out_size, void* d_ws, size_t ws_size,
                              hipStream_t stream)
{
    const float* x     = (const float*)d_in[0];
    const float* w1    = (const float*)d_in[1];
    const float* g1    = (const float*)d_in[2];
    const float* b1    = (const float*)d_in[3];
    const float* wq    = (const float*)d_in[4];
    const float* bq    = (const float*)d_in[5];
    const float* wk    = (const float*)d_in[6];
    const float* bk    = (const float*)d_in[7];
    const float* wv    = (const float*)d_in[8];
    const float* bv    = (const float*)d_in[9];
    const float* gamma = (const float*)d_in[10];
    const float* g2    = (const float*)d_in[11];
    const float* b2    = (const float*)d_in[12];
    const float* w3    = (const float*)d_in[13];
    const float* g3    = (const float*)d_in[14];
    const float* b3    = (const float*)d_in[15];
    float* out = (float*)d_out;

    char* wsb = (char*)d_ws;
    unsigned short* y1b = (unsigned short*)(wsb);                      // 32MB (later y3b)
    unsigned short* xt  = (unsigned short*)(wsb + (size_t)(32 << 20)); // 32MB (later upn)
    float* hs  = (float*)(wsb + (size_t)(64 << 20));                   // 16MB (later h2t)
    unsigned short* hst = (unsigned short*)(wsb + (size_t)(80 << 20)); // 8MB
    unsigned short* vbb = (unsigned short*)(wsb + (size_t)(88 << 20)); // 8MB
    unsigned short* qTb = (unsigned short*)(wsb + (size_t)(96 << 20)); // 1MB
    unsigned short* kTb = (unsigned short*)(wsb + (size_t)(97 << 20)); // 1MB
    unsigned short* w1b = (unsigned short*)(wsb + (size_t)(98 << 20));
    unsigned short* wvb = w1b + 65536;
    unsigned short* w3b = wvb + 65536;
    unsigned short* wqb = w3b + 65536;
    unsigned short* wkb = wqb + 8192;
    float* psum   = (float*)(wsb + (size_t)(99 << 20));                // 128KB
    float* psumsq = psum + 32768;                                      // 128KB
    float* sc1 = psumsq + 32768; float* sh1 = sc1 + 256;
    float* sc2 = sh1 + 256;      float* sh2 = sc2 + 256;
    float* sc3 = sh2 + 256;      float* sh3 = sc3 + 256;
    unsigned short* y3b = y1b;
    unsigned short* upn = xt;
    float* h2t = hs;

    cvt_weights<<<256, 256, 0, stream>>>(w1, wq, wk, wv, w3, w1b, wqb, wkb, wvb, w3b);
    transpose_cvt<<<dim3(256, 4, 4), 256, 0, stream>>>(x, xt, 16384);

    // net1: conv1 (MFMA) -> BN stats -> BN+ReLU+down
    gemm_mfma<128, 2><<<dim3(128, 2, 4), 256, 0, stream>>>(w1b, xt, nullptr, y1b, 16384);
    channel_stats_bf16<<<dim3(256, 4), 256, 0, stream>>>(y1b, psum, psumsq, 16384);
    bn_finalize<<<1, 256, 0, stream>>>(psum, psumsq, g1, b1, sc1, sh1, 1.f / 65536.f, 4);
    bnrelu_down<<<dim3(16, 256, 4), 256, 0, stream>>>(y1b, sc1, sh1, hs);
    transpose_cvt<<<dim3(64, 4, 4), 256, 0, stream>>>(hs, hst, 4096);

    // net2: q,k,v projections + fused MFMA attention
    gemm_mfma<32, 1><<<dim3(32, 1, 4), 256, 0, stream>>>(wqb, hst, bq, qTb, 4096);
    gemm_mfma<32, 1><<<dim3(32, 1, 4), 256, 0, stream>>>(wkb, hst, bk, kTb, 4096);
    gemm_mfma<128, 2><<<dim3(32, 2, 4), 256, 0, stream>>>(wvb, hst, bv, vbb, 4096);
    attn_mfma<<<dim3(64, 4), 512, 0, stream>>>(qTb, kTb, vbb, hst, gamma, h2t);

    // net2 tail: BN2 + ReLU fused into upsample
    stats_pmajor<<<dim3(32, 4), 256, 0, stream>>>(h2t, psum, psumsq);
    bn_finalize<<<1, 256, 0, stream>>>(psum, psumsq, g2, b2, sc2, sh2, 1.f / 16384.f, 128);
    upsample_bnrelu<<<dim3(16384, 4), 256, 0, stream>>>(h2t, sc2, sh2, upn);

    // net3: conv3 (MFMA) -> BN3 + residual + ReLU
    gemm_mfma<128, 2><<<dim3(128, 2, 4), 256, 0, stream>>>(w3b, upn, nullptr, y3b, 16384);
    channel_stats_bf16<<<dim3(256, 4), 256, 0, stream>>>(y3b, psum, psumsq, 16384);
    bn_finalize<<<1, 256, 0, stream>>>(psum, psumsq, g3, b3, sc3, sh3, 1.f / 65536.f, 4);
    final_add_relu<<<16384, 256, 0, stream>>>(y3b, sc3, sh3, x, out);
}

// Round 5
// 449.578 us; speedup vs baseline: 2.9242x; 1.0657x over previous
//
#include <hip/hip_runtime.h>
#include <hip/hip_bf16.h>

// B=4, C=256, C8=32, H=128, W=128, H2=W2=64, N=4096, HW=16384
#define EPS_BN 1e-5f

typedef short bf16x8 __attribute__((ext_vector_type(8)));
typedef float f32x4 __attribute__((ext_vector_type(4)));

__device__ __forceinline__ unsigned short f2bf(float f) {
    __hip_bfloat16 h = __float2bfloat16(f);
    return __builtin_bit_cast(unsigned short, h);
}
__device__ __forceinline__ float bf2f(unsigned short u) {
    return __builtin_bit_cast(float, (unsigned)u << 16);
}

// ---------------------------------------------------------------------------
// bf16 MFMA GEMM: Y[b,o,p] = sum_c Wb[o,c] * Xt[b,p,c]  (K=256 fixed)
// BM in {128,64,32}; BN=128; BK=32; 256 threads (4 waves), 2-phase prefetch.
// MODE 1: bf16 p-major out (B,P,O) + bias  (q/k merged projection)
// MODE 2: bf16 c-major out (B,256,P) + optional bias (conv1/conv3/v)
// ---------------------------------------------------------------------------
template<int BM, int MODE>
__global__ __launch_bounds__(256) void gemm_mfma(
    const unsigned short* __restrict__ Wb,   // (O,256) bf16
    const unsigned short* __restrict__ Xt,   // (B,P,256) bf16
    const float* __restrict__ bias,
    unsigned short* __restrict__ Y,
    int P, int O)
{
    const int tid = threadIdx.x;
    const int w = tid >> 6, l = tid & 63;
    const int b = blockIdx.z;
    const int p0 = blockIdx.x * 128;
    const int o0 = blockIdx.y * BM;
    const int lr = l & 15, lk = l >> 4;
    const int srow = l >> 2, sq = l & 3;     // staging: 16 rows x 4 chunks / wave

    __shared__ unsigned short Al[BM * 40];
    __shared__ unsigned short Bl[128 * 40];

    constexpr int WC = (BM == 32) ? 4 : 2;            // waves along p
    constexpr int MT = (BM == 128) ? 4 : 2;           // o-subtiles / wave
    constexpr int NT = (WC == 2) ? 4 : 2;             // p-subtiles / wave
    const int wr = w / WC, wc = w % WC;
    const int osub = wr * MT * 16, psub = wc * NT * 16;

    f32x4 acc[MT][NT];
#pragma unroll
    for (int i = 0; i < MT; i++)
#pragma unroll
        for (int j = 0; j < NT; j++) acc[i][j] = (f32x4){0.f, 0.f, 0.f, 0.f};

    const unsigned short* Xb = Xt + (size_t)b * P * 256;
    const int ar0 = w * 16, ar1 = w * 16 + 64;   // A rows staged by this wave
    const int br0 = w * 16, br1 = w * 16 + 64;   // B rows staged by this wave

    uint4 vb0, vb1, va0, va1;
#define G_LOADS(K0)                                                                        \
    vb0 = *(const uint4*)(Xb + (size_t)(p0 + br0 + srow) * 256 + (K0) + sq * 8);           \
    vb1 = *(const uint4*)(Xb + (size_t)(p0 + br1 + srow) * 256 + (K0) + sq * 8);           \
    if (ar0 < BM) va0 = *(const uint4*)(Wb + (size_t)(o0 + ar0 + srow) * 256 + (K0) + sq * 8); \
    if (ar1 < BM) va1 = *(const uint4*)(Wb + (size_t)(o0 + ar1 + srow) * 256 + (K0) + sq * 8);

    G_LOADS(0)
    for (int k0 = 0; k0 < 256; k0 += 32) {
        __syncthreads();   // prior k-step's LDS reads complete
        *(uint4*)&Bl[(br0 + srow) * 40 + sq * 8] = vb0;
        *(uint4*)&Bl[(br1 + srow) * 40 + sq * 8] = vb1;
        if (ar0 < BM) *(uint4*)&Al[(ar0 + srow) * 40 + sq * 8] = va0;
        if (ar1 < BM) *(uint4*)&Al[(ar1 + srow) * 40 + sq * 8] = va1;
        __syncthreads();   // staging visible
        if (k0 < 224) { G_LOADS(k0 + 32) }   // prefetch next, in flight during MFMA
        bf16x8 af[MT], bfr[NT];
#pragma unroll
        for (int i = 0; i < MT; i++) {
            int row = osub + i * 16 + lr;
            af[i] = *(const bf16x8*)&Al[row * 40 + lk * 8];
        }
#pragma unroll
        for (int j = 0; j < NT; j++) {
            int row = psub + j * 16 + lr;
            bfr[j] = *(const bf16x8*)&Bl[row * 40 + lk * 8];
        }
#pragma unroll
        for (int i = 0; i < MT; i++)
#pragma unroll
            for (int j = 0; j < NT; j++)
                acc[i][j] = __builtin_amdgcn_mfma_f32_16x16x32_bf16(af[i], bfr[j], acc[i][j], 0, 0, 0);
    }
#undef G_LOADS

    // epilogue; C/D: col = lane&15 (p), row = (lane>>4)*4 + reg (o)
    if (MODE == 1) {
#pragma unroll
        for (int i = 0; i < MT; i++) {
            int ob = o0 + osub + i * 16 + lk * 4;
#pragma unroll
            for (int j = 0; j < NT; j++) {
                int p = p0 + psub + j * 16 + lr;
                ushort4 pk;
                pk.x = f2bf(acc[i][j][0] + bias[ob + 0]);
                pk.y = f2bf(acc[i][j][1] + bias[ob + 1]);
                pk.z = f2bf(acc[i][j][2] + bias[ob + 2]);
                pk.w = f2bf(acc[i][j][3] + bias[ob + 3]);
                *(ushort4*)&Y[((size_t)b * P + p) * O + ob] = pk;
            }
        }
    } else {
#pragma unroll
        for (int i = 0; i < MT; i++)
#pragma unroll
            for (int r = 0; r < 4; r++) {
                int o = o0 + osub + i * 16 + lk * 4 + r;
                float bs = bias ? bias[o] : 0.f;
#pragma unroll
                for (int j = 0; j < NT; j++) {
                    int p = p0 + psub + j * 16 + lr;
                    Y[((size_t)(b * 256 + o)) * P + p] = f2bf(acc[i][j][r] + bs);
                }
            }
    }
}

// ---------------------------------------------------------------------------
// LDS-tiled transpose + cvt: (B,256,P) f32 -> (B,P,256) bf16
// ---------------------------------------------------------------------------
__global__ __launch_bounds__(256) void transpose_cvt(
    const float* __restrict__ src, unsigned short* __restrict__ dst, int P)
{
    __shared__ float t[64][65];
    const int tid = threadIdx.x;
    const int p0 = blockIdx.x * 64, c0 = blockIdx.y * 64, b = blockIdx.z;
    const float* sb = src + ((size_t)b * 256 + c0) * P + p0;
#pragma unroll
    for (int i = 0; i < 16; i++) {
        int r = (tid >> 6) + 4 * i;   // c-local
        int c = tid & 63;             // p-local
        t[c][r] = sb[(size_t)r * P + c];
    }
    __syncthreads();
#pragma unroll
    for (int i = 0; i < 8; i++) {
        int pr = (tid >> 5) + 8 * i;
        int cc = (tid & 31) * 2;
        unsigned pk = ((unsigned)f2bf(t[pr][cc + 1]) << 16) | f2bf(t[pr][cc]);
        *(unsigned*)&dst[((size_t)b * P + p0 + pr) * 256 + c0 + cc] = pk;
    }
}

__global__ void cvt_weights(const float* __restrict__ w1, const float* __restrict__ wq,
                            const float* __restrict__ wk, const float* __restrict__ wv,
                            const float* __restrict__ w3,
                            const float* __restrict__ bq, const float* __restrict__ bk,
                            unsigned short* o1, unsigned short* oqk,
                            unsigned short* ov, unsigned short* o3, float* obqk)
{
    int i = blockIdx.x * 256 + threadIdx.x;
    if (i < 65536) { o1[i] = f2bf(w1[i]); ov[i] = f2bf(wv[i]); o3[i] = f2bf(w3[i]); }
    if (i < 16384) oqk[i] = f2bf(i < 8192 ? wq[i] : wk[i - 8192]);
    if (i < 64)    obqk[i] = i < 32 ? bq[i] : bk[i - 32];
}

// per-(channel,batch) partial sums over c-major bf16 (B,256,Pn)
__global__ __launch_bounds__(256) void channel_stats_bf16(
    const unsigned short* __restrict__ Y, float* __restrict__ psum,
    float* __restrict__ psumsq, int Pn)
{
    const int o = blockIdx.x, b = blockIdx.y;
    const unsigned short* p = Y + ((size_t)b * 256 + o) * Pn;
    float s = 0.f, s2 = 0.f;
    for (int i = threadIdx.x * 8; i < Pn; i += 2048) {
        uint4 v = *(const uint4*)&p[i];
        unsigned uu[4] = {v.x, v.y, v.z, v.w};
#pragma unroll
        for (int k = 0; k < 4; k++) {
            float a = __builtin_bit_cast(float, uu[k] << 16);
            float c = __builtin_bit_cast(float, uu[k] & 0xffff0000u);
            s += a + c; s2 += a * a + c * c;
        }
    }
#pragma unroll
    for (int off = 32; off; off >>= 1) {
        s  += __shfl_down(s, off);
        s2 += __shfl_down(s2, off);
    }
    __shared__ float ws1[4], ws2[4];
    int lane = threadIdx.x & 63, w = threadIdx.x >> 6;
    if (lane == 0) { ws1[w] = s; ws2[w] = s2; }
    __syncthreads();
    if (threadIdx.x == 0) {
        float ts = 0.f, ts2 = 0.f;
#pragma unroll
        for (int k = 0; k < 4; k++) { ts += ws1[k]; ts2 += ws2[k]; }
        psum[(size_t)b * 256 + o] = ts;
        psumsq[(size_t)b * 256 + o] = ts2;
    }
}

// per-channel partials over p-major f32 (B,4096,256); grid (32, B)
__global__ __launch_bounds__(256) void stats_pmajor(
    const float* __restrict__ Y, float* __restrict__ psum, float* __restrict__ psumsq)
{
    const int chunk = blockIdx.x, b = blockIdx.y, c = threadIdx.x;
    const float* base = Y + ((size_t)b * 4096 + chunk * 128) * 256 + c;
    float s = 0.f, s2 = 0.f;
    for (int i = 0; i < 128; i++) { float v = base[(size_t)i * 256]; s += v; s2 += v * v; }
    psum[((size_t)b * 32 + chunk) * 256 + c] = s;
    psumsq[((size_t)b * 32 + chunk) * 256 + c] = s2;
}

__global__ void bn_finalize(const float* __restrict__ psum, const float* __restrict__ psumsq,
                            const float* __restrict__ g, const float* __restrict__ bb,
                            float* __restrict__ scale, float* __restrict__ shift,
                            float invN, int NP)
{
    int o = threadIdx.x;
    float s = 0.f, s2 = 0.f;
    for (int k = 0; k < NP; k++) { s += psum[k * 256 + o]; s2 += psumsq[k * 256 + o]; }
    float mean = s * invN;
    float var  = s2 * invN - mean * mean;
    float r = rsqrtf(var + EPS_BN);
    float sc = g[o] * r;
    scale[o] = sc;
    shift[o] = bb[o] - mean * sc;
}

// antialiased bilinear 2x downsample taps (jax.image.resize)
__device__ __forceinline__ int dtaps(int u, int* j, float* w) {
    if (u == 0)  { j[0]=0;   j[1]=1;   j[2]=2;   w[0]=3.f/7.f; w[1]=3.f/7.f; w[2]=1.f/7.f; return 3; }
    if (u == 63) { j[0]=125; j[1]=126; j[2]=127; w[0]=1.f/7.f; w[1]=3.f/7.f; w[2]=3.f/7.f; return 3; }
    j[0]=2*u-1; j[1]=2*u; j[2]=2*u+1; j[3]=2*u+2;
    w[0]=0.125f; w[1]=0.375f; w[2]=0.375f; w[3]=0.125f; return 4;
}

// BN + ReLU + 128->64 downsample; y1 bf16 c-major in, hs f32 c-major out
__global__ __launch_bounds__(256) void bnrelu_down(
    const unsigned short* __restrict__ y1, const float* __restrict__ scale,
    const float* __restrict__ shift, float* __restrict__ h)
{
    int i = blockIdx.x * 256 + threadIdx.x;  // 0..4095 over 64x64
    int o = blockIdx.y, b = blockIdx.z;
    int y2 = i >> 6, x2 = i & 63;
    const unsigned short* base = y1 + ((size_t)(b * 256 + o)) * 16384;
    float sc = scale[o], sh = shift[o];
    int jy[4]; float wy[4]; int ny = dtaps(y2, jy, wy);
    int jx[4]; float wx[4]; int nx = dtaps(x2, jx, wx);
    float acc = 0.f;
    for (int a = 0; a < ny; a++) {
        const unsigned short* row = base + jy[a] * 128;
        for (int c = 0; c < nx; c++) {
            float v = fmaxf(fmaf(sc, bf2f(row[jx[c]]), sh), 0.f);
            acc += wy[a] * wx[c] * v;
        }
    }
    h[((size_t)(b * 256 + o)) * 4096 + i] = acc;
}

// ---------------------------------------------------------------------------
// Split-K bf16 MFMA flash attention, S=4 chunks of 1024 keys.
// qkT (B,4096,64) bf16 (q cols 0..31, k cols 32..63); vb (B,256,4096) bf16.
// Per (i-tile, s, b) block: 16 KV tiles of 64; emits raw partials:
//   accP[((b*4+s)*4096+row)*256+ch] (unnormalized), mzP[(b*4+s)*4096+row]={m,z}.
// 512 thr = 8 waves: (wr=w>>1 -> rows i0+wr*16, wc=w&1 -> ch wc*128).
// LDS 45.5KB: K rows 40sh; V rows 64sh slot-XOR swizzled; P shared per wr
// (the wc-pair waves write bitwise-identical values -> benign duplicate).
// ---------------------------------------------------------------------------
__global__ __launch_bounds__(512) void attn_partial(
    const unsigned short* __restrict__ qkT, const unsigned short* __restrict__ vb,
    float* __restrict__ accP, float2* __restrict__ mzP)
{
    const int s = blockIdx.y;
    const int b = blockIdx.z;
    const int i0 = blockIdx.x * 64;
    const int tid = threadIdx.x;
    const int w = tid >> 6, l = tid & 63;
    const int wr = w >> 1, wc = w & 1;
    const int lr = l & 15, lk = l >> 4;

    __shared__ unsigned short Kl[64 * 40];        // 5.0 KB
    __shared__ unsigned short Vl[256 * 64];       // 32.0 KB (swizzled)
    __shared__ unsigned short Pl[4][16 * 68];     // 8.5 KB (shared per wr)

    const unsigned short* qkTb = qkT + (size_t)b * 4096 * 64;
    // Q fragment (A): row = i0+wr*16+lr, k = lk*8..+7
    bf16x8 qf = *(const bf16x8*)&qkTb[(size_t)(i0 + wr * 16 + lr) * 64 + lk * 8];

    f32x4 acc[8];
#pragma unroll
    for (int i = 0; i < 8; i++) acc[i] = (f32x4){0.f, 0.f, 0.f, 0.f};
    float m[4], zp[4];
#pragma unroll
    for (int r = 0; r < 4; r++) { m[r] = -1e30f; zp[r] = 0.f; }

    const unsigned short* vbb = vb + (size_t)b * 256 * 4096;
    unsigned short* Pw = Pl[wr];

    uint4 kreg, vreg[4];
#define LOAD_TILE(J0)                                                                      \
    if (w < 4)                                                                             \
        kreg = *(const uint4*)(qkTb + (size_t)((J0) + w * 16 + (l >> 2)) * 64 + 32 + (l & 3) * 8); \
    _Pragma("unroll")                                                                      \
    for (int it = 0; it < 4; it++)                                                         \
        vreg[it] = *(const uint4*)(vbb + (size_t)(w * 32 + it * 8 + (l >> 3)) * 4096       \
                                   + (J0) + (l & 7) * 8);

    const int jbase = s * 1024;
    LOAD_TILE(jbase)
    for (int t = 0; t < 16; t++) {
        const int j0 = jbase + t * 64;
        __syncthreads();   // prior tile's LDS reads complete
        // staged regs -> LDS
        if (w < 4)
            *(uint4*)&Kl[(w * 16 + (l >> 2)) * 40 + (l & 3) * 8] = kreg;
#pragma unroll
        for (int it = 0; it < 4; it++) {
            int ch = w * 32 + it * 8 + (l >> 3);
            *(uint4*)&Vl[ch * 64 + (((l & 7) ^ (ch & 7)) * 8)] = vreg[it];
        }
        __syncthreads();
        if (t < 15) { LOAD_TILE(j0 + 64) }   // prefetch next tile during compute

        // QK^T: 4 j-subtiles of 16
        f32x4 sv[4];
#pragma unroll
        for (int jt = 0; jt < 4; jt++) {
            int j = jt * 16 + lr;
            bf16x8 kf = *(const bf16x8*)&Kl[j * 40 + lk * 8];
            sv[jt] = __builtin_amdgcn_mfma_f32_16x16x32_bf16(qf, kf, (f32x4){0.f,0.f,0.f,0.f}, 0, 0, 0);
        }

        // online softmax (rows R = lk*4+r; reduce over 16-lane group lk)
        bool grew = false;
        float corr[4], pv[4][4];
#pragma unroll
        for (int r = 0; r < 4; r++) {
            float tm = fmaxf(fmaxf(sv[0][r], sv[1][r]), fmaxf(sv[2][r], sv[3][r]));
#pragma unroll
            for (int off = 1; off < 16; off <<= 1) tm = fmaxf(tm, __shfl_xor(tm, off));
            float mo = m[r];
            float mn = fmaxf(mo, tm);
            bool g = tm > mo;
            corr[r] = g ? __expf(mo - mn) : 1.f;
            grew |= g;
            m[r] = mn;
            float ps = 0.f;
#pragma unroll
            for (int jt = 0; jt < 4; jt++) {
                float p = __expf(sv[jt][r] - mn);
                pv[jt][r] = p; ps += p;
            }
            zp[r] = zp[r] * corr[r] + ps;
        }
        if (__any(grew)) {
#pragma unroll
            for (int i = 0; i < 8; i++)
#pragma unroll
                for (int r = 0; r < 4; r++) acc[i][r] *= corr[r];
        }

        // P -> shared-per-wr LDS (both wc waves write identical values)
#pragma unroll
        for (int jt = 0; jt < 4; jt++) {
            int cc = lr + 16 * jt;
#pragma unroll
            for (int r = 0; r < 4; r++) {
                int R = lk * 4 + r;
                Pw[R * 68 + cc] = f2bf(pv[jt][r]);
            }
        }

        // PV: 2 k-chunks x 8 channel subtiles (V read with matching swizzle)
#pragma unroll
        for (int kc = 0; kc < 2; kc++) {
            bf16x8 pa = *(const bf16x8*)&Pw[lr * 68 + (kc * 4 + lk) * 8];
#pragma unroll
            for (int ct = 0; ct < 8; ct++) {
                int ch = wc * 128 + ct * 16 + lr;
                bf16x8 vf = *(const bf16x8*)&Vl[ch * 64 + (((kc * 4 + lk) ^ (ch & 7)) * 8)];
                acc[ct] = __builtin_amdgcn_mfma_f32_16x16x32_bf16(pa, vf, acc[ct], 0, 0, 0);
            }
        }
    }
#undef LOAD_TILE

    // z-reduce over the 16-lane group; write raw partials
    float zs[4];
#pragma unroll
    for (int r = 0; r < 4; r++) {
        float zz = zp[r];
#pragma unroll
        for (int off = 1; off < 16; off <<= 1) zz += __shfl_xor(zz, off);
        zs[r] = zz;
    }
    const size_t rbase = (size_t)(b * 4 + s) * 4096 + i0 + wr * 16;
    if (wc == 0 && lr == 0) {
#pragma unroll
        for (int r = 0; r < 4; r++)
            mzP[rbase + lk * 4 + r] = make_float2(m[r], zs[r]);
    }
#pragma unroll
    for (int ct = 0; ct < 8; ct++) {
        int ch = wc * 128 + ct * 16 + lr;
#pragma unroll
        for (int r = 0; r < 4; r++)
            accP[(rbase + lk * 4 + r) * 256 + ch] = acc[ct][r];
    }
}

// merge S=4 chunk partials: out = gamma * (sum ws*acc)/(sum ws*z) + residual
__global__ __launch_bounds__(256) void attn_combine(
    const float* __restrict__ accP, const float2* __restrict__ mzP,
    const unsigned short* __restrict__ hst, const float* __restrict__ gamma_p,
    float* __restrict__ h2t)
{
    const int row = blockIdx.x, b = blockIdx.y, ch = threadIdx.x;
    float2 mz[4];
#pragma unroll
    for (int s = 0; s < 4; s++) mz[s] = mzP[(size_t)(b * 4 + s) * 4096 + row];
    float M = fmaxf(fmaxf(mz[0].x, mz[1].x), fmaxf(mz[2].x, mz[3].x));
    float Z = 0.f, a = 0.f;
#pragma unroll
    for (int s = 0; s < 4; s++) {
        float wgt = __expf(mz[s].x - M);
        Z += wgt * mz[s].y;
        a += wgt * accP[((size_t)(b * 4 + s) * 4096 + row) * 256 + ch];
    }
    size_t off = ((size_t)b * 4096 + row) * 256 + ch;
    h2t[off] = gamma_p[0] * a / Z + bf2f(hst[off]);
}

// BN2+ReLU fused with bilinear 64->128 upsample; p-major in/out
__global__ __launch_bounds__(256) void upsample_bnrelu(
    const float* __restrict__ h2t, const float* __restrict__ scale,
    const float* __restrict__ shift, unsigned short* __restrict__ upn)
{
    const int p = blockIdx.x, b = blockIdx.y, c = threadIdx.x;
    int y = p >> 7, x = p & 127;
    float fy = 0.5f * y - 0.25f, fx = 0.5f * x - 0.25f;
    float fiy = floorf(fy), fix = floorf(fx);
    float wy = fy - fiy, wx = fx - fix;
    int iy = (int)fiy, ix = (int)fix;
    int iy0 = max(iy, 0), iy1 = min(iy + 1, 63);
    int ix0 = max(ix, 0), ix1 = min(ix + 1, 63);
    const float* basep = h2t + ((size_t)b * 4096) * 256 + c;
    float sc = scale[c], sh = shift[c];
    float v00 = fmaxf(fmaf(sc, basep[(size_t)(iy0 * 64 + ix0) * 256], sh), 0.f);
    float v01 = fmaxf(fmaf(sc, basep[(size_t)(iy0 * 64 + ix1) * 256], sh), 0.f);
    float v10 = fmaxf(fmaf(sc, basep[(size_t)(iy1 * 64 + ix0) * 256], sh), 0.f);
    float v11 = fmaxf(fmaf(sc, basep[(size_t)(iy1 * 64 + ix1) * 256], sh), 0.f);
    float r0 = (1.f - wy) * ((1.f - wx) * v00 + wx * v01)
             + wy * ((1.f - wx) * v10 + wx * v11);
    upn[((size_t)b * 16384 + p) * 256 + c] = f2bf(r0);
}

// out = relu(bn3(y3) + x); y3 bf16 c-major
__global__ __launch_bounds__(256) void final_add_relu(
    const unsigned short* __restrict__ y3, const float* __restrict__ scale,
    const float* __restrict__ shift, const float* __restrict__ x,
    float* __restrict__ outp)
{
    size_t e = ((size_t)blockIdx.x * 256 + threadIdx.x) * 4;
    int c = (int)((e >> 14) & 255);
    ushort4 yv = *(const ushort4*)&y3[e];
    float4 xv = *(const float4*)&x[e];
    float sc = scale[c], sh = shift[c];
    float4 o;
    o.x = fmaxf(fmaf(sc, bf2f(yv.x), sh) + xv.x, 0.f);
    o.y = fmaxf(fmaf(sc, bf2f(yv.y), sh) + xv.y, 0.f);
    o.z = fmaxf(fmaf(sc, bf2f(yv.z), sh) + xv.z, 0.f);
    o.w = fmaxf(fmaf(sc, bf2f(yv.w), sh) + xv.w, 0.f);
    *(float4*)&outp[e] = o;
}

extern "C" void kernel_launch(void* const* d_in, const int* in_sizes, int n_in,
                              void* d_out, int out_size, void* d_ws, size_t ws_size,
                              hipStream_t stream)
{
    const float* x     = (const float*)d_in[0];
    const float* w1    = (const float*)d_in[1];
    const float* g1    = (const float*)d_in[2];
    const float* b1    = (const float*)d_in[3];
    const float* wq    = (const float*)d_in[4];
    const float* bq    = (const float*)d_in[5];
    const float* wk    = (const float*)d_in[6];
    const float* bk    = (const float*)d_in[7];
    const float* wv    = (const float*)d_in[8];
    const float* bv    = (const float*)d_in[9];
    const float* gamma = (const float*)d_in[10];
    const float* g2    = (const float*)d_in[11];
    const float* b2    = (const float*)d_in[12];
    const float* w3    = (const float*)d_in[13];
    const float* g3    = (const float*)d_in[14];
    const float* b3    = (const float*)d_in[15];
    float* out = (float*)d_out;

    char* wsb = (char*)d_ws;
    // 0-64MiB:  y1b(32)+xt(32) early; accP (64MiB exactly) during attention;
    //           y3b(0-32) / upn(32-64) in net3
    unsigned short* y1b = (unsigned short*)wsb;
    unsigned short* xt  = (unsigned short*)(wsb + ((size_t)32 << 20));
    float* accP = (float*)wsb;
    float* hs   = (float*)(wsb + ((size_t)64 << 20));                 // 64-80 (later h2t)
    unsigned short* vbb = (unsigned short*)(wsb + ((size_t)80 << 20)); // 80-88
    unsigned short* hst = (unsigned short*)(wsb + ((size_t)88 << 20)); // 88-96
    unsigned short* qkT = (unsigned short*)(wsb + ((size_t)96 << 20)); // 96-98 (2MiB)
    unsigned short* w1b = (unsigned short*)(wsb + ((size_t)98 << 20));
    unsigned short* wvb  = w1b + 65536;
    unsigned short* w3b  = wvb + 65536;
    unsigned short* wqkb = w3b + 65536;
    float* bqk = (float*)(wqkb + 16384);
    float2* mzP = (float2*)(wsb + ((size_t)98 << 20) + ((size_t)512 << 10)); // 512KB
    float* psum   = (float*)(wsb + ((size_t)99 << 20));
    float* psumsq = psum + 32768;
    float* sc1 = psumsq + 32768; float* sh1 = sc1 + 256;
    float* sc2 = sh1 + 256;      float* sh2 = sc2 + 256;
    float* sc3 = sh2 + 256;      float* sh3 = sc3 + 256;
    unsigned short* y3b = y1b;
    unsigned short* upn = xt;
    float* h2t = hs;

    cvt_weights<<<256, 256, 0, stream>>>(w1, wq, wk, wv, w3, bq, bk,
                                         w1b, wqkb, wvb, w3b, bqk);
    transpose_cvt<<<dim3(256, 4, 4), 256, 0, stream>>>(x, xt, 16384);

    // net1: conv1 (MFMA) -> BN stats -> BN+ReLU+down
    gemm_mfma<128, 2><<<dim3(128, 2, 4), 256, 0, stream>>>(w1b, xt, nullptr, y1b, 16384, 256);
    channel_stats_bf16<<<dim3(256, 4), 256, 0, stream>>>(y1b, psum, psumsq, 16384);
    bn_finalize<<<1, 256, 0, stream>>>(psum, psumsq, g1, b1, sc1, sh1, 1.f / 65536.f, 4);
    bnrelu_down<<<dim3(16, 256, 4), 256, 0, stream>>>(y1b, sc1, sh1, hs);
    transpose_cvt<<<dim3(64, 4, 4), 256, 0, stream>>>(hs, hst, 4096);

    // net2: merged qk projection + v projection + split-K attention + combine
    gemm_mfma<64, 1><<<dim3(32, 1, 4), 256, 0, stream>>>(wqkb, hst, bqk, qkT, 4096, 64);
    gemm_mfma<128, 2><<<dim3(32, 2, 4), 256, 0, stream>>>(wvb, hst, bv, vbb, 4096, 256);
    attn_partial<<<dim3(64, 4, 4), 512, 0, stream>>>(qkT, vbb, accP, mzP);
    attn_combine<<<dim3(4096, 4), 256, 0, stream>>>(accP, mzP, hst, gamma, h2t);

    // net2 tail: BN2 + ReLU fused into upsample
    stats_pmajor<<<dim3(32, 4), 256, 0, stream>>>(h2t, psum, psumsq);
    bn_finalize<<<1, 256, 0, stream>>>(psum, psumsq, g2, b2, sc2, sh2, 1.f / 16384.f, 128);
    upsample_bnrelu<<<dim3(16384, 4), 256, 0, stream>>>(h2t, sc2, sh2, upn);

    // net3: conv3 (MFMA) -> BN3 + residual + ReLU
    gemm_mfma<128, 2><<<dim3(128, 2, 4), 256, 0, stream>>>(w3b, upn, nullptr, y3b, 16384, 256);
    channel_stats_bf16<<<dim3(256, 4), 256, 0, stream>>>(y3b, psum, psumsq, 16384);
    bn_finalize<<<1, 256, 0, stream>>>(psum, psumsq, g3, b3, sc3, sh3, 1.f / 65536.f, 4);
    final_add_relu<<<16384, 256, 0, stream>>>(y3b, sc3, sh3, x, out);
}

// Round 6
// 439.623 us; speedup vs baseline: 2.9905x; 1.0226x over previous
//
#include <hip/hip_runtime.h>
#include <hip/hip_bf16.h>

// B=4, C=256, C8=32, H=128, W=128, H2=W2=64, N=4096, HW=16384
#define EPS_BN 1e-5f

typedef short bf16x8 __attribute__((ext_vector_type(8)));
typedef float f32x4 __attribute__((ext_vector_type(4)));

__device__ __forceinline__ unsigned short f2bf(float f) {
    __hip_bfloat16 h = __float2bfloat16(f);
    return __builtin_bit_cast(unsigned short, h);
}
__device__ __forceinline__ float bf2f(unsigned short u) {
    return __builtin_bit_cast(float, (unsigned)u << 16);
}

// ---------------------------------------------------------------------------
// bf16 MFMA GEMM: Y[b,o,p] = sum_c Wb[o,c] * Xt[b,p,c]  (K=256 fixed)
// BM in {128,64,32}; BN=128; BK=32; 256 threads (4 waves), 2-phase prefetch,
// hoisted per-thread pointers (+32/step).
// MODE 1: bf16 p-major out (B,P,O) + bias  (q/k merged projection)
// MODE 2: bf16 c-major out (B,256,P) + optional bias (conv1/conv3/v)
// ---------------------------------------------------------------------------
template<int BM, int MODE>
__global__ __launch_bounds__(256) void gemm_mfma(
    const unsigned short* __restrict__ Wb,   // (O,256) bf16
    const unsigned short* __restrict__ Xt,   // (B,P,256) bf16
    const float* __restrict__ bias,
    unsigned short* __restrict__ Y,
    int P, int O)
{
    const int tid = threadIdx.x;
    const int w = tid >> 6, l = tid & 63;
    const int b = blockIdx.z;
    const int p0 = blockIdx.x * 128;
    const int o0 = blockIdx.y * BM;
    const int lr = l & 15, lk = l >> 4;
    const int srow = l >> 2, sq = l & 3;     // staging: 16 rows x 4 chunks / wave

    __shared__ unsigned short Al[BM * 40];
    __shared__ unsigned short Bl[128 * 40];

    constexpr int WC = (BM == 32) ? 4 : 2;            // waves along p
    constexpr int MT = (BM == 128) ? 4 : 2;           // o-subtiles / wave
    constexpr int NT = (WC == 2) ? 4 : 2;             // p-subtiles / wave
    const int wr = w / WC, wc = w % WC;
    const int osub = wr * MT * 16, psub = wc * NT * 16;

    f32x4 acc[MT][NT];
#pragma unroll
    for (int i = 0; i < MT; i++)
#pragma unroll
        for (int j = 0; j < NT; j++) acc[i][j] = (f32x4){0.f, 0.f, 0.f, 0.f};

    const unsigned short* Xb = Xt + (size_t)b * P * 256;
    const int ar0 = w * 16, ar1 = w * 16 + 64;   // A rows staged by this wave
    const int br0 = w * 16, br1 = w * 16 + 64;   // B rows staged by this wave

    // hoisted pointers
    const unsigned short* pB0 = Xb + (size_t)(p0 + br0 + srow) * 256 + sq * 8;
    const unsigned short* pB1 = Xb + (size_t)(p0 + br1 + srow) * 256 + sq * 8;
    const unsigned short* pA0 = Wb + (size_t)(o0 + ar0 + srow) * 256 + sq * 8;
    const unsigned short* pA1 = Wb + (size_t)(o0 + ar1 + srow) * 256 + sq * 8;
    unsigned short* BlW0 = &Bl[(br0 + srow) * 40 + sq * 8];
    unsigned short* BlW1 = &Bl[(br1 + srow) * 40 + sq * 8];
    unsigned short* AlW0 = &Al[(ar0 + srow) * 40 + sq * 8];
    unsigned short* AlW1 = &Al[(ar1 + srow) * 40 + sq * 8];

    uint4 vb0, vb1, va0, va1;
#define G_LOADS                                                     \
    vb0 = *(const uint4*)pB0; pB0 += 32;                            \
    vb1 = *(const uint4*)pB1; pB1 += 32;                            \
    if (ar0 < BM) { va0 = *(const uint4*)pA0; pA0 += 32; }          \
    if (ar1 < BM) { va1 = *(const uint4*)pA1; pA1 += 32; }

    G_LOADS
    for (int k0 = 0; k0 < 256; k0 += 32) {
        __syncthreads();   // prior k-step's LDS reads complete
        *(uint4*)BlW0 = vb0;
        *(uint4*)BlW1 = vb1;
        if (ar0 < BM) *(uint4*)AlW0 = va0;
        if (ar1 < BM) *(uint4*)AlW1 = va1;
        __syncthreads();   // staging visible
        if (k0 < 224) { G_LOADS }   // prefetch next, in flight during MFMA
        bf16x8 af[MT], bfr[NT];
#pragma unroll
        for (int i = 0; i < MT; i++) {
            int row = osub + i * 16 + lr;
            af[i] = *(const bf16x8*)&Al[row * 40 + lk * 8];
        }
#pragma unroll
        for (int j = 0; j < NT; j++) {
            int row = psub + j * 16 + lr;
            bfr[j] = *(const bf16x8*)&Bl[row * 40 + lk * 8];
        }
#pragma unroll
        for (int i = 0; i < MT; i++)
#pragma unroll
            for (int j = 0; j < NT; j++)
                acc[i][j] = __builtin_amdgcn_mfma_f32_16x16x32_bf16(af[i], bfr[j], acc[i][j], 0, 0, 0);
    }
#undef G_LOADS

    // epilogue; C/D: col = lane&15 (p), row = (lane>>4)*4 + reg (o)
    if (MODE == 1) {
#pragma unroll
        for (int i = 0; i < MT; i++) {
            int ob = o0 + osub + i * 16 + lk * 4;
#pragma unroll
            for (int j = 0; j < NT; j++) {
                int p = p0 + psub + j * 16 + lr;
                ushort4 pk;
                pk.x = f2bf(acc[i][j][0] + bias[ob + 0]);
                pk.y = f2bf(acc[i][j][1] + bias[ob + 1]);
                pk.z = f2bf(acc[i][j][2] + bias[ob + 2]);
                pk.w = f2bf(acc[i][j][3] + bias[ob + 3]);
                *(ushort4*)&Y[((size_t)b * P + p) * O + ob] = pk;
            }
        }
    } else {
#pragma unroll
        for (int i = 0; i < MT; i++)
#pragma unroll
            for (int r = 0; r < 4; r++) {
                int o = o0 + osub + i * 16 + lk * 4 + r;
                float bs = bias ? bias[o] : 0.f;
#pragma unroll
                for (int j = 0; j < NT; j++) {
                    int p = p0 + psub + j * 16 + lr;
                    Y[((size_t)(b * 256 + o)) * P + p] = f2bf(acc[i][j][r] + bs);
                }
            }
    }
}

// ---------------------------------------------------------------------------
// LDS-tiled transpose + cvt: (B,256,P) f32 -> (B,P,256) bf16
// ---------------------------------------------------------------------------
__global__ __launch_bounds__(256) void transpose_cvt(
    const float* __restrict__ src, unsigned short* __restrict__ dst, int P)
{
    __shared__ float t[64][65];
    const int tid = threadIdx.x;
    const int p0 = blockIdx.x * 64, c0 = blockIdx.y * 64, b = blockIdx.z;
    const float* sb = src + ((size_t)b * 256 + c0) * P + p0;
#pragma unroll
    for (int i = 0; i < 16; i++) {
        int r = (tid >> 6) + 4 * i;   // c-local
        int c = tid & 63;             // p-local
        t[c][r] = sb[(size_t)r * P + c];
    }
    __syncthreads();
#pragma unroll
    for (int i = 0; i < 8; i++) {
        int pr = (tid >> 5) + 8 * i;
        int cc = (tid & 31) * 2;
        unsigned pk = ((unsigned)f2bf(t[pr][cc + 1]) << 16) | f2bf(t[pr][cc]);
        *(unsigned*)&dst[((size_t)b * P + p0 + pr) * 256 + c0 + cc] = pk;
    }
}

__global__ void cvt_weights(const float* __restrict__ w1, const float* __restrict__ wq,
                            const float* __restrict__ wk, const float* __restrict__ wv,
                            const float* __restrict__ w3,
                            const float* __restrict__ bq, const float* __restrict__ bk,
                            unsigned short* o1, unsigned short* oqk,
                            unsigned short* ov, unsigned short* o3, float* obqk)
{
    int i = blockIdx.x * 256 + threadIdx.x;
    if (i < 65536) { o1[i] = f2bf(w1[i]); ov[i] = f2bf(wv[i]); o3[i] = f2bf(w3[i]); }
    if (i < 16384) oqk[i] = f2bf(i < 8192 ? wq[i] : wk[i - 8192]);
    if (i < 64)    obqk[i] = i < 32 ? bq[i] : bk[i - 32];
}

// per-(channel,batch) partial sums over c-major bf16 (B,256,Pn)
__global__ __launch_bounds__(256) void channel_stats_bf16(
    const unsigned short* __restrict__ Y, float* __restrict__ psum,
    float* __restrict__ psumsq, int Pn)
{
    const int o = blockIdx.x, b = blockIdx.y;
    const unsigned short* p = Y + ((size_t)b * 256 + o) * Pn;
    float s = 0.f, s2 = 0.f;
    for (int i = threadIdx.x * 8; i < Pn; i += 2048) {
        uint4 v = *(const uint4*)&p[i];
        unsigned uu[4] = {v.x, v.y, v.z, v.w};
#pragma unroll
        for (int k = 0; k < 4; k++) {
            float a = __builtin_bit_cast(float, uu[k] << 16);
            float c = __builtin_bit_cast(float, uu[k] & 0xffff0000u);
            s += a + c; s2 += a * a + c * c;
        }
    }
#pragma unroll
    for (int off = 32; off; off >>= 1) {
        s  += __shfl_down(s, off);
        s2 += __shfl_down(s2, off);
    }
    __shared__ float ws1[4], ws2[4];
    int lane = threadIdx.x & 63, w = threadIdx.x >> 6;
    if (lane == 0) { ws1[w] = s; ws2[w] = s2; }
    __syncthreads();
    if (threadIdx.x == 0) {
        float ts = 0.f, ts2 = 0.f;
#pragma unroll
        for (int k = 0; k < 4; k++) { ts += ws1[k]; ts2 += ws2[k]; }
        psum[(size_t)b * 256 + o] = ts;
        psumsq[(size_t)b * 256 + o] = ts2;
    }
}

// per-channel partials over p-major f32 (B,4096,256); grid (32, B)
__global__ __launch_bounds__(256) void stats_pmajor(
    const float* __restrict__ Y, float* __restrict__ psum, float* __restrict__ psumsq)
{
    const int chunk = blockIdx.x, b = blockIdx.y, c = threadIdx.x;
    const float* base = Y + ((size_t)b * 4096 + chunk * 128) * 256 + c;
    float s = 0.f, s2 = 0.f;
    for (int i = 0; i < 128; i++) { float v = base[(size_t)i * 256]; s += v; s2 += v * v; }
    psum[((size_t)b * 32 + chunk) * 256 + c] = s;
    psumsq[((size_t)b * 32 + chunk) * 256 + c] = s2;
}

__global__ void bn_finalize(const float* __restrict__ psum, const float* __restrict__ psumsq,
                            const float* __restrict__ g, const float* __restrict__ bb,
                            float* __restrict__ scale, float* __restrict__ shift,
                            float invN, int NP)
{
    int o = threadIdx.x;
    float s = 0.f, s2 = 0.f;
    for (int k = 0; k < NP; k++) { s += psum[k * 256 + o]; s2 += psumsq[k * 256 + o]; }
    float mean = s * invN;
    float var  = s2 * invN - mean * mean;
    float r = rsqrtf(var + EPS_BN);
    float sc = g[o] * r;
    scale[o] = sc;
    shift[o] = bb[o] - mean * sc;
}

// antialiased bilinear 2x downsample taps (jax.image.resize)
__device__ __forceinline__ int dtaps(int u, int* j, float* w) {
    if (u == 0)  { j[0]=0;   j[1]=1;   j[2]=2;   w[0]=3.f/7.f; w[1]=3.f/7.f; w[2]=1.f/7.f; return 3; }
    if (u == 63) { j[0]=125; j[1]=126; j[2]=127; w[0]=1.f/7.f; w[1]=3.f/7.f; w[2]=3.f/7.f; return 3; }
    j[0]=2*u-1; j[1]=2*u; j[2]=2*u+1; j[3]=2*u+2;
    w[0]=0.125f; w[1]=0.375f; w[2]=0.375f; w[3]=0.125f; return 4;
}

// BN + ReLU + 128->64 downsample; y1 bf16 c-major in, hs f32 c-major out
__global__ __launch_bounds__(256) void bnrelu_down(
    const unsigned short* __restrict__ y1, const float* __restrict__ scale,
    const float* __restrict__ shift, float* __restrict__ h)
{
    int i = blockIdx.x * 256 + threadIdx.x;  // 0..4095 over 64x64
    int o = blockIdx.y, b = blockIdx.z;
    int y2 = i >> 6, x2 = i & 63;
    const unsigned short* base = y1 + ((size_t)(b * 256 + o)) * 16384;
    float sc = scale[o], sh = shift[o];
    int jy[4]; float wy[4]; int ny = dtaps(y2, jy, wy);
    int jx[4]; float wx[4]; int nx = dtaps(x2, jx, wx);
    float acc = 0.f;
    for (int a = 0; a < ny; a++) {
        const unsigned short* row = base + jy[a] * 128;
        for (int c = 0; c < nx; c++) {
            float v = fmaxf(fmaf(sc, bf2f(row[jx[c]]), sh), 0.f);
            acc += wy[a] * wx[c] * v;
        }
    }
    h[((size_t)(b * 256 + o)) * 4096 + i] = acc;
}

// ---------------------------------------------------------------------------
// Split-K bf16 MFMA flash attention, S=4 chunks of 1024 keys.
// qkT (B,4096,64) bf16 (q cols 0..31, k cols 32..63); vb (B,256,4096) bf16.
// Per (i-tile, s, b) block: 16 KV tiles of 64; raw partials out.
// 512 thr = 8 waves: (wr=w>>1 -> rows i0+wr*16, wc=w&1 -> ch wc*128).
// Hoisted per-thread pointers; coalesced f32 epilogue via LDS bounce
// (reuses Vl as a 32row x 256ch f32 buffer, two half passes).
// ---------------------------------------------------------------------------
__global__ __launch_bounds__(512) void attn_partial(
    const unsigned short* __restrict__ qkT, const unsigned short* __restrict__ vb,
    float* __restrict__ accP, float2* __restrict__ mzP)
{
    const int s = blockIdx.y;
    const int b = blockIdx.z;
    const int i0 = blockIdx.x * 64;
    const int tid = threadIdx.x;
    const int w = tid >> 6, l = tid & 63;
    const int wr = w >> 1, wc = w & 1;
    const int lr = l & 15, lk = l >> 4;

    __shared__ unsigned short Kl[64 * 40];        // 5.0 KB
    __shared__ unsigned short Vl[256 * 64];       // 32.0 KB (swizzled; f32 bounce in epilogue)
    __shared__ unsigned short Pl[4][16 * 68];     // 8.5 KB (shared per wr)

    const unsigned short* qkTb = qkT + (size_t)b * 4096 * 64;
    // Q fragment (A): row = i0+wr*16+lr, k = lk*8..+7
    bf16x8 qf = *(const bf16x8*)&qkTb[(size_t)(i0 + wr * 16 + lr) * 64 + lk * 8];

    f32x4 acc[8];
#pragma unroll
    for (int i = 0; i < 8; i++) acc[i] = (f32x4){0.f, 0.f, 0.f, 0.f};
    float m[4], zp[4];
#pragma unroll
    for (int r = 0; r < 4; r++) { m[r] = -1e30f; zp[r] = 0.f; }

    const unsigned short* vbb = vb + (size_t)b * 256 * 4096;
    unsigned short* Pw = Pl[wr];

    const int jbase = s * 1024;
    // hoisted global pointers (advance per tile: K rows +64 -> +4096 shorts; V cols +64)
    const unsigned short* kPtr =
        qkTb + (size_t)(jbase + w * 16 + (l >> 2)) * 64 + 32 + (l & 3) * 8;
    const unsigned short* vPtr[4];
#pragma unroll
    for (int it = 0; it < 4; it++)
        vPtr[it] = vbb + (size_t)(w * 32 + it * 8 + (l >> 3)) * 4096 + jbase + (l & 7) * 8;

    // hoisted LDS addresses
    unsigned short* KlW = &Kl[(w * 16 + (l >> 2)) * 40 + (l & 3) * 8];
    unsigned short* VlW[4];
#pragma unroll
    for (int it = 0; it < 4; it++) {
        int ch = w * 32 + it * 8 + (l >> 3);
        VlW[it] = &Vl[ch * 64 + (((l & 7) ^ (ch & 7)) * 8)];
    }
    // V read bases: ch = wc*128 + ct*16 + lr -> ch&7 == lr&7; ct adds 1024 shorts
    const unsigned short* VrB[2];
#pragma unroll
    for (int kc = 0; kc < 2; kc++)
        VrB[kc] = &Vl[(wc * 128 + lr) * 64 + (((kc * 4 + lk) ^ (lr & 7)) * 8)];
    // P write base: addr = (lk*4+r)*68 + lr + 16*jt  (r,jt compile-time offsets)
    unsigned short* PwW = &Pw[lk * 4 * 68 + lr];
    const unsigned short* PrB[2] = { &Pw[lr * 68 + lk * 8], &Pw[lr * 68 + (4 + lk) * 8] };

    uint4 kreg, vreg[4];
#define LOAD_TILE                                                   \
    if (w < 4) { kreg = *(const uint4*)kPtr; kPtr += 4096; }        \
    _Pragma("unroll")                                               \
    for (int it = 0; it < 4; it++) { vreg[it] = *(const uint4*)vPtr[it]; vPtr[it] += 64; }

    LOAD_TILE
    for (int t = 0; t < 16; t++) {
        __syncthreads();   // prior tile's LDS reads complete
        if (w < 4) *(uint4*)KlW = kreg;
#pragma unroll
        for (int it = 0; it < 4; it++) *(uint4*)VlW[it] = vreg[it];
        __syncthreads();
        if (t < 15) { LOAD_TILE }   // prefetch next tile during compute

        // QK^T: 4 j-subtiles of 16
        f32x4 sv[4];
#pragma unroll
        for (int jt = 0; jt < 4; jt++) {
            bf16x8 kf = *(const bf16x8*)&Kl[(jt * 16 + lr) * 40 + lk * 8];
            sv[jt] = __builtin_amdgcn_mfma_f32_16x16x32_bf16(qf, kf, (f32x4){0.f,0.f,0.f,0.f}, 0, 0, 0);
        }

        // online softmax (rows R = lk*4+r; reduce over 16-lane group lr)
        bool grew = false;
        float corr[4], pv[4][4];
#pragma unroll
        for (int r = 0; r < 4; r++) {
            float tm = fmaxf(fmaxf(sv[0][r], sv[1][r]), fmaxf(sv[2][r], sv[3][r]));
#pragma unroll
            for (int off = 1; off < 16; off <<= 1) tm = fmaxf(tm, __shfl_xor(tm, off));
            float mo = m[r];
            float mn = fmaxf(mo, tm);
            bool g = tm > mo;
            corr[r] = g ? __expf(mo - mn) : 1.f;
            grew |= g;
            m[r] = mn;
            float ps = 0.f;
#pragma unroll
            for (int jt = 0; jt < 4; jt++) {
                float p = __expf(sv[jt][r] - mn);
                pv[jt][r] = p; ps += p;
            }
            zp[r] = zp[r] * corr[r] + ps;
        }
        if (__any(grew)) {
#pragma unroll
            for (int i = 0; i < 8; i++)
#pragma unroll
                for (int r = 0; r < 4; r++) acc[i][r] *= corr[r];
        }

        // P -> shared-per-wr LDS (both wc waves write identical values)
#pragma unroll
        for (int jt = 0; jt < 4; jt++)
#pragma unroll
            for (int r = 0; r < 4; r++)
                PwW[r * 68 + jt * 16] = f2bf(pv[jt][r]);

        // PV: 2 k-chunks x 8 channel subtiles (compile-time ct offsets)
#pragma unroll
        for (int kc = 0; kc < 2; kc++) {
            bf16x8 pa = *(const bf16x8*)PrB[kc];
#pragma unroll
            for (int ct = 0; ct < 8; ct++) {
                bf16x8 vf = *(const bf16x8*)(VrB[kc] + ct * 1024);
                acc[ct] = __builtin_amdgcn_mfma_f32_16x16x32_bf16(pa, vf, acc[ct], 0, 0, 0);
            }
        }
    }
#undef LOAD_TILE

    // z-reduce over the 16-lane group
    float zs[4];
#pragma unroll
    for (int r = 0; r < 4; r++) {
        float zz = zp[r];
#pragma unroll
        for (int off = 1; off < 16; off <<= 1) zz += __shfl_xor(zz, off);
        zs[r] = zz;
    }
    const size_t rbase0 = (size_t)(b * 4 + s) * 4096 + i0;
    if (wc == 0 && lr == 0) {
#pragma unroll
        for (int r = 0; r < 4; r++)
            mzP[rbase0 + wr * 16 + lk * 4 + r] = make_float2(m[r], zs[r]);
    }

    // coalesced epilogue: two 32-row passes through LDS (Vl reused as f32 buf)
    float* Eb = (float*)Vl;   // 8192 f32 = 32 rows x 256 ch
    __syncthreads();          // all Vl/Pl reads complete
#pragma unroll
    for (int h = 0; h < 2; h++) {
        if ((wr >> 1) == h) {
            int rloc = (wr & 1) * 16;
#pragma unroll
            for (int ct = 0; ct < 8; ct++)
#pragma unroll
                for (int r = 0; r < 4; r++)
                    Eb[(rloc + lk * 4 + r) * 256 + wc * 128 + ct * 16 + lr] = acc[ct][r];
        }
        __syncthreads();
        float4* dst = (float4*)(accP + (rbase0 + h * 32) * 256);
        const float4* srcv = (const float4*)Eb;
#pragma unroll
        for (int q = 0; q < 4; q++) dst[tid + q * 512] = srcv[tid + q * 512];
        __syncthreads();
    }
}

// merge S=4 chunk partials: out = gamma * (sum ws*acc)/(sum ws*z) + residual
// grid (512, B): 8 rows per block
__global__ __launch_bounds__(256) void attn_combine(
    const float* __restrict__ accP, const float2* __restrict__ mzP,
    const unsigned short* __restrict__ hst, const float* __restrict__ gamma_p,
    float* __restrict__ h2t)
{
    const int b = blockIdx.y, ch = threadIdx.x;
    const float gamma = gamma_p[0];
    for (int rr = 0; rr < 8; rr++) {
        int row = blockIdx.x * 8 + rr;
        float2 mz[4];
#pragma unroll
        for (int s = 0; s < 4; s++) mz[s] = mzP[(size_t)(b * 4 + s) * 4096 + row];
        float M = fmaxf(fmaxf(mz[0].x, mz[1].x), fmaxf(mz[2].x, mz[3].x));
        float Z = 0.f, a = 0.f;
#pragma unroll
        for (int s = 0; s < 4; s++) {
            float wgt = __expf(mz[s].x - M);
            Z += wgt * mz[s].y;
            a += wgt * accP[((size_t)(b * 4 + s) * 4096 + row) * 256 + ch];
        }
        size_t off = ((size_t)b * 4096 + row) * 256 + ch;
        h2t[off] = gamma * a / Z + bf2f(hst[off]);
    }
}

// BN2+ReLU fused with bilinear 64->128 upsample; p-major in/out
// grid (1024, B): 16 pixels per block
__global__ __launch_bounds__(256) void upsample_bnrelu(
    const float* __restrict__ h2t, const float* __restrict__ scale,
    const float* __restrict__ shift, unsigned short* __restrict__ upn)
{
    const int b = blockIdx.y, c = threadIdx.x;
    const float* basep = h2t + ((size_t)b * 4096) * 256 + c;
    float sc = scale[c], sh = shift[c];
    for (int pp = 0; pp < 16; pp++) {
        int p = blockIdx.x * 16 + pp;
        int y = p >> 7, x = p & 127;
        float fy = 0.5f * y - 0.25f, fx = 0.5f * x - 0.25f;
        float fiy = floorf(fy), fix = floorf(fx);
        float wy = fy - fiy, wx = fx - fix;
        int iy = (int)fiy, ix = (int)fix;
        int iy0 = max(iy, 0), iy1 = min(iy + 1, 63);
        int ix0 = max(ix, 0), ix1 = min(ix + 1, 63);
        float v00 = fmaxf(fmaf(sc, basep[(size_t)(iy0 * 64 + ix0) * 256], sh), 0.f);
        float v01 = fmaxf(fmaf(sc, basep[(size_t)(iy0 * 64 + ix1) * 256], sh), 0.f);
        float v10 = fmaxf(fmaf(sc, basep[(size_t)(iy1 * 64 + ix0) * 256], sh), 0.f);
        float v11 = fmaxf(fmaf(sc, basep[(size_t)(iy1 * 64 + ix1) * 256], sh), 0.f);
        float r0 = (1.f - wy) * ((1.f - wx) * v00 + wx * v01)
                 + wy * ((1.f - wx) * v10 + wx * v11);
        upn[((size_t)b * 16384 + p) * 256 + c] = f2bf(r0);
    }
}

// out = relu(bn3(y3) + x); y3 bf16 c-major
__global__ __launch_bounds__(256) void final_add_relu(
    const unsigned short* __restrict__ y3, const float* __restrict__ scale,
    const float* __restrict__ shift, const float* __restrict__ x,
    float* __restrict__ outp)
{
    size_t e = ((size_t)blockIdx.x * 256 + threadIdx.x) * 4;
    int c = (int)((e >> 14) & 255);
    ushort4 yv = *(const ushort4*)&y3[e];
    float4 xv = *(const float4*)&x[e];
    float sc = scale[c], sh = shift[c];
    float4 o;
    o.x = fmaxf(fmaf(sc, bf2f(yv.x), sh) + xv.x, 0.f);
    o.y = fmaxf(fmaf(sc, bf2f(yv.y), sh) + xv.y, 0.f);
    o.z = fmaxf(fmaf(sc, bf2f(yv.z), sh) + xv.z, 0.f);
    o.w = fmaxf(fmaf(sc, bf2f(yv.w), sh) + xv.w, 0.f);
    *(float4*)&outp[e] = o;
}

extern "C" void kernel_launch(void* const* d_in, const int* in_sizes, int n_in,
                              void* d_out, int out_size, void* d_ws, size_t ws_size,
                              hipStream_t stream)
{
    const float* x     = (const float*)d_in[0];
    const float* w1    = (const float*)d_in[1];
    const float* g1    = (const float*)d_in[2];
    const float* b1    = (const float*)d_in[3];
    const float* wq    = (const float*)d_in[4];
    const float* bq    = (const float*)d_in[5];
    const float* wk    = (const float*)d_in[6];
    const float* bk    = (const float*)d_in[7];
    const float* wv    = (const float*)d_in[8];
    const float* bv    = (const float*)d_in[9];
    const float* gamma = (const float*)d_in[10];
    const float* g2    = (const float*)d_in[11];
    const float* b2    = (const float*)d_in[12];
    const float* w3    = (const float*)d_in[13];
    const float* g3    = (const float*)d_in[14];
    const float* b3    = (const float*)d_in[15];
    float* out = (float*)d_out;

    char* wsb = (char*)d_ws;
    unsigned short* y1b = (unsigned short*)wsb;                        // 0-32 (later y3b)
    unsigned short* xt  = (unsigned short*)(wsb + ((size_t)32 << 20)); // 32-64 (later upn)
    float* accP = (float*)wsb;                                         // 0-64 during attn
    float* hs   = (float*)(wsb + ((size_t)64 << 20));                  // 64-80 (later h2t)
    unsigned short* vbb = (unsigned short*)(wsb + ((size_t)80 << 20)); // 80-88
    unsigned short* hst = (unsigned short*)(wsb + ((size_t)88 << 20)); // 88-96
    unsigned short* qkT = (unsigned short*)(wsb + ((size_t)96 << 20)); // 96-98
    unsigned short* w1b = (unsigned short*)(wsb + ((size_t)98 << 20));
    unsigned short* wvb  = w1b + 65536;
    unsigned short* w3b  = wvb + 65536;
    unsigned short* wqkb = w3b + 65536;
    float* bqk = (float*)(wqkb + 16384);
    float2* mzP = (float2*)(wsb + ((size_t)98 << 20) + ((size_t)512 << 10));
    float* psum   = (float*)(wsb + ((size_t)99 << 20));
    float* psumsq = psum + 32768;
    float* sc1 = psumsq + 32768; float* sh1 = sc1 + 256;
    float* sc2 = sh1 + 256;      float* sh2 = sc2 + 256;
    float* sc3 = sh2 + 256;      float* sh3 = sc3 + 256;
    unsigned short* y3b = y1b;
    unsigned short* upn = xt;
    float* h2t = hs;

    cvt_weights<<<256, 256, 0, stream>>>(w1, wq, wk, wv, w3, bq, bk,
                                         w1b, wqkb, wvb, w3b, bqk);
    transpose_cvt<<<dim3(256, 4, 4), 256, 0, stream>>>(x, xt, 16384);

    // net1: conv1 (MFMA) -> BN stats -> BN+ReLU+down
    gemm_mfma<128, 2><<<dim3(128, 2, 4), 256, 0, stream>>>(w1b, xt, nullptr, y1b, 16384, 256);
    channel_stats_bf16<<<dim3(256, 4), 256, 0, stream>>>(y1b, psum, psumsq, 16384);
    bn_finalize<<<1, 256, 0, stream>>>(psum, psumsq, g1, b1, sc1, sh1, 1.f / 65536.f, 4);
    bnrelu_down<<<dim3(16, 256, 4), 256, 0, stream>>>(y1b, sc1, sh1, hs);
    transpose_cvt<<<dim3(64, 4, 4), 256, 0, stream>>>(hs, hst, 4096);

    // net2: merged qk projection + v projection + split-K attention + combine
    gemm_mfma<64, 1><<<dim3(32, 1, 4), 256, 0, stream>>>(wqkb, hst, bqk, qkT, 4096, 64);
    gemm_mfma<128, 2><<<dim3(32, 2, 4), 256, 0, stream>>>(wvb, hst, bv, vbb, 4096, 256);
    attn_partial<<<dim3(64, 4, 4), 512, 0, stream>>>(qkT, vbb, accP, mzP);
    attn_combine<<<dim3(512, 4), 256, 0, stream>>>(accP, mzP, hst, gamma, h2t);

    // net2 tail: BN2 + ReLU fused into upsample
    stats_pmajor<<<dim3(32, 4), 256, 0, stream>>>(h2t, psum, psumsq);
    bn_finalize<<<1, 256, 0, stream>>>(psum, psumsq, g2, b2, sc2, sh2, 1.f / 16384.f, 128);
    upsample_bnrelu<<<dim3(1024, 4), 256, 0, stream>>>(h2t, sc2, sh2, upn);

    // net3: conv3 (MFMA) -> BN3 + residual + ReLU
    gemm_mfma<128, 2><<<dim3(128, 2, 4), 256, 0, stream>>>(w3b, upn, nullptr, y3b, 16384, 256);
    channel_stats_bf16<<<dim3(256, 4), 256, 0, stream>>>(y3b, psum, psumsq, 16384);
    bn_finalize<<<1, 256, 0, stream>>>(psum, psumsq, g3, b3, sc3, sh3, 1.f / 65536.f, 4);
    final_add_relu<<<16384, 256, 0, stream>>>(y3b, sc3, sh3, x, out);
}

// Round 7
// 425.231 us; speedup vs baseline: 3.0917x; 1.0338x over previous
//
#include <hip/hip_runtime.h>
#include <hip/hip_bf16.h>

// B=4, C=256, C8=32, H=128, W=128, H2=W2=64, N=4096, HW=16384
#define EPS_BN 1e-5f

typedef short bf16x8 __attribute__((ext_vector_type(8)));
typedef float f32x4 __attribute__((ext_vector_type(4)));

__device__ __forceinline__ unsigned short f2bf(float f) {
    __hip_bfloat16 h = __float2bfloat16(f);
    return __builtin_bit_cast(unsigned short, h);
}
__device__ __forceinline__ float bf2f(unsigned short u) {
    return __builtin_bit_cast(float, (unsigned)u << 16);
}

// ---------------------------------------------------------------------------
// bf16 MFMA GEMM: Y[b,o,p] = sum_c Wb[o,c] * Xt[b,p,c]  (K=256 fixed)
// BM in {128,64,32}; BN=128; BK=32; 256 threads (4 waves), 2-phase prefetch,
// hoisted per-thread pointers (+32/step).
// MODE 1: bf16 p-major out (B,P,O) + bias  (q/k merged projection)
// MODE 2: bf16 c-major out (B,256,P) + optional bias (conv1/conv3/v)
// ---------------------------------------------------------------------------
template<int BM, int MODE>
__global__ __launch_bounds__(256) void gemm_mfma(
    const unsigned short* __restrict__ Wb,   // (O,256) bf16
    const unsigned short* __restrict__ Xt,   // (B,P,256) bf16
    const float* __restrict__ bias,
    unsigned short* __restrict__ Y,
    int P, int O)
{
    const int tid = threadIdx.x;
    const int w = tid >> 6, l = tid & 63;
    const int b = blockIdx.z;
    const int p0 = blockIdx.x * 128;
    const int o0 = blockIdx.y * BM;
    const int lr = l & 15, lk = l >> 4;
    const int srow = l >> 2, sq = l & 3;     // staging: 16 rows x 4 chunks / wave

    __shared__ unsigned short Al[BM * 40];
    __shared__ unsigned short Bl[128 * 40];

    constexpr int WC = (BM == 32) ? 4 : 2;            // waves along p
    constexpr int MT = (BM == 128) ? 4 : 2;           // o-subtiles / wave
    constexpr int NT = (WC == 2) ? 4 : 2;             // p-subtiles / wave
    const int wr = w / WC, wc = w % WC;
    const int osub = wr * MT * 16, psub = wc * NT * 16;

    f32x4 acc[MT][NT];
#pragma unroll
    for (int i = 0; i < MT; i++)
#pragma unroll
        for (int j = 0; j < NT; j++) acc[i][j] = (f32x4){0.f, 0.f, 0.f, 0.f};

    const unsigned short* Xb = Xt + (size_t)b * P * 256;
    const int ar0 = w * 16, ar1 = w * 16 + 64;   // A rows staged by this wave
    const int br0 = w * 16, br1 = w * 16 + 64;   // B rows staged by this wave

    // hoisted pointers
    const unsigned short* pB0 = Xb + (size_t)(p0 + br0 + srow) * 256 + sq * 8;
    const unsigned short* pB1 = Xb + (size_t)(p0 + br1 + srow) * 256 + sq * 8;
    const unsigned short* pA0 = Wb + (size_t)(o0 + ar0 + srow) * 256 + sq * 8;
    const unsigned short* pA1 = Wb + (size_t)(o0 + ar1 + srow) * 256 + sq * 8;
    unsigned short* BlW0 = &Bl[(br0 + srow) * 40 + sq * 8];
    unsigned short* BlW1 = &Bl[(br1 + srow) * 40 + sq * 8];
    unsigned short* AlW0 = &Al[(ar0 + srow) * 40 + sq * 8];
    unsigned short* AlW1 = &Al[(ar1 + srow) * 40 + sq * 8];

    uint4 vb0, vb1, va0, va1;
#define G_LOADS                                                     \
    vb0 = *(const uint4*)pB0; pB0 += 32;                            \
    vb1 = *(const uint4*)pB1; pB1 += 32;                            \
    if (ar0 < BM) { va0 = *(const uint4*)pA0; pA0 += 32; }          \
    if (ar1 < BM) { va1 = *(const uint4*)pA1; pA1 += 32; }

    G_LOADS
    for (int k0 = 0; k0 < 256; k0 += 32) {
        __syncthreads();   // prior k-step's LDS reads complete
        *(uint4*)BlW0 = vb0;
        *(uint4*)BlW1 = vb1;
        if (ar0 < BM) *(uint4*)AlW0 = va0;
        if (ar1 < BM) *(uint4*)AlW1 = va1;
        __syncthreads();   // staging visible
        if (k0 < 224) { G_LOADS }   // prefetch next, in flight during MFMA
        bf16x8 af[MT], bfr[NT];
#pragma unroll
        for (int i = 0; i < MT; i++) {
            int row = osub + i * 16 + lr;
            af[i] = *(const bf16x8*)&Al[row * 40 + lk * 8];
        }
#pragma unroll
        for (int j = 0; j < NT; j++) {
            int row = psub + j * 16 + lr;
            bfr[j] = *(const bf16x8*)&Bl[row * 40 + lk * 8];
        }
#pragma unroll
        for (int i = 0; i < MT; i++)
#pragma unroll
            for (int j = 0; j < NT; j++)
                acc[i][j] = __builtin_amdgcn_mfma_f32_16x16x32_bf16(af[i], bfr[j], acc[i][j], 0, 0, 0);
    }
#undef G_LOADS

    // epilogue; C/D: col = lane&15 (p), row = (lane>>4)*4 + reg (o)
    if (MODE == 1) {
#pragma unroll
        for (int i = 0; i < MT; i++) {
            int ob = o0 + osub + i * 16 + lk * 4;
#pragma unroll
            for (int j = 0; j < NT; j++) {
                int p = p0 + psub + j * 16 + lr;
                ushort4 pk;
                pk.x = f2bf(acc[i][j][0] + bias[ob + 0]);
                pk.y = f2bf(acc[i][j][1] + bias[ob + 1]);
                pk.z = f2bf(acc[i][j][2] + bias[ob + 2]);
                pk.w = f2bf(acc[i][j][3] + bias[ob + 3]);
                *(ushort4*)&Y[((size_t)b * P + p) * O + ob] = pk;
            }
        }
    } else {
#pragma unroll
        for (int i = 0; i < MT; i++)
#pragma unroll
            for (int r = 0; r < 4; r++) {
                int o = o0 + osub + i * 16 + lk * 4 + r;
                float bs = bias ? bias[o] : 0.f;
#pragma unroll
                for (int j = 0; j < NT; j++) {
                    int p = p0 + psub + j * 16 + lr;
                    Y[((size_t)(b * 256 + o)) * P + p] = f2bf(acc[i][j][r] + bs);
                }
            }
    }
}

// ---------------------------------------------------------------------------
// LDS-tiled transpose + cvt: (B,256,P) f32 -> (B,P,256) bf16
// ---------------------------------------------------------------------------
__global__ __launch_bounds__(256) void transpose_cvt(
    const float* __restrict__ src, unsigned short* __restrict__ dst, int P)
{
    __shared__ float t[64][65];
    const int tid = threadIdx.x;
    const int p0 = blockIdx.x * 64, c0 = blockIdx.y * 64, b = blockIdx.z;
    const float* sb = src + ((size_t)b * 256 + c0) * P + p0;
#pragma unroll
    for (int i = 0; i < 16; i++) {
        int r = (tid >> 6) + 4 * i;   // c-local
        int c = tid & 63;             // p-local
        t[c][r] = sb[(size_t)r * P + c];
    }
    __syncthreads();
#pragma unroll
    for (int i = 0; i < 8; i++) {
        int pr = (tid >> 5) + 8 * i;
        int cc = (tid & 31) * 2;
        unsigned pk = ((unsigned)f2bf(t[pr][cc + 1]) << 16) | f2bf(t[pr][cc]);
        *(unsigned*)&dst[((size_t)b * P + p0 + pr) * 256 + c0 + cc] = pk;
    }
}

__global__ void cvt_weights(const float* __restrict__ w1, const float* __restrict__ wq,
                            const float* __restrict__ wk, const float* __restrict__ wv,
                            const float* __restrict__ w3,
                            const float* __restrict__ bq, const float* __restrict__ bk,
                            unsigned short* o1, unsigned short* oqk,
                            unsigned short* ov, unsigned short* o3, float* obqk)
{
    int i = blockIdx.x * 256 + threadIdx.x;
    if (i < 65536) { o1[i] = f2bf(w1[i]); ov[i] = f2bf(wv[i]); o3[i] = f2bf(w3[i]); }
    if (i < 16384) oqk[i] = f2bf(i < 8192 ? wq[i] : wk[i - 8192]);
    if (i < 64)    obqk[i] = i < 32 ? bq[i] : bk[i - 32];
}

// per-(channel,batch) partial sums over c-major bf16 (B,256,Pn)
__global__ __launch_bounds__(256) void channel_stats_bf16(
    const unsigned short* __restrict__ Y, float* __restrict__ psum,
    float* __restrict__ psumsq, int Pn)
{
    const int o = blockIdx.x, b = blockIdx.y;
    const unsigned short* p = Y + ((size_t)b * 256 + o) * Pn;
    float s = 0.f, s2 = 0.f;
    for (int i = threadIdx.x * 8; i < Pn; i += 2048) {
        uint4 v = *(const uint4*)&p[i];
        unsigned uu[4] = {v.x, v.y, v.z, v.w};
#pragma unroll
        for (int k = 0; k < 4; k++) {
            float a = __builtin_bit_cast(float, uu[k] << 16);
            float c = __builtin_bit_cast(float, uu[k] & 0xffff0000u);
            s += a + c; s2 += a * a + c * c;
        }
    }
#pragma unroll
    for (int off = 32; off; off >>= 1) {
        s  += __shfl_down(s, off);
        s2 += __shfl_down(s2, off);
    }
    __shared__ float ws1[4], ws2[4];
    int lane = threadIdx.x & 63, w = threadIdx.x >> 6;
    if (lane == 0) { ws1[w] = s; ws2[w] = s2; }
    __syncthreads();
    if (threadIdx.x == 0) {
        float ts = 0.f, ts2 = 0.f;
#pragma unroll
        for (int k = 0; k < 4; k++) { ts += ws1[k]; ts2 += ws2[k]; }
        psum[(size_t)b * 256 + o] = ts;
        psumsq[(size_t)b * 256 + o] = ts2;
    }
}

// per-channel partials over p-major f32 (B,4096,256); grid (32, B)
__global__ __launch_bounds__(256) void stats_pmajor(
    const float* __restrict__ Y, float* __restrict__ psum, float* __restrict__ psumsq)
{
    const int chunk = blockIdx.x, b = blockIdx.y, c = threadIdx.x;
    const float* base = Y + ((size_t)b * 4096 + chunk * 128) * 256 + c;
    float s = 0.f, s2 = 0.f;
    for (int i = 0; i < 128; i++) { float v = base[(size_t)i * 256]; s += v; s2 += v * v; }
    psum[((size_t)b * 32 + chunk) * 256 + c] = s;
    psumsq[((size_t)b * 32 + chunk) * 256 + c] = s2;
}

__global__ void bn_finalize(const float* __restrict__ psum, const float* __restrict__ psumsq,
                            const float* __restrict__ g, const float* __restrict__ bb,
                            float* __restrict__ scale, float* __restrict__ shift,
                            float invN, int NP)
{
    int o = threadIdx.x;
    float s = 0.f, s2 = 0.f;
    for (int k = 0; k < NP; k++) { s += psum[k * 256 + o]; s2 += psumsq[k * 256 + o]; }
    float mean = s * invN;
    float var  = s2 * invN - mean * mean;
    float r = rsqrtf(var + EPS_BN);
    float sc = g[o] * r;
    scale[o] = sc;
    shift[o] = bb[o] - mean * sc;
}

// antialiased bilinear 2x downsample taps (jax.image.resize)
__device__ __forceinline__ int dtaps(int u, int* j, float* w) {
    if (u == 0)  { j[0]=0;   j[1]=1;   j[2]=2;   w[0]=3.f/7.f; w[1]=3.f/7.f; w[2]=1.f/7.f; return 3; }
    if (u == 63) { j[0]=125; j[1]=126; j[2]=127; w[0]=1.f/7.f; w[1]=3.f/7.f; w[2]=3.f/7.f; return 3; }
    j[0]=2*u-1; j[1]=2*u; j[2]=2*u+1; j[3]=2*u+2;
    w[0]=0.125f; w[1]=0.375f; w[2]=0.375f; w[3]=0.125f; return 4;
}

// BN + ReLU + 128->64 downsample; y1 bf16 c-major in, hs f32 c-major out
__global__ __launch_bounds__(256) void bnrelu_down(
    const unsigned short* __restrict__ y1, const float* __restrict__ scale,
    const float* __restrict__ shift, float* __restrict__ h)
{
    int i = blockIdx.x * 256 + threadIdx.x;  // 0..4095 over 64x64
    int o = blockIdx.y, b = blockIdx.z;
    int y2 = i >> 6, x2 = i & 63;
    const unsigned short* base = y1 + ((size_t)(b * 256 + o)) * 16384;
    float sc = scale[o], sh = shift[o];
    int jy[4]; float wy[4]; int ny = dtaps(y2, jy, wy);
    int jx[4]; float wx[4]; int nx = dtaps(x2, jx, wx);
    float acc = 0.f;
    for (int a = 0; a < ny; a++) {
        const unsigned short* row = base + jy[a] * 128;
        for (int c = 0; c < nx; c++) {
            float v = fmaxf(fmaf(sc, bf2f(row[jx[c]]), sh), 0.f);
            acc += wy[a] * wx[c] * v;
        }
    }
    h[((size_t)(b * 256 + o)) * 4096 + i] = acc;
}

// ---------------------------------------------------------------------------
// Split-K bf16 MFMA flash attention, S=4 chunks of 1024 keys.
// qkT (B,4096,64) bf16 (q cols 0..31, k cols 32..63); vb (B,256,4096) bf16.
// Per (i-tile, s, b) block: 16 KV tiles of 64; partials out (bf16 acc + f32 mz).
// 512 thr = 8 waves: (wr=w>>1 -> rows i0+wr*16, wc=w&1 -> ch wc*128).
// __launch_bounds__(512,2): 256-VGPR budget -> NO scratch spills (round-6
// lesson: spill traffic was the 290MB/dispatch HBM write leak).
// Addresses recomputed inline; P written to LDS as computed (no pv array).
// ---------------------------------------------------------------------------
__global__ __launch_bounds__(512, 2) void attn_partial(
    const unsigned short* __restrict__ qkT, const unsigned short* __restrict__ vb,
    unsigned short* __restrict__ accP, float2* __restrict__ mzP)
{
    const int s = blockIdx.y;
    const int b = blockIdx.z;
    const int i0 = blockIdx.x * 64;
    const int tid = threadIdx.x;
    const int w = tid >> 6, l = tid & 63;
    const int wr = w >> 1, wc = w & 1;
    const int lr = l & 15, lk = l >> 4;

    __shared__ unsigned short Kl[64 * 40];        // 5.0 KB
    __shared__ unsigned short Vl[256 * 64];       // 32.0 KB (swizzled; f32 bounce in epilogue)
    __shared__ unsigned short Pl[4][16 * 68];     // 8.5 KB (shared per wr)

    const unsigned short* qkTb = qkT + (size_t)b * 4096 * 64;
    // Q fragment (A): row = i0+wr*16+lr, k = lk*8..+7
    bf16x8 qf = *(const bf16x8*)&qkTb[(size_t)(i0 + wr * 16 + lr) * 64 + lk * 8];

    f32x4 acc[8];
#pragma unroll
    for (int i = 0; i < 8; i++) acc[i] = (f32x4){0.f, 0.f, 0.f, 0.f};
    float m[4], zp[4];
#pragma unroll
    for (int r = 0; r < 4; r++) { m[r] = -1e30f; zp[r] = 0.f; }

    const int jbase = s * 1024;
    // per-thread global pointers, bumped by constants per tile
    const unsigned short* kPtr =
        qkTb + (size_t)(jbase + w * 16 + (l >> 2)) * 64 + 32 + (l & 3) * 8;
    const unsigned short* vPtr =
        vb + (size_t)b * 256 * 4096 + (size_t)(w * 32 + (l >> 3)) * 4096 + jbase + (l & 7) * 8;
    unsigned short* Pw = Pl[wr];

    uint4 kreg, vreg[4];
    if (w < 4) kreg = *(const uint4*)kPtr;
#pragma unroll
    for (int it = 0; it < 4; it++) vreg[it] = *(const uint4*)(vPtr + it * 32768);

    for (int t = 0; t < 16; t++) {
        __syncthreads();   // prior tile's LDS reads complete
        if (w < 4) *(uint4*)&Kl[(w * 16 + (l >> 2)) * 40 + (l & 3) * 8] = kreg;
#pragma unroll
        for (int it = 0; it < 4; it++) {
            int ch = w * 32 + it * 8 + (l >> 3);
            *(uint4*)&Vl[ch * 64 + (((l & 7) ^ (ch & 7)) * 8)] = vreg[it];
        }
        __syncthreads();
        if (t < 15) {   // prefetch next tile during compute
            kPtr += 4096; vPtr += 64;
            if (w < 4) kreg = *(const uint4*)kPtr;
#pragma unroll
            for (int it = 0; it < 4; it++) vreg[it] = *(const uint4*)(vPtr + it * 32768);
        }

        // QK^T: 4 j-subtiles of 16
        f32x4 sv[4];
#pragma unroll
        for (int jt = 0; jt < 4; jt++) {
            bf16x8 kf = *(const bf16x8*)&Kl[(jt * 16 + lr) * 40 + lk * 8];
            sv[jt] = __builtin_amdgcn_mfma_f32_16x16x32_bf16(qf, kf, (f32x4){0.f,0.f,0.f,0.f}, 0, 0, 0);
        }

        // online softmax (rows R = lk*4+r; reduce over 16-lane group);
        // P written to LDS as computed (no transient array)
        bool grew = false;
        float corr[4];
#pragma unroll
        for (int r = 0; r < 4; r++) {
            float tm = fmaxf(fmaxf(sv[0][r], sv[1][r]), fmaxf(sv[2][r], sv[3][r]));
#pragma unroll
            for (int off = 1; off < 16; off <<= 1) tm = fmaxf(tm, __shfl_xor(tm, off));
            float mo = m[r];
            float mn = fmaxf(mo, tm);
            bool g = tm > mo;
            corr[r] = g ? __expf(mo - mn) : 1.f;
            grew |= g;
            m[r] = mn;
            float ps = 0.f;
#pragma unroll
            for (int jt = 0; jt < 4; jt++) {
                float p = __expf(sv[jt][r] - mn);
                ps += p;
                Pw[(lk * 4 + r) * 68 + lr + jt * 16] = f2bf(p);
            }
            zp[r] = zp[r] * corr[r] + ps;
        }
        if (__any(grew)) {
#pragma unroll
            for (int i = 0; i < 8; i++)
#pragma unroll
                for (int r = 0; r < 4; r++) acc[i][r] *= corr[r];
        }

        // PV: 2 k-chunks x 8 channel subtiles (V read with matching swizzle)
#pragma unroll
        for (int kc = 0; kc < 2; kc++) {
            bf16x8 pa = *(const bf16x8*)&Pw[lr * 68 + (kc * 4 + lk) * 8];
#pragma unroll
            for (int ct = 0; ct < 8; ct++) {
                int ch = wc * 128 + ct * 16 + lr;
                bf16x8 vf = *(const bf16x8*)&Vl[ch * 64 + (((kc * 4 + lk) ^ (lr & 7)) * 8)];
                acc[ct] = __builtin_amdgcn_mfma_f32_16x16x32_bf16(pa, vf, acc[ct], 0, 0, 0);
            }
        }
    }

    // z-reduce over the 16-lane group
    float zs[4];
#pragma unroll
    for (int r = 0; r < 4; r++) {
        float zz = zp[r];
#pragma unroll
        for (int off = 1; off < 16; off <<= 1) zz += __shfl_xor(zz, off);
        zs[r] = zz;
    }
    const size_t rbase0 = (size_t)(b * 4 + s) * 4096 + i0;
    if (wc == 0 && lr == 0) {
#pragma unroll
        for (int r = 0; r < 4; r++)
            mzP[rbase0 + wr * 16 + lk * 4 + r] = make_float2(m[r], zs[r]);
    }

    // coalesced bf16 epilogue: two 32-row passes through LDS (Vl reused f32)
    float* Eb = (float*)Vl;   // 8192 f32 = 32 rows x 256 ch
    __syncthreads();          // all Vl/Pl reads complete
#pragma unroll
    for (int h = 0; h < 2; h++) {
        if ((wr >> 1) == h) {
            int rloc = (wr & 1) * 16;
#pragma unroll
            for (int ct = 0; ct < 8; ct++)
#pragma unroll
                for (int r = 0; r < 4; r++)
                    Eb[(rloc + lk * 4 + r) * 256 + wc * 128 + ct * 16 + lr] = acc[ct][r];
        }
        __syncthreads();
        unsigned short* dst = accP + (rbase0 + h * 32) * 256;
#pragma unroll
        for (int q = 0; q < 4; q++) {
            float4 v = ((const float4*)Eb)[tid + q * 512];
            ushort4 pk = { f2bf(v.x), f2bf(v.y), f2bf(v.z), f2bf(v.w) };
            *(ushort4*)&dst[(tid + q * 512) * 4] = pk;
        }
        __syncthreads();
    }
}

// merge S=4 chunk partials: out = gamma * (sum ws*acc)/(sum ws*z) + residual
// grid (512, B): 8 rows per block
__global__ __launch_bounds__(256) void attn_combine(
    const unsigned short* __restrict__ accP, const float2* __restrict__ mzP,
    const unsigned short* __restrict__ hst, const float* __restrict__ gamma_p,
    float* __restrict__ h2t)
{
    const int b = blockIdx.y, ch = threadIdx.x;
    const float gamma = gamma_p[0];
    for (int rr = 0; rr < 8; rr++) {
        int row = blockIdx.x * 8 + rr;
        float2 mz[4];
#pragma unroll
        for (int s = 0; s < 4; s++) mz[s] = mzP[(size_t)(b * 4 + s) * 4096 + row];
        float M = fmaxf(fmaxf(mz[0].x, mz[1].x), fmaxf(mz[2].x, mz[3].x));
        float Z = 0.f, a = 0.f;
#pragma unroll
        for (int s = 0; s < 4; s++) {
            float wgt = __expf(mz[s].x - M);
            Z += wgt * mz[s].y;
            a += wgt * bf2f(accP[((size_t)(b * 4 + s) * 4096 + row) * 256 + ch]);
        }
        size_t off = ((size_t)b * 4096 + row) * 256 + ch;
        h2t[off] = gamma * a / Z + bf2f(hst[off]);
    }
}

// BN2+ReLU fused with bilinear 64->128 upsample; p-major in/out
// grid (1024, B): 16 pixels per block
__global__ __launch_bounds__(256) void upsample_bnrelu(
    const float* __restrict__ h2t, const float* __restrict__ scale,
    const float* __restrict__ shift, unsigned short* __restrict__ upn)
{
    const int b = blockIdx.y, c = threadIdx.x;
    const float* basep = h2t + ((size_t)b * 4096) * 256 + c;
    float sc = scale[c], sh = shift[c];
    for (int pp = 0; pp < 16; pp++) {
        int p = blockIdx.x * 16 + pp;
        int y = p >> 7, x = p & 127;
        float fy = 0.5f * y - 0.25f, fx = 0.5f * x - 0.25f;
        float fiy = floorf(fy), fix = floorf(fx);
        float wy = fy - fiy, wx = fx - fix;
        int iy = (int)fiy, ix = (int)fix;
        int iy0 = max(iy, 0), iy1 = min(iy + 1, 63);
        int ix0 = max(ix, 0), ix1 = min(ix + 1, 63);
        float v00 = fmaxf(fmaf(sc, basep[(size_t)(iy0 * 64 + ix0) * 256], sh), 0.f);
        float v01 = fmaxf(fmaf(sc, basep[(size_t)(iy0 * 64 + ix1) * 256], sh), 0.f);
        float v10 = fmaxf(fmaf(sc, basep[(size_t)(iy1 * 64 + ix0) * 256], sh), 0.f);
        float v11 = fmaxf(fmaf(sc, basep[(size_t)(iy1 * 64 + ix1) * 256], sh), 0.f);
        float r0 = (1.f - wy) * ((1.f - wx) * v00 + wx * v01)
                 + wy * ((1.f - wx) * v10 + wx * v11);
        upn[((size_t)b * 16384 + p) * 256 + c] = f2bf(r0);
    }
}

// out = relu(bn3(y3) + x); y3 bf16 c-major
__global__ __launch_bounds__(256) void final_add_relu(
    const unsigned short* __restrict__ y3, const float* __restrict__ scale,
    const float* __restrict__ shift, const float* __restrict__ x,
    float* __restrict__ outp)
{
    size_t e = ((size_t)blockIdx.x * 256 + threadIdx.x) * 4;
    int c = (int)((e >> 14) & 255);
    ushort4 yv = *(const ushort4*)&y3[e];
    float4 xv = *(const float4*)&x[e];
    float sc = scale[c], sh = shift[c];
    float4 o;
    o.x = fmaxf(fmaf(sc, bf2f(yv.x), sh) + xv.x, 0.f);
    o.y = fmaxf(fmaf(sc, bf2f(yv.y), sh) + xv.y, 0.f);
    o.z = fmaxf(fmaf(sc, bf2f(yv.z), sh) + xv.z, 0.f);
    o.w = fmaxf(fmaf(sc, bf2f(yv.w), sh) + xv.w, 0.f);
    *(float4*)&outp[e] = o;
}

extern "C" void kernel_launch(void* const* d_in, const int* in_sizes, int n_in,
                              void* d_out, int out_size, void* d_ws, size_t ws_size,
                              hipStream_t stream)
{
    const float* x     = (const float*)d_in[0];
    const float* w1    = (const float*)d_in[1];
    const float* g1    = (const float*)d_in[2];
    const float* b1    = (const float*)d_in[3];
    const float* wq    = (const float*)d_in[4];
    const float* bq    = (const float*)d_in[5];
    const float* wk    = (const float*)d_in[6];
    const float* bk    = (const float*)d_in[7];
    const float* wv    = (const float*)d_in[8];
    const float* bv    = (const float*)d_in[9];
    const float* gamma = (const float*)d_in[10];
    const float* g2    = (const float*)d_in[11];
    const float* b2    = (const float*)d_in[12];
    const float* w3    = (const float*)d_in[13];
    const float* g3    = (const float*)d_in[14];
    const float* b3    = (const float*)d_in[15];
    float* out = (float*)d_out;

    char* wsb = (char*)d_ws;
    unsigned short* y1b = (unsigned short*)wsb;                        // 0-32 (later y3b)
    unsigned short* xt  = (unsigned short*)(wsb + ((size_t)32 << 20)); // 32-64 (later upn)
    unsigned short* accPb = (unsigned short*)wsb;                      // 0-32 during attn (bf16)
    float* hs   = (float*)(wsb + ((size_t)64 << 20));                  // 64-80 (later h2t)
    unsigned short* vbb = (unsigned short*)(wsb + ((size_t)80 << 20)); // 80-88
    unsigned short* hst = (unsigned short*)(wsb + ((size_t)88 << 20)); // 88-96
    unsigned short* qkT = (unsigned short*)(wsb + ((size_t)96 << 20)); // 96-98
    unsigned short* w1b = (unsigned short*)(wsb + ((size_t)98 << 20));
    unsigned short* wvb  = w1b + 65536;
    unsigned short* w3b  = wvb + 65536;
    unsigned short* wqkb = w3b + 65536;
    float* bqk = (float*)(wqkb + 16384);
    float2* mzP = (float2*)(wsb + ((size_t)98 << 20) + ((size_t)512 << 10));
    float* psum   = (float*)(wsb + ((size_t)99 << 20));
    float* psumsq = psum + 32768;
    float* sc1 = psumsq + 32768; float* sh1 = sc1 + 256;
    float* sc2 = sh1 + 256;      float* sh2 = sc2 + 256;
    float* sc3 = sh2 + 256;      float* sh3 = sc3 + 256;
    unsigned short* y3b = y1b;
    unsigned short* upn = xt;
    float* h2t = hs;

    cvt_weights<<<256, 256, 0, stream>>>(w1, wq, wk, wv, w3, bq, bk,
                                         w1b, wqkb, wvb, w3b, bqk);
    transpose_cvt<<<dim3(256, 4, 4), 256, 0, stream>>>(x, xt, 16384);

    // net1: conv1 (MFMA) -> BN stats -> BN+ReLU+down
    gemm_mfma<128, 2><<<dim3(128, 2, 4), 256, 0, stream>>>(w1b, xt, nullptr, y1b, 16384, 256);
    channel_stats_bf16<<<dim3(256, 4), 256, 0, stream>>>(y1b, psum, psumsq, 16384);
    bn_finalize<<<1, 256, 0, stream>>>(psum, psumsq, g1, b1, sc1, sh1, 1.f / 65536.f, 4);
    bnrelu_down<<<dim3(16, 256, 4), 256, 0, stream>>>(y1b, sc1, sh1, hs);
    transpose_cvt<<<dim3(64, 4, 4), 256, 0, stream>>>(hs, hst, 4096);

    // net2: merged qk projection + v projection + split-K attention + combine
    gemm_mfma<64, 1><<<dim3(32, 1, 4), 256, 0, stream>>>(wqkb, hst, bqk, qkT, 4096, 64);
    gemm_mfma<128, 2><<<dim3(32, 2, 4), 256, 0, stream>>>(wvb, hst, bv, vbb, 4096, 256);
    attn_partial<<<dim3(64, 4, 4), 512, 0, stream>>>(qkT, vbb, accPb, mzP);
    attn_combine<<<dim3(512, 4), 256, 0, stream>>>(accPb, mzP, hst, gamma, h2t);

    // net2 tail: BN2 + ReLU fused into upsample
    stats_pmajor<<<dim3(32, 4), 256, 0, stream>>>(h2t, psum, psumsq);
    bn_finalize<<<1, 256, 0, stream>>>(psum, psumsq, g2, b2, sc2, sh2, 1.f / 16384.f, 128);
    upsample_bnrelu<<<dim3(1024, 4), 256, 0, stream>>>(h2t, sc2, sh2, upn);

    // net3: conv3 (MFMA) -> BN3 + residual + ReLU
    gemm_mfma<128, 2><<<dim3(128, 2, 4), 256, 0, stream>>>(w3b, upn, nullptr, y3b, 16384, 256);
    channel_stats_bf16<<<dim3(256, 4), 256, 0, stream>>>(y3b, psum, psumsq, 16384);
    bn_finalize<<<1, 256, 0, stream>>>(psum, psumsq, g3, b3, sc3, sh3, 1.f / 65536.f, 4);
    final_add_relu<<<16384, 256, 0, stream>>>(y3b, sc3, sh3, x, out);
}

// Round 8
// 415.407 us; speedup vs baseline: 3.1648x; 1.0236x over previous
//
#include <hip/hip_runtime.h>
#include <hip/hip_bf16.h>

// B=4, C=256, C8=32, H=128, W=128, H2=W2=64, N=4096, HW=16384
#define EPS_BN 1e-5f

typedef short bf16x8 __attribute__((ext_vector_type(8)));
typedef float f32x4 __attribute__((ext_vector_type(4)));

__device__ __forceinline__ unsigned short f2bf(float f) {
    __hip_bfloat16 h = __float2bfloat16(f);
    return __builtin_bit_cast(unsigned short, h);
}
__device__ __forceinline__ float bf2f(unsigned short u) {
    return __builtin_bit_cast(float, (unsigned)u << 16);
}

// ---------------------------------------------------------------------------
// bf16 MFMA GEMM: Y[b,o,p] = sum_c Wb[o,c] * Xt[b,p,c]  (K=256 fixed)
// BM in {128,64,32}; BN=128; BK=32; 256 threads (4 waves), 2-phase prefetch,
// hoisted per-thread pointers (+32/step).
// MODE 1: bf16 p-major out (B,P,O) + bias  (q/k merged projection)
// MODE 2: bf16 c-major out (B,256,P) + optional bias (conv1/conv3/v)
// ---------------------------------------------------------------------------
template<int BM, int MODE>
__global__ __launch_bounds__(256) void gemm_mfma(
    const unsigned short* __restrict__ Wb,   // (O,256) bf16
    const unsigned short* __restrict__ Xt,   // (B,P,256) bf16
    const float* __restrict__ bias,
    unsigned short* __restrict__ Y,
    int P, int O)
{
    const int tid = threadIdx.x;
    const int w = tid >> 6, l = tid & 63;
    const int b = blockIdx.z;
    const int p0 = blockIdx.x * 128;
    const int o0 = blockIdx.y * BM;
    const int lr = l & 15, lk = l >> 4;
    const int srow = l >> 2, sq = l & 3;     // staging: 16 rows x 4 chunks / wave

    __shared__ unsigned short Al[BM * 40];
    __shared__ unsigned short Bl[128 * 40];

    constexpr int WC = (BM == 32) ? 4 : 2;            // waves along p
    constexpr int MT = (BM == 128) ? 4 : 2;           // o-subtiles / wave
    constexpr int NT = (WC == 2) ? 4 : 2;             // p-subtiles / wave
    const int wr = w / WC, wc = w % WC;
    const int osub = wr * MT * 16, psub = wc * NT * 16;

    f32x4 acc[MT][NT];
#pragma unroll
    for (int i = 0; i < MT; i++)
#pragma unroll
        for (int j = 0; j < NT; j++) acc[i][j] = (f32x4){0.f, 0.f, 0.f, 0.f};

    const unsigned short* Xb = Xt + (size_t)b * P * 256;
    const int ar0 = w * 16, ar1 = w * 16 + 64;   // A rows staged by this wave
    const int br0 = w * 16, br1 = w * 16 + 64;   // B rows staged by this wave

    // hoisted pointers
    const unsigned short* pB0 = Xb + (size_t)(p0 + br0 + srow) * 256 + sq * 8;
    const unsigned short* pB1 = Xb + (size_t)(p0 + br1 + srow) * 256 + sq * 8;
    const unsigned short* pA0 = Wb + (size_t)(o0 + ar0 + srow) * 256 + sq * 8;
    const unsigned short* pA1 = Wb + (size_t)(o0 + ar1 + srow) * 256 + sq * 8;
    unsigned short* BlW0 = &Bl[(br0 + srow) * 40 + sq * 8];
    unsigned short* BlW1 = &Bl[(br1 + srow) * 40 + sq * 8];
    unsigned short* AlW0 = &Al[(ar0 + srow) * 40 + sq * 8];
    unsigned short* AlW1 = &Al[(ar1 + srow) * 40 + sq * 8];

    uint4 vb0, vb1, va0, va1;
#define G_LOADS                                                     \
    vb0 = *(const uint4*)pB0; pB0 += 32;                            \
    vb1 = *(const uint4*)pB1; pB1 += 32;                            \
    if (ar0 < BM) { va0 = *(const uint4*)pA0; pA0 += 32; }          \
    if (ar1 < BM) { va1 = *(const uint4*)pA1; pA1 += 32; }

    G_LOADS
    for (int k0 = 0; k0 < 256; k0 += 32) {
        __syncthreads();   // prior k-step's LDS reads complete
        *(uint4*)BlW0 = vb0;
        *(uint4*)BlW1 = vb1;
        if (ar0 < BM) *(uint4*)AlW0 = va0;
        if (ar1 < BM) *(uint4*)AlW1 = va1;
        __syncthreads();   // staging visible
        if (k0 < 224) { G_LOADS }   // prefetch next, in flight during MFMA
        bf16x8 af[MT], bfr[NT];
#pragma unroll
        for (int i = 0; i < MT; i++) {
            int row = osub + i * 16 + lr;
            af[i] = *(const bf16x8*)&Al[row * 40 + lk * 8];
        }
#pragma unroll
        for (int j = 0; j < NT; j++) {
            int row = psub + j * 16 + lr;
            bfr[j] = *(const bf16x8*)&Bl[row * 40 + lk * 8];
        }
#pragma unroll
        for (int i = 0; i < MT; i++)
#pragma unroll
            for (int j = 0; j < NT; j++)
                acc[i][j] = __builtin_amdgcn_mfma_f32_16x16x32_bf16(af[i], bfr[j], acc[i][j], 0, 0, 0);
    }
#undef G_LOADS

    // epilogue; C/D: col = lane&15 (p), row = (lane>>4)*4 + reg (o)
    if (MODE == 1) {
#pragma unroll
        for (int i = 0; i < MT; i++) {
            int ob = o0 + osub + i * 16 + lk * 4;
#pragma unroll
            for (int j = 0; j < NT; j++) {
                int p = p0 + psub + j * 16 + lr;
                ushort4 pk;
                pk.x = f2bf(acc[i][j][0] + bias[ob + 0]);
                pk.y = f2bf(acc[i][j][1] + bias[ob + 1]);
                pk.z = f2bf(acc[i][j][2] + bias[ob + 2]);
                pk.w = f2bf(acc[i][j][3] + bias[ob + 3]);
                *(ushort4*)&Y[((size_t)b * P + p) * O + ob] = pk;
            }
        }
    } else {
#pragma unroll
        for (int i = 0; i < MT; i++)
#pragma unroll
            for (int r = 0; r < 4; r++) {
                int o = o0 + osub + i * 16 + lk * 4 + r;
                float bs = bias ? bias[o] : 0.f;
#pragma unroll
                for (int j = 0; j < NT; j++) {
                    int p = p0 + psub + j * 16 + lr;
                    Y[((size_t)(b * 256 + o)) * P + p] = f2bf(acc[i][j][r] + bs);
                }
            }
    }
}

// ---------------------------------------------------------------------------
// LDS-tiled transpose + cvt: (B,256,P) f32 -> (B,P,256) bf16
// ---------------------------------------------------------------------------
__global__ __launch_bounds__(256) void transpose_cvt(
    const float* __restrict__ src, unsigned short* __restrict__ dst, int P)
{
    __shared__ float t[64][65];
    const int tid = threadIdx.x;
    const int p0 = blockIdx.x * 64, c0 = blockIdx.y * 64, b = blockIdx.z;
    const float* sb = src + ((size_t)b * 256 + c0) * P + p0;
#pragma unroll
    for (int i = 0; i < 16; i++) {
        int r = (tid >> 6) + 4 * i;   // c-local
        int c = tid & 63;             // p-local
        t[c][r] = sb[(size_t)r * P + c];
    }
    __syncthreads();
#pragma unroll
    for (int i = 0; i < 8; i++) {
        int pr = (tid >> 5) + 8 * i;
        int cc = (tid & 31) * 2;
        unsigned pk = ((unsigned)f2bf(t[pr][cc + 1]) << 16) | f2bf(t[pr][cc]);
        *(unsigned*)&dst[((size_t)b * P + p0 + pr) * 256 + c0 + cc] = pk;
    }
}

__global__ void cvt_weights(const float* __restrict__ w1, const float* __restrict__ wq,
                            const float* __restrict__ wk, const float* __restrict__ wv,
                            const float* __restrict__ w3,
                            const float* __restrict__ bq, const float* __restrict__ bk,
                            unsigned short* o1, unsigned short* oqk,
                            unsigned short* ov, unsigned short* o3, float* obqk)
{
    int i = blockIdx.x * 256 + threadIdx.x;
    if (i < 65536) { o1[i] = f2bf(w1[i]); ov[i] = f2bf(wv[i]); o3[i] = f2bf(w3[i]); }
    if (i < 16384) oqk[i] = f2bf(i < 8192 ? wq[i] : wk[i - 8192]);
    if (i < 64)    obqk[i] = i < 32 ? bq[i] : bk[i - 32];
}

// per-(channel,batch) partial sums over c-major bf16 (B,256,Pn)
__global__ __launch_bounds__(256) void channel_stats_bf16(
    const unsigned short* __restrict__ Y, float* __restrict__ psum,
    float* __restrict__ psumsq, int Pn)
{
    const int o = blockIdx.x, b = blockIdx.y;
    const unsigned short* p = Y + ((size_t)b * 256 + o) * Pn;
    float s = 0.f, s2 = 0.f;
    for (int i = threadIdx.x * 8; i < Pn; i += 2048) {
        uint4 v = *(const uint4*)&p[i];
        unsigned uu[4] = {v.x, v.y, v.z, v.w};
#pragma unroll
        for (int k = 0; k < 4; k++) {
            float a = __builtin_bit_cast(float, uu[k] << 16);
            float c = __builtin_bit_cast(float, uu[k] & 0xffff0000u);
            s += a + c; s2 += a * a + c * c;
        }
    }
#pragma unroll
    for (int off = 32; off; off >>= 1) {
        s  += __shfl_down(s, off);
        s2 += __shfl_down(s2, off);
    }
    __shared__ float ws1[4], ws2[4];
    int lane = threadIdx.x & 63, w = threadIdx.x >> 6;
    if (lane == 0) { ws1[w] = s; ws2[w] = s2; }
    __syncthreads();
    if (threadIdx.x == 0) {
        float ts = 0.f, ts2 = 0.f;
#pragma unroll
        for (int k = 0; k < 4; k++) { ts += ws1[k]; ts2 += ws2[k]; }
        psum[(size_t)b * 256 + o] = ts;
        psumsq[(size_t)b * 256 + o] = ts2;
    }
}

// per-channel partials over p-major f32 (B,4096,256); grid (32, B)
__global__ __launch_bounds__(256) void stats_pmajor(
    const float* __restrict__ Y, float* __restrict__ psum, float* __restrict__ psumsq)
{
    const int chunk = blockIdx.x, b = blockIdx.y, c = threadIdx.x;
    const float* base = Y + ((size_t)b * 4096 + chunk * 128) * 256 + c;
    float s = 0.f, s2 = 0.f;
    for (int i = 0; i < 128; i++) { float v = base[(size_t)i * 256]; s += v; s2 += v * v; }
    psum[((size_t)b * 32 + chunk) * 256 + c] = s;
    psumsq[((size_t)b * 32 + chunk) * 256 + c] = s2;
}

__global__ void bn_finalize(const float* __restrict__ psum, const float* __restrict__ psumsq,
                            const float* __restrict__ g, const float* __restrict__ bb,
                            float* __restrict__ scale, float* __restrict__ shift,
                            float invN, int NP)
{
    int o = threadIdx.x;
    float s = 0.f, s2 = 0.f;
    for (int k = 0; k < NP; k++) { s += psum[k * 256 + o]; s2 += psumsq[k * 256 + o]; }
    float mean = s * invN;
    float var  = s2 * invN - mean * mean;
    float r = rsqrtf(var + EPS_BN);
    float sc = g[o] * r;
    scale[o] = sc;
    shift[o] = bb[o] - mean * sc;
}

// antialiased bilinear 2x downsample taps (jax.image.resize)
__device__ __forceinline__ int dtaps(int u, int* j, float* w) {
    if (u == 0)  { j[0]=0;   j[1]=1;   j[2]=2;   w[0]=3.f/7.f; w[1]=3.f/7.f; w[2]=1.f/7.f; return 3; }
    if (u == 63) { j[0]=125; j[1]=126; j[2]=127; w[0]=1.f/7.f; w[1]=3.f/7.f; w[2]=3.f/7.f; return 3; }
    j[0]=2*u-1; j[1]=2*u; j[2]=2*u+1; j[3]=2*u+2;
    w[0]=0.125f; w[1]=0.375f; w[2]=0.375f; w[3]=0.125f; return 4;
}

// BN + ReLU + 128->64 downsample; y1 bf16 c-major in, hs f32 c-major out
__global__ __launch_bounds__(256) void bnrelu_down(
    const unsigned short* __restrict__ y1, const float* __restrict__ scale,
    const float* __restrict__ shift, float* __restrict__ h)
{
    int i = blockIdx.x * 256 + threadIdx.x;  // 0..4095 over 64x64
    int o = blockIdx.y, b = blockIdx.z;
    int y2 = i >> 6, x2 = i & 63;
    const unsigned short* base = y1 + ((size_t)(b * 256 + o)) * 16384;
    float sc = scale[o], sh = shift[o];
    int jy[4]; float wy[4]; int ny = dtaps(y2, jy, wy);
    int jx[4]; float wx[4]; int nx = dtaps(x2, jx, wx);
    float acc = 0.f;
    for (int a = 0; a < ny; a++) {
        const unsigned short* row = base + jy[a] * 128;
        for (int c = 0; c < nx; c++) {
            float v = fmaxf(fmaf(sc, bf2f(row[jx[c]]), sh), 0.f);
            acc += wy[a] * wx[c] * v;
        }
    }
    h[((size_t)(b * 256 + o)) * 4096 + i] = acc;
}

// ---------------------------------------------------------------------------
// Split-K bf16 MFMA flash attention, S=4 chunks of 1024 keys, 128-row Q tiles.
// qkT (B,4096,64) bf16 (q cols 0..31, k cols 32..63); vb (B,256,4096) bf16.
// Per (i-tile, s, b) block: 16 KV tiles of 64; partials out (bf16 acc + f32 mz).
// 512 thr = 8 waves: (wr=w>>1 -> rows i0+wr*32 as 2 subtiles of 16,
//                     wc=w&1 -> ch wc*128).
// Round-8: 128 q-rows/block so each staged K/V tile (and every LDS vf/kf
// read) amortizes over 2x outputs — kernel was LDS-pipe-throughput bound.
// LDS 54KB: Kl 5KB; Vl 32KB slot-XOR swizzled; Pl 17.4KB shared per wr.
// ---------------------------------------------------------------------------
__global__ __launch_bounds__(512) void attn_partial(
    const unsigned short* __restrict__ qkT, const unsigned short* __restrict__ vb,
    unsigned short* __restrict__ accP, float2* __restrict__ mzP)
{
    const int s = blockIdx.y;
    const int b = blockIdx.z;
    const int i0 = blockIdx.x * 128;
    const int tid = threadIdx.x;
    const int w = tid >> 6, l = tid & 63;
    const int wr = w >> 1, wc = w & 1;
    const int lr = l & 15, lk = l >> 4;

    __shared__ unsigned short Kl[64 * 40];        // 5.0 KB
    __shared__ unsigned short Vl[256 * 64];       // 32.0 KB (swizzled; f32 bounce in epilogue)
    __shared__ unsigned short Pl[4][32 * 68];     // 17.4 KB (shared per wr)

    const unsigned short* qkTb = qkT + (size_t)b * 4096 * 64;
    // Q fragments (A): rows = i0 + wr*32 + i*16 + lr, k = lk*8..+7
    bf16x8 qf[2];
#pragma unroll
    for (int i = 0; i < 2; i++)
        qf[i] = *(const bf16x8*)&qkTb[(size_t)(i0 + wr * 32 + i * 16 + lr) * 64 + lk * 8];

    f32x4 acc[2][8];
#pragma unroll
    for (int i = 0; i < 2; i++)
#pragma unroll
        for (int c = 0; c < 8; c++) acc[i][c] = (f32x4){0.f, 0.f, 0.f, 0.f};
    float m[2][4], zp[2][4];
#pragma unroll
    for (int i = 0; i < 2; i++)
#pragma unroll
        for (int r = 0; r < 4; r++) { m[i][r] = -1e30f; zp[i][r] = 0.f; }

    const int jbase = s * 1024;
    // per-thread global pointers, bumped by constants per tile
    const unsigned short* kPtr =
        qkTb + (size_t)(jbase + w * 16 + (l >> 2)) * 64 + 32 + (l & 3) * 8;
    const unsigned short* vPtr =
        vb + (size_t)b * 256 * 4096 + (size_t)(w * 32 + (l >> 3)) * 4096 + jbase + (l & 7) * 8;
    unsigned short* Pw = Pl[wr];

    uint4 kreg, vreg[4];
    if (w < 4) kreg = *(const uint4*)kPtr;
#pragma unroll
    for (int it = 0; it < 4; it++) vreg[it] = *(const uint4*)(vPtr + it * 32768);

    for (int t = 0; t < 16; t++) {
        __syncthreads();   // prior tile's LDS reads complete
        if (w < 4) *(uint4*)&Kl[(w * 16 + (l >> 2)) * 40 + (l & 3) * 8] = kreg;
#pragma unroll
        for (int it = 0; it < 4; it++) {
            int ch = w * 32 + it * 8 + (l >> 3);
            *(uint4*)&Vl[ch * 64 + (((l & 7) ^ (ch & 7)) * 8)] = vreg[it];
        }
        __syncthreads();
        if (t < 15) {   // prefetch next tile during compute
            kPtr += 4096; vPtr += 64;
            if (w < 4) kreg = *(const uint4*)kPtr;
#pragma unroll
            for (int it = 0; it < 4; it++) vreg[it] = *(const uint4*)(vPtr + it * 32768);
        }

        // per row-subtile: QK^T -> softmax -> P write (sv reused across i)
#pragma unroll
        for (int i = 0; i < 2; i++) {
            f32x4 sv[4];
#pragma unroll
            for (int jt = 0; jt < 4; jt++) {
                bf16x8 kf = *(const bf16x8*)&Kl[(jt * 16 + lr) * 40 + lk * 8];
                sv[jt] = __builtin_amdgcn_mfma_f32_16x16x32_bf16(qf[i], kf, (f32x4){0.f,0.f,0.f,0.f}, 0, 0, 0);
            }
            bool grew = false;
            float corr[4];
#pragma unroll
            for (int r = 0; r < 4; r++) {
                float tm = fmaxf(fmaxf(sv[0][r], sv[1][r]), fmaxf(sv[2][r], sv[3][r]));
#pragma unroll
                for (int off = 1; off < 16; off <<= 1) tm = fmaxf(tm, __shfl_xor(tm, off));
                float mo = m[i][r];
                float mn = fmaxf(mo, tm);
                bool g = tm > mo;
                corr[r] = g ? __expf(mo - mn) : 1.f;
                grew |= g;
                m[i][r] = mn;
                float ps = 0.f;
#pragma unroll
                for (int jt = 0; jt < 4; jt++) {
                    float p = __expf(sv[jt][r] - mn);
                    ps += p;
                    Pw[(i * 16 + lk * 4 + r) * 68 + lr + jt * 16] = f2bf(p);
                }
                zp[i][r] = zp[i][r] * corr[r] + ps;
            }
            if (__any(grew)) {
#pragma unroll
                for (int c = 0; c < 8; c++)
#pragma unroll
                    for (int r = 0; r < 4; r++) acc[i][c][r] *= corr[r];
            }
        }

        // PV: 2 k-chunks x 8 channel subtiles; vf reused across both subtiles
#pragma unroll
        for (int kc = 0; kc < 2; kc++) {
            bf16x8 pa[2];
#pragma unroll
            for (int i = 0; i < 2; i++)
                pa[i] = *(const bf16x8*)&Pw[(i * 16 + lr) * 68 + (kc * 4 + lk) * 8];
#pragma unroll
            for (int ct = 0; ct < 8; ct++) {
                int ch = wc * 128 + ct * 16 + lr;
                bf16x8 vf = *(const bf16x8*)&Vl[ch * 64 + (((kc * 4 + lk) ^ (lr & 7)) * 8)];
#pragma unroll
                for (int i = 0; i < 2; i++)
                    acc[i][ct] = __builtin_amdgcn_mfma_f32_16x16x32_bf16(pa[i], vf, acc[i][ct], 0, 0, 0);
            }
        }
    }

    // z-reduce over the 16-lane group
    float zs[2][4];
#pragma unroll
    for (int i = 0; i < 2; i++)
#pragma unroll
        for (int r = 0; r < 4; r++) {
            float zz = zp[i][r];
#pragma unroll
            for (int off = 1; off < 16; off <<= 1) zz += __shfl_xor(zz, off);
            zs[i][r] = zz;
        }
    const size_t rbase0 = (size_t)(b * 4 + s) * 4096 + i0;
    if (wc == 0 && lr == 0) {
#pragma unroll
        for (int i = 0; i < 2; i++)
#pragma unroll
            for (int r = 0; r < 4; r++)
                mzP[rbase0 + wr * 32 + i * 16 + lk * 4 + r] = make_float2(m[i][r], zs[i][r]);
    }

    // coalesced bf16 epilogue: four 32-row passes through LDS (Vl reused f32)
    float* Eb = (float*)Vl;   // 8192 f32 = 32 rows x 256 ch
    __syncthreads();          // all Vl/Pl reads complete
#pragma unroll
    for (int h = 0; h < 4; h++) {
        if (wr == h) {
#pragma unroll
            for (int i = 0; i < 2; i++)
#pragma unroll
                for (int ct = 0; ct < 8; ct++)
#pragma unroll
                    for (int r = 0; r < 4; r++)
                        Eb[(i * 16 + lk * 4 + r) * 256 + wc * 128 + ct * 16 + lr] = acc[i][ct][r];
        }
        __syncthreads();
        unsigned short* dst = accP + (rbase0 + h * 32) * 256;
#pragma unroll
        for (int q = 0; q < 4; q++) {
            float4 v = ((const float4*)Eb)[tid + q * 512];
            ushort4 pk = { f2bf(v.x), f2bf(v.y), f2bf(v.z), f2bf(v.w) };
            *(ushort4*)&dst[(tid + q * 512) * 4] = pk;
        }
        __syncthreads();
    }
}

// merge S=4 chunk partials: out = gamma * (sum ws*acc)/(sum ws*z) + residual
// grid (512, B): 8 rows per block
__global__ __launch_bounds__(256) void attn_combine(
    const unsigned short* __restrict__ accP, const float2* __restrict__ mzP,
    const unsigned short* __restrict__ hst, const float* __restrict__ gamma_p,
    float* __restrict__ h2t)
{
    const int b = blockIdx.y, ch = threadIdx.x;
    const float gamma = gamma_p[0];
    for (int rr = 0; rr < 8; rr++) {
        int row = blockIdx.x * 8 + rr;
        float2 mz[4];
#pragma unroll
        for (int s = 0; s < 4; s++) mz[s] = mzP[(size_t)(b * 4 + s) * 4096 + row];
        float M = fmaxf(fmaxf(mz[0].x, mz[1].x), fmaxf(mz[2].x, mz[3].x));
        float Z = 0.f, a = 0.f;
#pragma unroll
        for (int s = 0; s < 4; s++) {
            float wgt = __expf(mz[s].x - M);
            Z += wgt * mz[s].y;
            a += wgt * bf2f(accP[((size_t)(b * 4 + s) * 4096 + row) * 256 + ch]);
        }
        size_t off = ((size_t)b * 4096 + row) * 256 + ch;
        h2t[off] = gamma * a / Z + bf2f(hst[off]);
    }
}

// BN2+ReLU fused with bilinear 64->128 upsample; p-major in/out
// grid (1024, B): 16 pixels per block
__global__ __launch_bounds__(256) void upsample_bnrelu(
    const float* __restrict__ h2t, const float* __restrict__ scale,
    const float* __restrict__ shift, unsigned short* __restrict__ upn)
{
    const int b = blockIdx.y, c = threadIdx.x;
    const float* basep = h2t + ((size_t)b * 4096) * 256 + c;
    float sc = scale[c], sh = shift[c];
    for (int pp = 0; pp < 16; pp++) {
        int p = blockIdx.x * 16 + pp;
        int y = p >> 7, x = p & 127;
        float fy = 0.5f * y - 0.25f, fx = 0.5f * x - 0.25f;
        float fiy = floorf(fy), fix = floorf(fx);
        float wy = fy - fiy, wx = fx - fix;
        int iy = (int)fiy, ix = (int)fix;
        int iy0 = max(iy, 0), iy1 = min(iy + 1, 63);
        int ix0 = max(ix, 0), ix1 = min(ix + 1, 63);
        float v00 = fmaxf(fmaf(sc, basep[(size_t)(iy0 * 64 + ix0) * 256], sh), 0.f);
        float v01 = fmaxf(fmaf(sc, basep[(size_t)(iy0 * 64 + ix1) * 256], sh), 0.f);
        float v10 = fmaxf(fmaf(sc, basep[(size_t)(iy1 * 64 + ix0) * 256], sh), 0.f);
        float v11 = fmaxf(fmaf(sc, basep[(size_t)(iy1 * 64 + ix1) * 256], sh), 0.f);
        float r0 = (1.f - wy) * ((1.f - wx) * v00 + wx * v01)
                 + wy * ((1.f - wx) * v10 + wx * v11);
        upn[((size_t)b * 16384 + p) * 256 + c] = f2bf(r0);
    }
}

// out = relu(bn3(y3) + x); y3 bf16 c-major
__global__ __launch_bounds__(256) void final_add_relu(
    const unsigned short* __restrict__ y3, const float* __restrict__ scale,
    const float* __restrict__ shift, const float* __restrict__ x,
    float* __restrict__ outp)
{
    size_t e = ((size_t)blockIdx.x * 256 + threadIdx.x) * 4;
    int c = (int)((e >> 14) & 255);
    ushort4 yv = *(const ushort4*)&y3[e];
    float4 xv = *(const float4*)&x[e];
    float sc = scale[c], sh = shift[c];
    float4 o;
    o.x = fmaxf(fmaf(sc, bf2f(yv.x), sh) + xv.x, 0.f);
    o.y = fmaxf(fmaf(sc, bf2f(yv.y), sh) + xv.y, 0.f);
    o.z = fmaxf(fmaf(sc, bf2f(yv.z), sh) + xv.z, 0.f);
    o.w = fmaxf(fmaf(sc, bf2f(yv.w), sh) + xv.w, 0.f);
    *(float4*)&outp[e] = o;
}

extern "C" void kernel_launch(void* const* d_in, const int* in_sizes, int n_in,
                              void* d_out, int out_size, void* d_ws, size_t ws_size,
                              hipStream_t stream)
{
    const float* x     = (const float*)d_in[0];
    const float* w1    = (const float*)d_in[1];
    const float* g1    = (const float*)d_in[2];
    const float* b1    = (const float*)d_in[3];
    const float* wq    = (const float*)d_in[4];
    const float* bq    = (const float*)d_in[5];
    const float* wk    = (const float*)d_in[6];
    const float* bk    = (const float*)d_in[7];
    const float* wv    = (const float*)d_in[8];
    const float* bv    = (const float*)d_in[9];
    const float* gamma = (const float*)d_in[10];
    const float* g2    = (const float*)d_in[11];
    const float* b2    = (const float*)d_in[12];
    const float* w3    = (const float*)d_in[13];
    const float* g3    = (const float*)d_in[14];
    const float* b3    = (const float*)d_in[15];
    float* out = (float*)d_out;

    char* wsb = (char*)d_ws;
    unsigned short* y1b = (unsigned short*)wsb;                        // 0-32 (later y3b)
    unsigned short* xt  = (unsigned short*)(wsb + ((size_t)32 << 20)); // 32-64 (later upn)
    unsigned short* accPb = (unsigned short*)wsb;                      // 0-32 during attn (bf16)
    float* hs   = (float*)(wsb + ((size_t)64 << 20));                  // 64-80 (later h2t)
    unsigned short* vbb = (unsigned short*)(wsb + ((size_t)80 << 20)); // 80-88
    unsigned short* hst = (unsigned short*)(wsb + ((size_t)88 << 20)); // 88-96
    unsigned short* qkT = (unsigned short*)(wsb + ((size_t)96 << 20)); // 96-98
    unsigned short* w1b = (unsigned short*)(wsb + ((size_t)98 << 20));
    unsigned short* wvb  = w1b + 65536;
    unsigned short* w3b  = wvb + 65536;
    unsigned short* wqkb = w3b + 65536;
    float* bqk = (float*)(wqkb + 16384);
    float2* mzP = (float2*)(wsb + ((size_t)98 << 20) + ((size_t)512 << 10));
    float* psum   = (float*)(wsb + ((size_t)99 << 20));
    float* psumsq = psum + 32768;
    float* sc1 = psumsq + 32768; float* sh1 = sc1 + 256;
    float* sc2 = sh1 + 256;      float* sh2 = sc2 + 256;
    float* sc3 = sh2 + 256;      float* sh3 = sc3 + 256;
    unsigned short* y3b = y1b;
    unsigned short* upn = xt;
    float* h2t = hs;

    cvt_weights<<<256, 256, 0, stream>>>(w1, wq, wk, wv, w3, bq, bk,
                                         w1b, wqkb, wvb, w3b, bqk);
    transpose_cvt<<<dim3(256, 4, 4), 256, 0, stream>>>(x, xt, 16384);

    // net1: conv1 (MFMA) -> BN stats -> BN+ReLU+down
    gemm_mfma<128, 2><<<dim3(128, 2, 4), 256, 0, stream>>>(w1b, xt, nullptr, y1b, 16384, 256);
    channel_stats_bf16<<<dim3(256, 4), 256, 0, stream>>>(y1b, psum, psumsq, 16384);
    bn_finalize<<<1, 256, 0, stream>>>(psum, psumsq, g1, b1, sc1, sh1, 1.f / 65536.f, 4);
    bnrelu_down<<<dim3(16, 256, 4), 256, 0, stream>>>(y1b, sc1, sh1, hs);
    transpose_cvt<<<dim3(64, 4, 4), 256, 0, stream>>>(hs, hst, 4096);

    // net2: merged qk projection + v projection + split-K attention + combine
    gemm_mfma<64, 1><<<dim3(32, 1, 4), 256, 0, stream>>>(wqkb, hst, bqk, qkT, 4096, 64);
    gemm_mfma<128, 2><<<dim3(32, 2, 4), 256, 0, stream>>>(wvb, hst, bv, vbb, 4096, 256);
    attn_partial<<<dim3(32, 4, 4), 512, 0, stream>>>(qkT, vbb, accPb, mzP);
    attn_combine<<<dim3(512, 4), 256, 0, stream>>>(accPb, mzP, hst, gamma, h2t);

    // net2 tail: BN2 + ReLU fused into upsample
    stats_pmajor<<<dim3(32, 4), 256, 0, stream>>>(h2t, psum, psumsq);
    bn_finalize<<<1, 256, 0, stream>>>(psum, psumsq, g2, b2, sc2, sh2, 1.f / 16384.f, 128);
    upsample_bnrelu<<<dim3(1024, 4), 256, 0, stream>>>(h2t, sc2, sh2, upn);

    // net3: conv3 (MFMA) -> BN3 + residual + ReLU
    gemm_mfma<128, 2><<<dim3(128, 2, 4), 256, 0, stream>>>(w3b, upn, nullptr, y3b, 16384, 256);
    channel_stats_bf16<<<dim3(256, 4), 256, 0, stream>>>(y3b, psum, psumsq, 16384);
    bn_finalize<<<1, 256, 0, stream>>>(psum, psumsq, g3, b3, sc3, sh3, 1.f / 65536.f, 4);
    final_add_relu<<<16384, 256, 0, stream>>>(y3b, sc3, sh3, x, out);
}

// Round 9
// 403.313 us; speedup vs baseline: 3.2597x; 1.0300x over previous
//
#include <hip/hip_runtime.h>
#include <hip/hip_bf16.h>

// B=4, C=256, C8=32, H=128, W=128, H2=W2=64, N=4096, HW=16384
#define EPS_BN 1e-5f

typedef short bf16x8 __attribute__((ext_vector_type(8)));
typedef float f32x4 __attribute__((ext_vector_type(4)));

__device__ __forceinline__ unsigned short f2bf(float f) {
    __hip_bfloat16 h = __float2bfloat16(f);
    return __builtin_bit_cast(unsigned short, h);
}
__device__ __forceinline__ float bf2f(unsigned short u) {
    return __builtin_bit_cast(float, (unsigned)u << 16);
}

// ---------------------------------------------------------------------------
// bf16 MFMA GEMM: Y[b,o,p] = sum_c Wb[o,c] * Xt[b,p,c]  (K=256 fixed)
// BM in {128,64,32}; BN=128; BK=32; 256 threads (4 waves), 2-phase prefetch,
// hoisted per-thread pointers (+32/step).
// MODE 1: bf16 p-major out (B,P,O) + bias  (q/k merged projection)
// MODE 2: bf16 c-major out (B,256,P) + optional bias (conv1/conv3/v)
// ---------------------------------------------------------------------------
template<int BM, int MODE>
__global__ __launch_bounds__(256) void gemm_mfma(
    const unsigned short* __restrict__ Wb,   // (O,256) bf16
    const unsigned short* __restrict__ Xt,   // (B,P,256) bf16
    const float* __restrict__ bias,
    unsigned short* __restrict__ Y,
    int P, int O)
{
    const int tid = threadIdx.x;
    const int w = tid >> 6, l = tid & 63;
    const int b = blockIdx.z;
    const int p0 = blockIdx.x * 128;
    const int o0 = blockIdx.y * BM;
    const int lr = l & 15, lk = l >> 4;
    const int srow = l >> 2, sq = l & 3;     // staging: 16 rows x 4 chunks / wave

    __shared__ unsigned short Al[BM * 40];
    __shared__ unsigned short Bl[128 * 40];

    constexpr int WC = (BM == 32) ? 4 : 2;            // waves along p
    constexpr int MT = (BM == 128) ? 4 : 2;           // o-subtiles / wave
    constexpr int NT = (WC == 2) ? 4 : 2;             // p-subtiles / wave
    const int wr = w / WC, wc = w % WC;
    const int osub = wr * MT * 16, psub = wc * NT * 16;

    f32x4 acc[MT][NT];
#pragma unroll
    for (int i = 0; i < MT; i++)
#pragma unroll
        for (int j = 0; j < NT; j++) acc[i][j] = (f32x4){0.f, 0.f, 0.f, 0.f};

    const unsigned short* Xb = Xt + (size_t)b * P * 256;
    const int ar0 = w * 16, ar1 = w * 16 + 64;   // A rows staged by this wave
    const int br0 = w * 16, br1 = w * 16 + 64;   // B rows staged by this wave

    // hoisted pointers
    const unsigned short* pB0 = Xb + (size_t)(p0 + br0 + srow) * 256 + sq * 8;
    const unsigned short* pB1 = Xb + (size_t)(p0 + br1 + srow) * 256 + sq * 8;
    const unsigned short* pA0 = Wb + (size_t)(o0 + ar0 + srow) * 256 + sq * 8;
    const unsigned short* pA1 = Wb + (size_t)(o0 + ar1 + srow) * 256 + sq * 8;
    unsigned short* BlW0 = &Bl[(br0 + srow) * 40 + sq * 8];
    unsigned short* BlW1 = &Bl[(br1 + srow) * 40 + sq * 8];
    unsigned short* AlW0 = &Al[(ar0 + srow) * 40 + sq * 8];
    unsigned short* AlW1 = &Al[(ar1 + srow) * 40 + sq * 8];

    uint4 vb0, vb1, va0, va1;
#define G_LOADS                                                     \
    vb0 = *(const uint4*)pB0; pB0 += 32;                            \
    vb1 = *(const uint4*)pB1; pB1 += 32;                            \
    if (ar0 < BM) { va0 = *(const uint4*)pA0; pA0 += 32; }          \
    if (ar1 < BM) { va1 = *(const uint4*)pA1; pA1 += 32; }

    G_LOADS
    for (int k0 = 0; k0 < 256; k0 += 32) {
        __syncthreads();   // prior k-step's LDS reads complete
        *(uint4*)BlW0 = vb0;
        *(uint4*)BlW1 = vb1;
        if (ar0 < BM) *(uint4*)AlW0 = va0;
        if (ar1 < BM) *(uint4*)AlW1 = va1;
        __syncthreads();   // staging visible
        if (k0 < 224) { G_LOADS }   // prefetch next, in flight during MFMA
        bf16x8 af[MT], bfr[NT];
#pragma unroll
        for (int i = 0; i < MT; i++) {
            int row = osub + i * 16 + lr;
            af[i] = *(const bf16x8*)&Al[row * 40 + lk * 8];
        }
#pragma unroll
        for (int j = 0; j < NT; j++) {
            int row = psub + j * 16 + lr;
            bfr[j] = *(const bf16x8*)&Bl[row * 40 + lk * 8];
        }
#pragma unroll
        for (int i = 0; i < MT; i++)
#pragma unroll
            for (int j = 0; j < NT; j++)
                acc[i][j] = __builtin_amdgcn_mfma_f32_16x16x32_bf16(af[i], bfr[j], acc[i][j], 0, 0, 0);
    }
#undef G_LOADS

    // epilogue; C/D: col = lane&15 (p), row = (lane>>4)*4 + reg (o)
    if (MODE == 1) {
#pragma unroll
        for (int i = 0; i < MT; i++) {
            int ob = o0 + osub + i * 16 + lk * 4;
#pragma unroll
            for (int j = 0; j < NT; j++) {
                int p = p0 + psub + j * 16 + lr;
                ushort4 pk;
                pk.x = f2bf(acc[i][j][0] + bias[ob + 0]);
                pk.y = f2bf(acc[i][j][1] + bias[ob + 1]);
                pk.z = f2bf(acc[i][j][2] + bias[ob + 2]);
                pk.w = f2bf(acc[i][j][3] + bias[ob + 3]);
                *(ushort4*)&Y[((size_t)b * P + p) * O + ob] = pk;
            }
        }
    } else {
#pragma unroll
        for (int i = 0; i < MT; i++)
#pragma unroll
            for (int r = 0; r < 4; r++) {
                int o = o0 + osub + i * 16 + lk * 4 + r;
                float bs = bias ? bias[o] : 0.f;
#pragma unroll
                for (int j = 0; j < NT; j++) {
                    int p = p0 + psub + j * 16 + lr;
                    Y[((size_t)(b * 256 + o)) * P + p] = f2bf(acc[i][j][r] + bs);
                }
            }
    }
}

// ---------------------------------------------------------------------------
// LDS-tiled transpose + cvt: (B,256,P) f32 -> (B,P,256) bf16
// ---------------------------------------------------------------------------
__global__ __launch_bounds__(256) void transpose_cvt(
    const float* __restrict__ src, unsigned short* __restrict__ dst, int P)
{
    __shared__ float t[64][65];
    const int tid = threadIdx.x;
    const int p0 = blockIdx.x * 64, c0 = blockIdx.y * 64, b = blockIdx.z;
    const float* sb = src + ((size_t)b * 256 + c0) * P + p0;
#pragma unroll
    for (int i = 0; i < 16; i++) {
        int r = (tid >> 6) + 4 * i;   // c-local
        int c = tid & 63;             // p-local
        t[c][r] = sb[(size_t)r * P + c];
    }
    __syncthreads();
#pragma unroll
    for (int i = 0; i < 8; i++) {
        int pr = (tid >> 5) + 8 * i;
        int cc = (tid & 31) * 2;
        unsigned pk = ((unsigned)f2bf(t[pr][cc + 1]) << 16) | f2bf(t[pr][cc]);
        *(unsigned*)&dst[((size_t)b * P + p0 + pr) * 256 + c0 + cc] = pk;
    }
}

__global__ void cvt_weights(const float* __restrict__ w1, const float* __restrict__ wq,
                            const float* __restrict__ wk, const float* __restrict__ wv,
                            const float* __restrict__ w3,
                            const float* __restrict__ bq, const float* __restrict__ bk,
                            unsigned short* o1, unsigned short* oqk,
                            unsigned short* ov, unsigned short* o3, float* obqk)
{
    int i = blockIdx.x * 256 + threadIdx.x;
    if (i < 65536) { o1[i] = f2bf(w1[i]); ov[i] = f2bf(wv[i]); o3[i] = f2bf(w3[i]); }
    if (i < 16384) oqk[i] = f2bf(i < 8192 ? wq[i] : wk[i - 8192]);
    if (i < 64)    obqk[i] = i < 32 ? bq[i] : bk[i - 32];
}

// per-(channel,batch) partial sums over c-major bf16 (B,256,Pn)
__global__ __launch_bounds__(256) void channel_stats_bf16(
    const unsigned short* __restrict__ Y, float* __restrict__ psum,
    float* __restrict__ psumsq, int Pn)
{
    const int o = blockIdx.x, b = blockIdx.y;
    const unsigned short* p = Y + ((size_t)b * 256 + o) * Pn;
    float s = 0.f, s2 = 0.f;
    for (int i = threadIdx.x * 8; i < Pn; i += 2048) {
        uint4 v = *(const uint4*)&p[i];
        unsigned uu[4] = {v.x, v.y, v.z, v.w};
#pragma unroll
        for (int k = 0; k < 4; k++) {
            float a = __builtin_bit_cast(float, uu[k] << 16);
            float c = __builtin_bit_cast(float, uu[k] & 0xffff0000u);
            s += a + c; s2 += a * a + c * c;
        }
    }
#pragma unroll
    for (int off = 32; off; off >>= 1) {
        s  += __shfl_down(s, off);
        s2 += __shfl_down(s2, off);
    }
    __shared__ float ws1[4], ws2[4];
    int lane = threadIdx.x & 63, w = threadIdx.x >> 6;
    if (lane == 0) { ws1[w] = s; ws2[w] = s2; }
    __syncthreads();
    if (threadIdx.x == 0) {
        float ts = 0.f, ts2 = 0.f;
#pragma unroll
        for (int k = 0; k < 4; k++) { ts += ws1[k]; ts2 += ws2[k]; }
        psum[(size_t)b * 256 + o] = ts;
        psumsq[(size_t)b * 256 + o] = ts2;
    }
}

// per-channel partials over p-major f32 (B,4096,256); grid (32, B)
__global__ __launch_bounds__(256) void stats_pmajor(
    const float* __restrict__ Y, float* __restrict__ psum, float* __restrict__ psumsq)
{
    const int chunk = blockIdx.x, b = blockIdx.y, c = threadIdx.x;
    const float* base = Y + ((size_t)b * 4096 + chunk * 128) * 256 + c;
    float s = 0.f, s2 = 0.f;
    for (int i = 0; i < 128; i++) { float v = base[(size_t)i * 256]; s += v; s2 += v * v; }
    psum[((size_t)b * 32 + chunk) * 256 + c] = s;
    psumsq[((size_t)b * 32 + chunk) * 256 + c] = s2;
}

__global__ void bn_finalize(const float* __restrict__ psum, const float* __restrict__ psumsq,
                            const float* __restrict__ g, const float* __restrict__ bb,
                            float* __restrict__ scale, float* __restrict__ shift,
                            float invN, int NP)
{
    int o = threadIdx.x;
    float s = 0.f, s2 = 0.f;
    for (int k = 0; k < NP; k++) { s += psum[k * 256 + o]; s2 += psumsq[k * 256 + o]; }
    float mean = s * invN;
    float var  = s2 * invN - mean * mean;
    float r = rsqrtf(var + EPS_BN);
    float sc = g[o] * r;
    scale[o] = sc;
    shift[o] = bb[o] - mean * sc;
}

// antialiased bilinear 2x downsample taps (jax.image.resize)
__device__ __forceinline__ int dtaps(int u, int* j, float* w) {
    if (u == 0)  { j[0]=0;   j[1]=1;   j[2]=2;   w[0]=3.f/7.f; w[1]=3.f/7.f; w[2]=1.f/7.f; return 3; }
    if (u == 63) { j[0]=125; j[1]=126; j[2]=127; w[0]=1.f/7.f; w[1]=3.f/7.f; w[2]=3.f/7.f; return 3; }
    j[0]=2*u-1; j[1]=2*u; j[2]=2*u+1; j[3]=2*u+2;
    w[0]=0.125f; w[1]=0.375f; w[2]=0.375f; w[3]=0.125f; return 4;
}

// BN + ReLU + 128->64 downsample; y1 bf16 c-major in, hs f32 c-major out
__global__ __launch_bounds__(256) void bnrelu_down(
    const unsigned short* __restrict__ y1, const float* __restrict__ scale,
    const float* __restrict__ shift, float* __restrict__ h)
{
    int i = blockIdx.x * 256 + threadIdx.x;  // 0..4095 over 64x64
    int o = blockIdx.y, b = blockIdx.z;
    int y2 = i >> 6, x2 = i & 63;
    const unsigned short* base = y1 + ((size_t)(b * 256 + o)) * 16384;
    float sc = scale[o], sh = shift[o];
    int jy[4]; float wy[4]; int ny = dtaps(y2, jy, wy);
    int jx[4]; float wx[4]; int nx = dtaps(x2, jx, wx);
    float acc = 0.f;
    for (int a = 0; a < ny; a++) {
        const unsigned short* row = base + jy[a] * 128;
        for (int c = 0; c < nx; c++) {
            float v = fmaxf(fmaf(sc, bf2f(row[jx[c]]), sh), 0.f);
            acc += wy[a] * wx[c] * v;
        }
    }
    h[((size_t)(b * 256 + o)) * 4096 + i] = acc;
}

// ---------------------------------------------------------------------------
// Split-K bf16 MFMA flash attention, S=4 chunks of 1024 keys, 128-row Q tiles.
// Round-9: kernel is LDS-pipe bound (r8 accounting: shuffles 5.6K + PV 3.8K +
// P-writes 2.6K + K-reads 1.5K cyc/CU/tile ≈ 13.3K measured wall).
//  (a) defer-max: skip the 4-step shuffle reduce unless a lane exceeds
//      m_old+10 (exact math — shift is arbitrary; bounded exp<=e^10).
//  (b) K fragments loaded directly from global/L2 (Kl staging deleted).
// LDS 50.2KB: Vl 32KB slot-XOR swizzled; Pl 17.4KB padded-68, shared per wr
// (wc-pair waves compute identical data -> identical writes, benign).
// ---------------------------------------------------------------------------
__global__ __launch_bounds__(512) void attn_partial(
    const unsigned short* __restrict__ qkT, const unsigned short* __restrict__ vb,
    unsigned short* __restrict__ accP, float2* __restrict__ mzP)
{
    const int s = blockIdx.y;
    const int b = blockIdx.z;
    const int i0 = blockIdx.x * 128;
    const int tid = threadIdx.x;
    const int w = tid >> 6, l = tid & 63;
    const int wr = w >> 1, wc = w & 1;
    const int lr = l & 15, lk = l >> 4;

    __shared__ unsigned short Vl[256 * 64];       // 32.0 KB (swizzled; f32 bounce in epilogue)
    __shared__ unsigned short Pl[4][32 * 68];     // 17.4 KB (shared per wr)

    const unsigned short* qkTb = qkT + (size_t)b * 4096 * 64;
    // Q fragments (A): rows = i0 + wr*32 + i*16 + lr, k = lk*8..+7
    bf16x8 qf[2];
#pragma unroll
    for (int i = 0; i < 2; i++)
        qf[i] = *(const bf16x8*)&qkTb[(size_t)(i0 + wr * 32 + i * 16 + lr) * 64 + lk * 8];

    f32x4 acc[2][8];
#pragma unroll
    for (int i = 0; i < 2; i++)
#pragma unroll
        for (int c = 0; c < 8; c++) acc[i][c] = (f32x4){0.f, 0.f, 0.f, 0.f};
    float m[2][4], zp[2][4];
#pragma unroll
    for (int i = 0; i < 2; i++)
#pragma unroll
        for (int r = 0; r < 4; r++) { m[i][r] = -1e30f; zp[i][r] = 0.f; }

    const int jbase = s * 1024;
    // K fragment pointer (direct global): row jbase + jt*16 + lr, col 32+lk*8
    const unsigned short* kPtr = qkTb + (size_t)(jbase + lr) * 64 + 32 + lk * 8;
    const unsigned short* vPtr =
        vb + (size_t)b * 256 * 4096 + (size_t)(w * 32 + (l >> 3)) * 4096 + jbase + (l & 7) * 8;
    unsigned short* Pw = Pl[wr];

    uint4 kfr[4], vreg[4];
#pragma unroll
    for (int jt = 0; jt < 4; jt++) kfr[jt] = *(const uint4*)(kPtr + jt * 1024);
    kPtr += 4096;
#pragma unroll
    for (int it = 0; it < 4; it++) vreg[it] = *(const uint4*)(vPtr + it * 32768);

    for (int t = 0; t < 16; t++) {
        __syncthreads();   // prior tile's LDS reads complete
#pragma unroll
        for (int it = 0; it < 4; it++) {
            int ch = w * 32 + it * 8 + (l >> 3);
            *(uint4*)&Vl[ch * 64 + (((l & 7) ^ (ch & 7)) * 8)] = vreg[it];
        }
        __syncthreads();
        if (t < 15) {   // V prefetch for next tile
            vPtr += 64;
#pragma unroll
            for (int it = 0; it < 4; it++) vreg[it] = *(const uint4*)(vPtr + it * 32768);
        }

        // per row-subtile: QK^T -> defer-max softmax -> P write
#pragma unroll
        for (int i = 0; i < 2; i++) {
            f32x4 sv[4];
#pragma unroll
            for (int jt = 0; jt < 4; jt++)
                sv[jt] = __builtin_amdgcn_mfma_f32_16x16x32_bf16(
                    qf[i], __builtin_bit_cast(bf16x8, kfr[jt]), (f32x4){0.f,0.f,0.f,0.f}, 0, 0, 0);
            float tml[4];
            bool trig = false;
#pragma unroll
            for (int r = 0; r < 4; r++) {
                tml[r] = fmaxf(fmaxf(sv[0][r], sv[1][r]), fmaxf(sv[2][r], sv[3][r]));
                trig |= (tml[r] > m[i][r] + 10.0f);
            }
            if (__any(trig)) {   // rare: full reduce + rescale
                float corr[4];
#pragma unroll
                for (int r = 0; r < 4; r++) {
                    float tm = tml[r];
#pragma unroll
                    for (int off = 1; off < 16; off <<= 1) tm = fmaxf(tm, __shfl_xor(tm, off));
                    float mo = m[i][r];
                    float mn = fmaxf(mo, tm);
                    corr[r] = __expf(mo - mn);
                    m[i][r] = mn;
                    float ps = 0.f;
#pragma unroll
                    for (int jt = 0; jt < 4; jt++) {
                        float p = __expf(sv[jt][r] - mn);
                        ps += p;
                        Pw[(i * 16 + lk * 4 + r) * 68 + lr + jt * 16] = f2bf(p);
                    }
                    zp[i][r] = zp[i][r] * corr[r] + ps;
                }
#pragma unroll
                for (int c = 0; c < 8; c++)
#pragma unroll
                    for (int r = 0; r < 4; r++) acc[i][c][r] *= corr[r];
            } else {             // common: stale max, no shuffles, no rescale
#pragma unroll
                for (int r = 0; r < 4; r++) {
                    float mn = m[i][r];
                    float ps = 0.f;
#pragma unroll
                    for (int jt = 0; jt < 4; jt++) {
                        float p = __expf(sv[jt][r] - mn);
                        ps += p;
                        Pw[(i * 16 + lk * 4 + r) * 68 + lr + jt * 16] = f2bf(p);
                    }
                    zp[i][r] += ps;
                }
            }
        }

        if (t < 15) {   // K prefetch for next tile (after last kfr use)
#pragma unroll
            for (int jt = 0; jt < 4; jt++) kfr[jt] = *(const uint4*)(kPtr + jt * 1024);
            kPtr += 4096;
        }

        // PV: 2 k-chunks x 8 channel subtiles; vf reused across both subtiles
#pragma unroll
        for (int kc = 0; kc < 2; kc++) {
            bf16x8 pa[2];
#pragma unroll
            for (int i = 0; i < 2; i++)
                pa[i] = *(const bf16x8*)&Pw[(i * 16 + lr) * 68 + (kc * 4 + lk) * 8];
#pragma unroll
            for (int ct = 0; ct < 8; ct++) {
                int ch = wc * 128 + ct * 16 + lr;
                bf16x8 vf = *(const bf16x8*)&Vl[ch * 64 + (((kc * 4 + lk) ^ (lr & 7)) * 8)];
#pragma unroll
                for (int i = 0; i < 2; i++)
                    acc[i][ct] = __builtin_amdgcn_mfma_f32_16x16x32_bf16(pa[i], vf, acc[i][ct], 0, 0, 0);
            }
        }
    }

    // z-reduce over the 16-lane group
    float zs[2][4];
#pragma unroll
    for (int i = 0; i < 2; i++)
#pragma unroll
        for (int r = 0; r < 4; r++) {
            float zz = zp[i][r];
#pragma unroll
            for (int off = 1; off < 16; off <<= 1) zz += __shfl_xor(zz, off);
            zs[i][r] = zz;
        }
    const size_t rbase0 = (size_t)(b * 4 + s) * 4096 + i0;
    if (wc == 0 && lr == 0) {
#pragma unroll
        for (int i = 0; i < 2; i++)
#pragma unroll
            for (int r = 0; r < 4; r++)
                mzP[rbase0 + wr * 32 + i * 16 + lk * 4 + r] = make_float2(m[i][r], zs[i][r]);
    }

    // coalesced bf16 epilogue: four 32-row passes through LDS (Vl reused f32)
    float* Eb = (float*)Vl;   // 8192 f32 = 32 rows x 256 ch
    __syncthreads();          // all Vl/Pl reads complete
#pragma unroll
    for (int h = 0; h < 4; h++) {
        if (wr == h) {
#pragma unroll
            for (int i = 0; i < 2; i++)
#pragma unroll
                for (int ct = 0; ct < 8; ct++)
#pragma unroll
                    for (int r = 0; r < 4; r++)
                        Eb[(i * 16 + lk * 4 + r) * 256 + wc * 128 + ct * 16 + lr] = acc[i][ct][r];
        }
        __syncthreads();
        unsigned short* dst = accP + (rbase0 + h * 32) * 256;
#pragma unroll
        for (int q = 0; q < 4; q++) {
            float4 v = ((const float4*)Eb)[tid + q * 512];
            ushort4 pk = { f2bf(v.x), f2bf(v.y), f2bf(v.z), f2bf(v.w) };
            *(ushort4*)&dst[(tid + q * 512) * 4] = pk;
        }
        __syncthreads();
    }
}

// merge S=4 chunk partials: out = gamma * (sum ws*acc)/(sum ws*z) + residual
// grid (512, B): 8 rows per block
__global__ __launch_bounds__(256) void attn_combine(
    const unsigned short* __restrict__ accP, const float2* __restrict__ mzP,
    const unsigned short* __restrict__ hst, const float* __restrict__ gamma_p,
    float* __restrict__ h2t)
{
    const int b = blockIdx.y, ch = threadIdx.x;
    const float gamma = gamma_p[0];
    for (int rr = 0; rr < 8; rr++) {
        int row = blockIdx.x * 8 + rr;
        float2 mz[4];
#pragma unroll
        for (int s = 0; s < 4; s++) mz[s] = mzP[(size_t)(b * 4 + s) * 4096 + row];
        float M = fmaxf(fmaxf(mz[0].x, mz[1].x), fmaxf(mz[2].x, mz[3].x));
        float Z = 0.f, a = 0.f;
#pragma unroll
        for (int s = 0; s < 4; s++) {
            float wgt = __expf(mz[s].x - M);
            Z += wgt * mz[s].y;
            a += wgt * bf2f(accP[((size_t)(b * 4 + s) * 4096 + row) * 256 + ch]);
        }
        size_t off = ((size_t)b * 4096 + row) * 256 + ch;
        h2t[off] = gamma * a / Z + bf2f(hst[off]);
    }
}

// BN2+ReLU fused with bilinear 64->128 upsample; p-major in/out
// grid (1024, B): 16 pixels per block
__global__ __launch_bounds__(256) void upsample_bnrelu(
    const float* __restrict__ h2t, const float* __restrict__ scale,
    const float* __restrict__ shift, unsigned short* __restrict__ upn)
{
    const int b = blockIdx.y, c = threadIdx.x;
    const float* basep = h2t + ((size_t)b * 4096) * 256 + c;
    float sc = scale[c], sh = shift[c];
    for (int pp = 0; pp < 16; pp++) {
        int p = blockIdx.x * 16 + pp;
        int y = p >> 7, x = p & 127;
        float fy = 0.5f * y - 0.25f, fx = 0.5f * x - 0.25f;
        float fiy = floorf(fy), fix = floorf(fx);
        float wy = fy - fiy, wx = fx - fix;
        int iy = (int)fiy, ix = (int)fix;
        int iy0 = max(iy, 0), iy1 = min(iy + 1, 63);
        int ix0 = max(ix, 0), ix1 = min(ix + 1, 63);
        float v00 = fmaxf(fmaf(sc, basep[(size_t)(iy0 * 64 + ix0) * 256], sh), 0.f);
        float v01 = fmaxf(fmaf(sc, basep[(size_t)(iy0 * 64 + ix1) * 256], sh), 0.f);
        float v10 = fmaxf(fmaf(sc, basep[(size_t)(iy1 * 64 + ix0) * 256], sh), 0.f);
        float v11 = fmaxf(fmaf(sc, basep[(size_t)(iy1 * 64 + ix1) * 256], sh), 0.f);
        float r0 = (1.f - wy) * ((1.f - wx) * v00 + wx * v01)
                 + wy * ((1.f - wx) * v10 + wx * v11);
        upn[((size_t)b * 16384 + p) * 256 + c] = f2bf(r0);
    }
}

// out = relu(bn3(y3) + x); y3 bf16 c-major
__global__ __launch_bounds__(256) void final_add_relu(
    const unsigned short* __restrict__ y3, const float* __restrict__ scale,
    const float* __restrict__ shift, const float* __restrict__ x,
    float* __restrict__ outp)
{
    size_t e = ((size_t)blockIdx.x * 256 + threadIdx.x) * 4;
    int c = (int)((e >> 14) & 255);
    ushort4 yv = *(const ushort4*)&y3[e];
    float4 xv = *(const float4*)&x[e];
    float sc = scale[c], sh = shift[c];
    float4 o;
    o.x = fmaxf(fmaf(sc, bf2f(yv.x), sh) + xv.x, 0.f);
    o.y = fmaxf(fmaf(sc, bf2f(yv.y), sh) + xv.y, 0.f);
    o.z = fmaxf(fmaf(sc, bf2f(yv.z), sh) + xv.z, 0.f);
    o.w = fmaxf(fmaf(sc, bf2f(yv.w), sh) + xv.w, 0.f);
    *(float4*)&outp[e] = o;
}

extern "C" void kernel_launch(void* const* d_in, const int* in_sizes, int n_in,
                              void* d_out, int out_size, void* d_ws, size_t ws_size,
                              hipStream_t stream)
{
    const float* x     = (const float*)d_in[0];
    const float* w1    = (const float*)d_in[1];
    const float* g1    = (const float*)d_in[2];
    const float* b1    = (const float*)d_in[3];
    const float* wq    = (const float*)d_in[4];
    const float* bq    = (const float*)d_in[5];
    const float* wk    = (const float*)d_in[6];
    const float* bk    = (const float*)d_in[7];
    const float* wv    = (const float*)d_in[8];
    const float* bv    = (const float*)d_in[9];
    const float* gamma = (const float*)d_in[10];
    const float* g2    = (const float*)d_in[11];
    const float* b2    = (const float*)d_in[12];
    const float* w3    = (const float*)d_in[13];
    const float* g3    = (const float*)d_in[14];
    const float* b3    = (const float*)d_in[15];
    float* out = (float*)d_out;

    char* wsb = (char*)d_ws;
    unsigned short* y1b = (unsigned short*)wsb;                        // 0-32 (later y3b)
    unsigned short* xt  = (unsigned short*)(wsb + ((size_t)32 << 20)); // 32-64 (later upn)
    unsigned short* accPb = (unsigned short*)wsb;                      // 0-32 during attn (bf16)
    float* hs   = (float*)(wsb + ((size_t)64 << 20));                  // 64-80 (later h2t)
    unsigned short* vbb = (unsigned short*)(wsb + ((size_t)80 << 20)); // 80-88
    unsigned short* hst = (unsigned short*)(wsb + ((size_t)88 << 20)); // 88-96
    unsigned short* qkT = (unsigned short*)(wsb + ((size_t)96 << 20)); // 96-98
    unsigned short* w1b = (unsigned short*)(wsb + ((size_t)98 << 20));
    unsigned short* wvb  = w1b + 65536;
    unsigned short* w3b  = wvb + 65536;
    unsigned short* wqkb = w3b + 65536;
    float* bqk = (float*)(wqkb + 16384);
    float2* mzP = (float2*)(wsb + ((size_t)98 << 20) + ((size_t)512 << 10));
    float* psum   = (float*)(wsb + ((size_t)99 << 20));
    float* psumsq = psum + 32768;
    float* sc1 = psumsq + 32768; float* sh1 = sc1 + 256;
    float* sc2 = sh1 + 256;      float* sh2 = sc2 + 256;
    float* sc3 = sh2 + 256;      float* sh3 = sc3 + 256;
    unsigned short* y3b = y1b;
    unsigned short* upn = xt;
    float* h2t = hs;

    cvt_weights<<<256, 256, 0, stream>>>(w1, wq, wk, wv, w3, bq, bk,
                                         w1b, wqkb, wvb, w3b, bqk);
    transpose_cvt<<<dim3(256, 4, 4), 256, 0, stream>>>(x, xt, 16384);

    // net1: conv1 (MFMA) -> BN stats -> BN+ReLU+down
    gemm_mfma<128, 2><<<dim3(128, 2, 4), 256, 0, stream>>>(w1b, xt, nullptr, y1b, 16384, 256);
    channel_stats_bf16<<<dim3(256, 4), 256, 0, stream>>>(y1b, psum, psumsq, 16384);
    bn_finalize<<<1, 256, 0, stream>>>(psum, psumsq, g1, b1, sc1, sh1, 1.f / 65536.f, 4);
    bnrelu_down<<<dim3(16, 256, 4), 256, 0, stream>>>(y1b, sc1, sh1, hs);
    transpose_cvt<<<dim3(64, 4, 4), 256, 0, stream>>>(hs, hst, 4096);

    // net2: merged qk projection + v projection + split-K attention + combine
    gemm_mfma<64, 1><<<dim3(32, 1, 4), 256, 0, stream>>>(wqkb, hst, bqk, qkT, 4096, 64);
    gemm_mfma<128, 2><<<dim3(32, 2, 4), 256, 0, stream>>>(wvb, hst, bv, vbb, 4096, 256);
    attn_partial<<<dim3(32, 4, 4), 512, 0, stream>>>(qkT, vbb, accPb, mzP);
    attn_combine<<<dim3(512, 4), 256, 0, stream>>>(accPb, mzP, hst, gamma, h2t);

    // net2 tail: BN2 + ReLU fused into upsample
    stats_pmajor<<<dim3(32, 4), 256, 0, stream>>>(h2t, psum, psumsq);
    bn_finalize<<<1, 256, 0, stream>>>(psum, psumsq, g2, b2, sc2, sh2, 1.f / 16384.f, 128);
    upsample_bnrelu<<<dim3(1024, 4), 256, 0, stream>>>(h2t, sc2, sh2, upn);

    // net3: conv3 (MFMA) -> BN3 + residual + ReLU
    gemm_mfma<128, 2><<<dim3(128, 2, 4), 256, 0, stream>>>(w3b, upn, nullptr, y3b, 16384, 256);
    channel_stats_bf16<<<dim3(256, 4), 256, 0, stream>>>(y3b, psum, psumsq, 16384);
    bn_finalize<<<1, 256, 0, stream>>>(psum, psumsq, g3, b3, sc3, sh3, 1.f / 65536.f, 4);
    final_add_relu<<<16384, 256, 0, stream>>>(y3b, sc3, sh3, x, out);
}